// Round 8
// baseline (914.165 us; speedup 1.0000x reference)
//
#include <hip/hip_runtime.h>
#include <math.h>

#define NPTS 576
#define N2 331776           // 576*576
#define BSZ 4
#define NB 64               // cholesky block
#define NT 9                // 576/64

#define INVL2 (1.0f/0.29311396f)

typedef __attribute__((ext_vector_type(8))) short short8v;   // 8 bf16 (4 VGPRs)
typedef __attribute__((ext_vector_type(16))) float f32x16;   // MFMA 32x32 acc

// ---------------------------------------------------------------------------
// build Kxx (+jitter) and opiK (4 planes) from xin; fused: copy_xout + w2.
// ---------------------------------------------------------------------------
__global__ void build_k(const float* __restrict__ xin,
                        float* __restrict__ Kxx, float* __restrict__ opiK,
                        float* __restrict__ out,
                        const float* __restrict__ w, float* __restrict__ W2) {
    int idx = blockIdx.x * 256 + threadIdx.x;
    if (idx < 4608) out[idx] = xin[idx];     // fused copy_xout
    int b = idx / N2;
    int rem = idx - b * N2;
    int m = rem / NPTS;
    int nn = rem - m * NPTS;
    const float* xb = xin + (size_t)b * NPTS * 2;
    float xm0 = xb[m*2],  xm1 = xb[m*2+1];
    float xn0 = xb[nn*2], xn1 = xb[nn*2+1];
    float r0 = xm0 - xn0, r1 = xm1 - xn1;
    float u = (r0*r0 + r1*r1) * INVL2;
    float Kv = expf(-0.5f * u);
    Kxx[idx] = Kv + ((m == nn) ? 1e-5f : 0.0f);
    size_t base = (size_t)b * 4 * N2 + rem;
    opiK[base]          = Kv;
    opiK[base + N2]     = -r0 * INVL2 * Kv;
    opiK[base + 2*N2]   = -r1 * INVL2 * Kv;
    opiK[base + 3*N2]   = (u - 2.0f) * INVL2 * Kv;
    // fused w2 (one WG): W2[i][j] = mean_o sum_c w[o][c][i] w[o][c][j]
    if (blockIdx.x == 5183) {
        __shared__ float red[256];
        int tid = threadIdx.x;
        int pair = tid & 15;
        int slice = tid >> 4;
        int i = pair >> 2, j = pair & 3;
        float s = 0.0f;
        for (int o = slice * 4; o < slice * 4 + 4; ++o)
            for (int c = 0; c < 32; ++c)
                s += w[o*128 + c*4 + i] * w[o*128 + c*4 + j];
        red[tid] = s;
        __syncthreads();
        if (tid < 16) {
            float t = 0.0f;
            #pragma unroll
            for (int k = 0; k < 16; ++k) t += red[pair + 16*k];
            W2[pair] = t * (1.0f/64.0f);
        }
    }
}

// ---------------------------------------------------------------------------
// factor 64x64 SPD block in T (lower), produce V = T^{-1} (lower).
// r4: panel factor row-per-lane in registers + __shfl (no LDS on the chain).
// r5: diag 16x16 inverse also register+shuffle. Block-solve r0 verbatim.
// ---------------------------------------------------------------------------
__device__ void factor_invert_64(float (*T)[NB+1], float (*V)[NB+1],
                                 float (*tmp)[17], int tid) {
    for (int p = 0; p < 4; ++p) {
        int cp = p * 16;
        if (tid < 64) {
            int r = tid;
            float reg[16];
            #pragma unroll
            for (int q = 0; q < 16; ++q) reg[q] = T[r][cp + q];
            #pragma unroll
            for (int j = 0; j < 16; ++j) {
                int col = cp + j;
                float d2 = __shfl(reg[j], col);          // pivot (pre-sqrt)
                float d = sqrtf(fmaxf(d2, 1e-12f));
                float lr = (r == col) ? d : reg[j] / d;  // junk for r<col, unused
                reg[j] = lr;
                #pragma unroll
                for (int q = j + 1; q < 16; ++q) {
                    float lc = __shfl(lr, cp + q);       // L[cp+q][col]
                    if (r >= cp + q) reg[q] -= lr * lc;
                }
            }
            #pragma unroll
            for (int q = 0; q < 16; ++q) T[r][cp + q] = reg[q];
        }
        __syncthreads();
        int tr = 48 - cp;
        if (tr > 0) {
            for (int idx = tid; idx < tr * tr; idx += 256) {
                int r = cp + 16 + idx / tr;
                int c = cp + 16 + idx % tr;
                if (c <= r) {
                    float s = 0.0f;
                    #pragma unroll
                    for (int k = 0; k < 16; ++k) s += T[r][cp+k] * T[c][cp+k];
                    T[r][c] -= s;
                }
            }
        }
        __syncthreads();
    }
    // diag 16x16 inverses: column-per-lane forward substitution in registers.
    if (tid < 64) {
        int I = tid >> 4, c = tid & 15, base = I * 16;
        float tcol[16];
        #pragma unroll
        for (int i = 0; i < 16; ++i) tcol[i] = T[base + i][base + c];
        float v[16];
        #pragma unroll
        for (int i = 0; i < 16; ++i) {
            float s = (i == c) ? 1.0f : 0.0f;
            #pragma unroll
            for (int k = 0; k < 16; ++k) {
                if (k < i) {                              // compile-time mask
                    float tik = __shfl(tcol[i], base + k);
                    s -= tik * v[k];
                }
            }
            float tii = __shfl(tcol[i], base + i);
            v[i] = s / tii;                               // exact 0 for i<c
        }
        #pragma unroll
        for (int i = 0; i < 16; ++i) V[base + i][base + c] = v[i];
    }
    __syncthreads();
    const int PI[6] = {1,2,3,2,3,3};
    const int PJ[6] = {0,1,2,0,1,0};
    int rr16 = tid >> 4, cc16 = tid & 15;
    for (int p = 0; p < 6; ++p) {
        int I = PI[p], J = PJ[p];
        float s = 0.0f;
        for (int K = J; K < I; ++K)
            #pragma unroll
            for (int t = 0; t < 16; ++t)
                s += T[I*16+rr16][K*16+t] * V[K*16+t][J*16+cc16];
        tmp[rr16][cc16] = s;
        __syncthreads();
        float s2 = 0.0f;
        for (int t = 0; t <= rr16; ++t) s2 += V[I*16+rr16][I*16+t] * tmp[t][cc16];
        __syncthreads();
        V[I*16+rr16][J*16+cc16] = -s2;
        __syncthreads();
    }
}

// ---------------------------------------------------------------------------
__global__ void chol_diag0(const float* __restrict__ A, float* __restrict__ LinvKK,
                           float* __restrict__ VTKK) {
    int b = blockIdx.x;
    const float* Ab = A + (size_t)b * N2;
    __shared__ float T[NB][NB+1];
    __shared__ float V[NB][NB+1];
    __shared__ float tmp[16][17];
    int tid = threadIdx.x;
    for (int idx = tid; idx < NB*NB; idx += 256) {
        int r = idx >> 6, c = idx & 63;
        T[r][c] = Ab[(size_t)r * NPTS + c];
        V[r][c] = 0.0f;
    }
    __syncthreads();
    factor_invert_64(T, V, tmp, tid);
    float* Vg  = LinvKK + (size_t)b * NT * NB * NB;
    float* VTg = VTKK  + (size_t)b * NT * NB * NB;
    for (int idx = tid; idx < NB*NB; idx += 256) {
        Vg[idx]  = V[idx >> 6][idx & 63];
        VTg[idx] = V[idx & 63][idx >> 6];    // V^T for trinv float4 staging
    }
}

// ---------------------------------------------------------------------------
// fused Cholesky step for panel kb. 9 total launches.
// r7: diag blocks write the L panel TRANSPOSED to LT; V^T alongside V.
// ---------------------------------------------------------------------------
__global__ __launch_bounds__(256)
void chol_step(float* __restrict__ A, float* __restrict__ LT,
               float* __restrict__ LinvKK, float* __restrict__ VTKK, int kb) {
    int b = blockIdx.y;
    int p = blockIdx.x;
    int ir = 0;
    while (p >= ir + 1) { p -= ir + 1; ir++; }
    int ib = kb + 1 + ir, jb = kb + 1 + p;
    float* Ab = A + (size_t)b * N2;
    float* LTb = LT + (size_t)b * N2;
    __shared__ float Ai[NB][NB+1];
    __shared__ float Aj[NB][NB+1];
    __shared__ float Vs[NB][NB+1];
    __shared__ float tmp[16][17];
    int tid = threadIdx.x;
    int tx = tid & 15, ty = tid >> 4;
    const float* Vg = LinvKK + ((size_t)b * NT + kb) * NB * NB;
    bool diag = (ib == jb);
    for (int idx = tid; idx < NB*NB; idx += 256) {
        int r = idx >> 6, c = idx & 63;
        Ai[r][c] = Ab[(size_t)(ib*NB + r) * NPTS + kb*NB + c];
        Aj[r][c] = diag ? 0.0f : Ab[(size_t)(jb*NB + r) * NPTS + kb*NB + c];
        Vs[r][c] = Vg[idx];
    }
    float U[4][4];
    #pragma unroll
    for (int i = 0; i < 4; ++i)
        #pragma unroll
        for (int j = 0; j < 4; ++j)
            U[i][j] = Ab[(size_t)(ib*NB + ty*4+i) * NPTS + jb*NB + tx*4+j];
    __syncthreads();
    float Li[4][4] = {}, Lj[4][4] = {};
    for (int k = 0; k < NB; ++k) {
        float a[4], v[4];
        #pragma unroll
        for (int i = 0; i < 4; ++i) a[i] = Ai[ty*4+i][k];
        #pragma unroll
        for (int j = 0; j < 4; ++j) v[j] = Vs[tx*4+j][k];
        #pragma unroll
        for (int i = 0; i < 4; ++i)
            #pragma unroll
            for (int j = 0; j < 4; ++j) Li[i][j] += a[i] * v[j];
        if (!diag) {
            float aj[4];
            #pragma unroll
            for (int i = 0; i < 4; ++i) aj[i] = Aj[ty*4+i][k];
            #pragma unroll
            for (int i = 0; i < 4; ++i)
                #pragma unroll
                for (int j = 0; j < 4; ++j) Lj[i][j] += aj[i] * v[j];
        }
    }
    __syncthreads();
    #pragma unroll
    for (int i = 0; i < 4; ++i)
        #pragma unroll
        for (int j = 0; j < 4; ++j) {
            Ai[ty*4+i][tx*4+j] = Li[i][j];
            Aj[ty*4+i][tx*4+j] = diag ? Li[i][j] : Lj[i][j];
        }
    if (diag) {
        // write panel L[ib][kb] transposed: LT[kb*NB+col][ib*NB+row]
        #pragma unroll
        for (int i = 0; i < 4; ++i)
            #pragma unroll
            for (int j = 0; j < 4; ++j)
                LTb[(size_t)(kb*NB + tx*4+j) * NPTS + ib*NB + ty*4+i] = Li[i][j];
    }
    __syncthreads();
    float s[4][4] = {};
    for (int k = 0; k < NB; ++k) {
        float a[4], v[4];
        #pragma unroll
        for (int i = 0; i < 4; ++i) a[i] = Ai[ty*4+i][k];
        #pragma unroll
        for (int j = 0; j < 4; ++j) v[j] = Aj[tx*4+j][k];
        #pragma unroll
        for (int i = 0; i < 4; ++i)
            #pragma unroll
            for (int j = 0; j < 4; ++j) s[i][j] += a[i] * v[j];
    }
    #pragma unroll
    for (int i = 0; i < 4; ++i)
        #pragma unroll
        for (int j = 0; j < 4; ++j) U[i][j] -= s[i][j];
    if (blockIdx.x != 0) {
        #pragma unroll
        for (int i = 0; i < 4; ++i)
            #pragma unroll
            for (int j = 0; j < 4; ++j)
                Ab[(size_t)(ib*NB + ty*4+i) * NPTS + jb*NB + tx*4+j] = U[i][j];
        return;
    }
    __syncthreads();
    #pragma unroll
    for (int i = 0; i < 4; ++i)
        #pragma unroll
        for (int j = 0; j < 4; ++j) Ai[ty*4+i][tx*4+j] = U[i][j];
    for (int idx = tid; idx < NB*NB; idx += 256) Aj[idx >> 6][idx & 63] = 0.0f;
    __syncthreads();
    factor_invert_64(Ai, Aj, tmp, tid);
    float* Vo  = LinvKK + ((size_t)b * NT + (kb + 1)) * NB * NB;
    float* VTo = VTKK  + ((size_t)b * NT + (kb + 1)) * NB * NB;
    for (int idx = tid; idx < NB*NB; idx += 256) {
        Vo[idx]  = Aj[idx >> 6][idx & 63];
        VTo[idx] = Aj[idx & 63][idx >> 6];
    }
}

// ---------------------------------------------------------------------------
// blocked triangular inverse. grid (4 col-splits, 9 block-cols, 4 batch)
// r8: REGISTER PREFETCH — stage addresses are data-independent, so the next
// stage's 4xfloat4 global loads issue BEFORE the current compute loop and
// commit regs->LDS after the barrier. HBM latency (~900cyc, FETCH=10.7MB all
// misses) overlaps compute instead of extending the 44-stage serial chain.
// Also zero-fills its own upper-triangle columns (replaces hipMemsetAsync).
// Values bit-identical to r7.
// ---------------------------------------------------------------------------
__global__ __launch_bounds__(256)
void trinv_blk(const float* __restrict__ LT, const float* __restrict__ LinvKK,
               const float* __restrict__ VTKK, float* __restrict__ Linv) {
    int sp = blockIdx.x, jb = blockIdx.y, b = blockIdx.z;
    const float* LTb = LT + (size_t)b * N2;
    float* Xg = Linv + (size_t)b * N2;
    const float* Vg  = LinvKK + (size_t)b * NT * NB * NB;
    const float* VTg = VTKK  + (size_t)b * NT * NB * NB;
    int c0 = jb * NB + sp * 16;

    __shared__ float LsT[64][72];
    __shared__ float Xc[576][17];
    __shared__ float Ss[64][17];

    int tid = threadIdx.x;
    int tx = tid & 15, ty = tid >> 4;
    int st = tid >> 2, sc = (tid & 3) * 16;   // staging coords (64 x 4x16)

    // zero upper-triangle rows [0, jb*NB) of this block's 16 columns
    // (replaces the hipMemsetAsync dispatch; no overlap across blocks)
    {
        float4 z = {0.0f, 0.0f, 0.0f, 0.0f};
        for (int i = tid; i < jb * NB * 4; i += 256) {
            int r = i >> 2, q = i & 3;
            *(float4*)(Xg + (size_t)r * NPTS + c0 + q * 4) = z;
        }
    }

    float4 pf[4];
    auto issueL = [&](int ib, int kb) {
        const float* src = LTb + (size_t)(kb * NB + st) * NPTS + ib * NB + sc;
        #pragma unroll
        for (int q = 0; q < 4; ++q) pf[q] = *(const float4*)(src + q * 4);
    };
    auto issueV = [&](int ib) {
        const float* src = VTg + (size_t)ib * NB * NB + st * NB + sc;
        #pragma unroll
        for (int q = 0; q < 4; ++q) pf[q] = *(const float4*)(src + q * 4);
    };
    auto commit = [&]() {
        #pragma unroll
        for (int q = 0; q < 4; ++q) *(float4*)&LsT[st][sc + q * 4] = pf[q];
    };

    {
        const float* Vjj = Vg + (size_t)jb * NB * NB;
        int r = tid >> 2, c4 = (tid & 3) * 4;
        float4 v = *(const float4*)(Vjj + r * NB + sp * 16 + c4);
        Xc[r][c4+0] = v.x; Xc[r][c4+1] = v.y; Xc[r][c4+2] = v.z; Xc[r][c4+3] = v.w;
        *(float4*)(Xg + (size_t)(jb * NB + r) * NPTS + c0 + c4) = v;
    }
    if (jb + 1 < NT) issueL(jb + 1, jb);
    __syncthreads();

    for (int ib = jb + 1; ib < NT; ++ib) {
        float acc[4] = {};
        for (int kb = jb; kb < ib; ++kb) {
            commit();                          // pf -> LsT (loads awaited here)
            __syncthreads();
            if (kb + 1 < ib) issueL(ib, kb + 1);   // prefetch next stage
            else             issueV(ib);
            int xbase = (kb - jb) * 64;
            #pragma unroll 8
            for (int t = 0; t < 64; ++t) {
                float a4[4]; *(float4*)a4 = *(const float4*)&LsT[t][ty*4];
                float xv = Xc[xbase + t][tx];
                #pragma unroll
                for (int i = 0; i < 4; ++i) acc[i] += a4[i] * xv;
            }
            __syncthreads();
        }
        commit();                              // VT tile
        #pragma unroll
        for (int i = 0; i < 4; ++i) Ss[ty*4+i][tx] = acc[i];
        __syncthreads();
        if (ib + 1 < NT) issueL(ib + 1, jb);   // prefetch next ib's first stage
        float acc2[4] = {};
        #pragma unroll 8
        for (int t = 0; t < 64; ++t) {
            float a4[4]; *(float4*)a4 = *(const float4*)&LsT[t][ty*4];
            float sv = Ss[t][tx];
            #pragma unroll
            for (int i = 0; i < 4; ++i) acc2[i] += a4[i] * sv;
        }
        int obase = (ib - jb) * 64;
        #pragma unroll
        for (int i = 0; i < 4; ++i) {
            float v = -acc2[i];
            Xc[obase + ty*4 + i][tx] = v;
            Xg[(size_t)(ib * NB + ty*4 + i) * NPTS + c0 + tx] = v;
        }
        __syncthreads();
    }
}

// ---------------------------------------------------------------------------
// bf16x3 split helpers for fp32-precision MFMA GEMM.
// ---------------------------------------------------------------------------
__device__ inline void split3(float v, unsigned short& h0, unsigned short& h1,
                              unsigned short& h2) {
    unsigned u0 = __float_as_uint(v) & 0xffff0000u;
    float f0 = __uint_as_float(u0);
    float r1 = v - f0;                       // exact
    unsigned u1 = __float_as_uint(r1) & 0xffff0000u;
    float f1 = __uint_as_float(u1);
    float r2 = r1 - f1;                      // exact
    h0 = (unsigned short)(u0 >> 16);
    h1 = (unsigned short)(u1 >> 16);
    h2 = (unsigned short)((__float_as_uint(r2) + 0x8000u) >> 16);  // RNE-ish
}

__device__ inline void pack_store(unsigned short* dst, const unsigned short* v) {
    uint4 w;
    w.x = (unsigned)v[0] | ((unsigned)v[1] << 16);
    w.y = (unsigned)v[2] | ((unsigned)v[3] << 16);
    w.z = (unsigned)v[4] | ((unsigned)v[5] << 16);
    w.w = (unsigned)v[6] | ((unsigned)v[7] << 16);
    *(uint4*)dst = w;
}

// ---------------------------------------------------------------------------
// mm_p2_mfma: plane-pair GEMM C[p] = A[p] @ B (bf16x3, 6 MFMAs/product).
// ---------------------------------------------------------------------------
template<int EPIB>
__global__ __launch_bounds__(256, 2)
void mm_p2_mfma(const float* __restrict__ Aall, const float* __restrict__ Ball,
                float* __restrict__ Call, long sA, long sB, long sC)
{
    int id = blockIdx.x;
    int x8 = id & 7, qq = id >> 3;
    int nx = qq % 9;
    int band = x8 + 8 * (qq / 9);
    if (band >= 18 * BSZ) return;
    int t  = band % 18;
    int b  = band / 18;
    int pp = t / 9, my = t % 9;
    const float* A0 = Aall + (size_t)b * sA + (size_t)(pp * 2) * N2;
    const float* A1 = A0 + N2;
    const float* B  = Ball + (size_t)b * sB;
    float* C0 = Call + (size_t)b * sC + (size_t)(pp * 2) * N2;
    float* C1 = C0 + N2;
    int n0 = nx * 64, m0 = my * 64;

    __shared__ __align__(16) unsigned short As[12][2][64][8];   // 24 KB
    __shared__ __align__(16) unsigned short Bs[6][2][64][8];    // 12 KB

    int tid  = threadIdx.x;
    int lane = tid & 63;
    int wid  = tid >> 6;
    int wr = wid >> 1, wc = wid & 1;

    f32x16 acc0, acc1;
    #pragma unroll
    for (int i = 0; i < 16; ++i) { acc0[i] = 0.0f; acc1[i] = 0.0f; }

    int ap   = tid >> 7;
    int aq   = tid & 127;
    int ar   = aq >> 1;
    int asub = aq & 1;
    const float* Apl = ap ? A1 : A0;
    int areg = ar >> 5;
    int aln  = ar & 31;

    int bc   = tid & 63;
    int bkg  = tid >> 6;
    int bsub = bkg >> 1;
    int bln  = (bc & 31) + 32 * (bkg & 1);
    int bwc  = bc >> 5;

    float av[16];
    float bv[8];

    auto loadA = [&](int k0) {
        const float* p = Apl + (size_t)(m0 + ar) * 576 + k0 + asub * 16;
        float4 t0 = *(const float4*)(p);
        float4 t1 = *(const float4*)(p + 4);
        float4 t2 = *(const float4*)(p + 8);
        float4 t3 = *(const float4*)(p + 12);
        av[0]=t0.x;  av[1]=t0.y;  av[2]=t0.z;  av[3]=t0.w;
        av[4]=t1.x;  av[5]=t1.y;  av[6]=t1.z;  av[7]=t1.w;
        av[8]=t2.x;  av[9]=t2.y;  av[10]=t2.z; av[11]=t2.w;
        av[12]=t3.x; av[13]=t3.y; av[14]=t3.z; av[15]=t3.w;
    };
    auto loadB = [&](int k0) {
        const float* p = B + (size_t)(k0 + bkg * 8) * 576 + n0 + bc;
        #pragma unroll
        for (int j = 0; j < 8; ++j) {
            float v = p[(size_t)j * 576];
            if (EPIB) { if (k0 + bkg * 8 + j == n0 + bc) v -= 1.0f; }
            bv[j] = v;
        }
    };
    auto storeA = [&]() {
        unsigned short s0[16], s1[16], s2[16];
        #pragma unroll
        for (int j = 0; j < 16; ++j) split3(av[j], s0[j], s1[j], s2[j]);
        #pragma unroll
        for (int h = 0; h < 2; ++h) {
            int ln = aln + 32 * h;
            pack_store(&As[(ap*3 + 0)*2 + areg][asub][ln][0], &s0[8*h]);
            pack_store(&As[(ap*3 + 1)*2 + areg][asub][ln][0], &s1[8*h]);
            pack_store(&As[(ap*3 + 2)*2 + areg][asub][ln][0], &s2[8*h]);
        }
    };
    auto storeB = [&]() {
        unsigned short s0[8], s1[8], s2[8];
        #pragma unroll
        for (int j = 0; j < 8; ++j) split3(bv[j], s0[j], s1[j], s2[j]);
        pack_store(&Bs[0*2 + bwc][bsub][bln][0], s0);
        pack_store(&Bs[1*2 + bwc][bsub][bln][0], s1);
        pack_store(&Bs[2*2 + bwc][bsub][bln][0], s2);
    };

    const short8v* Af = (const short8v*)As;
    const short8v* Bf = (const short8v*)Bs;

    loadA(0); loadB(0);
    for (int k0 = 0; k0 < 576; k0 += 32) {
        storeA(); storeB();
        __syncthreads();
        if (k0 + 32 < 576) { loadA(k0 + 32); loadB(k0 + 32); }
        #pragma unroll
        for (int sub = 0; sub < 2; ++sub) {
            short8v b0 = Bf[((0*2 + wc)*2 + sub)*64 + lane];
            short8v b1 = Bf[((1*2 + wc)*2 + sub)*64 + lane];
            short8v b2 = Bf[((2*2 + wc)*2 + sub)*64 + lane];
            short8v a0 = Af[((0*3 + 0)*2 + wr)*128 + sub*64 + lane];
            short8v a1 = Af[((0*3 + 1)*2 + wr)*128 + sub*64 + lane];
            short8v a2 = Af[((0*3 + 2)*2 + wr)*128 + sub*64 + lane];
            acc0 = __builtin_amdgcn_mfma_f32_32x32x16_bf16(a0, b0, acc0, 0, 0, 0);
            acc0 = __builtin_amdgcn_mfma_f32_32x32x16_bf16(a0, b1, acc0, 0, 0, 0);
            acc0 = __builtin_amdgcn_mfma_f32_32x32x16_bf16(a1, b0, acc0, 0, 0, 0);
            acc0 = __builtin_amdgcn_mfma_f32_32x32x16_bf16(a1, b1, acc0, 0, 0, 0);
            acc0 = __builtin_amdgcn_mfma_f32_32x32x16_bf16(a0, b2, acc0, 0, 0, 0);
            acc0 = __builtin_amdgcn_mfma_f32_32x32x16_bf16(a2, b0, acc0, 0, 0, 0);
            a0 = Af[((1*3 + 0)*2 + wr)*128 + sub*64 + lane];
            a1 = Af[((1*3 + 1)*2 + wr)*128 + sub*64 + lane];
            a2 = Af[((1*3 + 2)*2 + wr)*128 + sub*64 + lane];
            acc1 = __builtin_amdgcn_mfma_f32_32x32x16_bf16(a0, b0, acc1, 0, 0, 0);
            acc1 = __builtin_amdgcn_mfma_f32_32x32x16_bf16(a0, b1, acc1, 0, 0, 0);
            acc1 = __builtin_amdgcn_mfma_f32_32x32x16_bf16(a1, b0, acc1, 0, 0, 0);
            acc1 = __builtin_amdgcn_mfma_f32_32x32x16_bf16(a1, b1, acc1, 0, 0, 0);
            acc1 = __builtin_amdgcn_mfma_f32_32x32x16_bf16(a0, b2, acc1, 0, 0, 0);
            acc1 = __builtin_amdgcn_mfma_f32_32x32x16_bf16(a2, b0, acc1, 0, 0, 0);
        }
        __syncthreads();
    }

    int colg = n0 + 32*wc + (lane & 31);
    int rowb = m0 + 32*wr + 4*(lane >> 5);
    #pragma unroll
    for (int reg = 0; reg < 16; ++reg) {
        int row = rowb + (reg & 3) + 8*(reg >> 2);
        C0[(size_t)row * 576 + colg] = acc0[reg];
        C1[(size_t)row * 576 + colg] = acc1[reg];
    }
}

// ---------------------------------------------------------------------------
// mm_abt_mfma: final AKA partial GEMM (C = A @ B^T per plane), r5-verified.
// ---------------------------------------------------------------------------
__global__ __launch_bounds__(256, 2)
void mm_abt_mfma(const float* __restrict__ Aall, const float* __restrict__ Ball,
                 float* __restrict__ Call, long sA, long sB, long sC, long sSplit)
{
    int p = blockIdx.x;
    int ir = 0;
    while (p >= ir + 1) { p -= ir + 1; ir++; }
    int my = ir, nx = p;
    int zz = blockIdx.z;
    int sp = zz & 3, b = zz >> 2;
    const float* A = Aall + (size_t)b * sA + (size_t)sp * N2;   // [m][k]
    const float* B = Ball + (size_t)b * sB + (size_t)sp * N2;   // [n][k]
    float* Cp = Call + (size_t)b * sC + (size_t)sp * sSplit;
    int m0 = my * 64, n0 = nx * 64;

    __shared__ __align__(16) unsigned short Fr[12][2][64][8];   // 24 KB

    int tid  = threadIdx.x;
    int lane = tid & 63;
    int wid  = tid >> 6;
    int wr = wid >> 1, wc = wid & 1;

    f32x16 acc;
    #pragma unroll
    for (int i = 0; i < 16; ++i) acc[i] = 0.0f;

    int sel  = tid >> 7;          // 0: stage A, 1: stage B
    int q2   = tid & 127;
    int r    = q2 >> 1;           // row 0..63 (m for A, n for B)
    int ssub = q2 & 1;            // 16-k half
    const float* Src = sel ? B : A;
    int base0 = sel ? n0 : m0;
    int rreg = r >> 5;
    int rln  = r & 31;

    float av[16];

    auto loadF = [&](int k0) {
        const float* pp = Src + (size_t)(base0 + r) * 576 + k0 + ssub * 16;
        float4 t0 = *(const float4*)(pp);
        float4 t1 = *(const float4*)(pp + 4);
        float4 t2 = *(const float4*)(pp + 8);
        float4 t3 = *(const float4*)(pp + 12);
        av[0]=t0.x;  av[1]=t0.y;  av[2]=t0.z;  av[3]=t0.w;
        av[4]=t1.x;  av[5]=t1.y;  av[6]=t1.z;  av[7]=t1.w;
        av[8]=t2.x;  av[9]=t2.y;  av[10]=t2.z; av[11]=t2.w;
        av[12]=t3.x; av[13]=t3.y; av[14]=t3.z; av[15]=t3.w;
    };
    auto storeF = [&]() {
        unsigned short s0[16], s1[16], s2[16];
        #pragma unroll
        for (int j = 0; j < 16; ++j) split3(av[j], s0[j], s1[j], s2[j]);
        #pragma unroll
        for (int h = 0; h < 2; ++h) {
            int ln = rln + 32 * h;
            pack_store(&Fr[sel*6 + 0*2 + rreg][ssub][ln][0], &s0[8*h]);
            pack_store(&Fr[sel*6 + 1*2 + rreg][ssub][ln][0], &s1[8*h]);
            pack_store(&Fr[sel*6 + 2*2 + rreg][ssub][ln][0], &s2[8*h]);
        }
    };

    const short8v* Ff = (const short8v*)Fr;   // region*128 + sub*64 + lane

    loadF(0);
    for (int k0 = 0; k0 < 576; k0 += 32) {
        storeF();
        __syncthreads();
        if (k0 + 32 < 576) loadF(k0 + 32);
        #pragma unroll
        for (int sub = 0; sub < 2; ++sub) {
            short8v a0 = Ff[((0*2 + wr)*2 + sub)*64 + lane];
            short8v a1 = Ff[((1*2 + wr)*2 + sub)*64 + lane];
            short8v a2 = Ff[((2*2 + wr)*2 + sub)*64 + lane];
            short8v b0 = Ff[((6 + 0*2 + wc)*2 + sub)*64 + lane];
            short8v b1 = Ff[((6 + 1*2 + wc)*2 + sub)*64 + lane];
            short8v b2 = Ff[((6 + 2*2 + wc)*2 + sub)*64 + lane];
            acc = __builtin_amdgcn_mfma_f32_32x32x16_bf16(a0, b0, acc, 0, 0, 0);
            acc = __builtin_amdgcn_mfma_f32_32x32x16_bf16(a0, b1, acc, 0, 0, 0);
            acc = __builtin_amdgcn_mfma_f32_32x32x16_bf16(a1, b0, acc, 0, 0, 0);
            acc = __builtin_amdgcn_mfma_f32_32x32x16_bf16(a1, b1, acc, 0, 0, 0);
            acc = __builtin_amdgcn_mfma_f32_32x32x16_bf16(a0, b2, acc, 0, 0, 0);
            acc = __builtin_amdgcn_mfma_f32_32x32x16_bf16(a2, b0, acc, 0, 0, 0);
        }
        __syncthreads();
    }

    int colg = n0 + 32*wc + (lane & 31);
    int rowb = m0 + 32*wr + 4*(lane >> 5);
    #pragma unroll
    for (int reg = 0; reg < 16; ++reg) {
        int row = rowb + (reg & 3) + 8*(reg >> 2);
        Cp[(size_t)row * 576 + colg] = acc[reg];
    }
}

// ---------------------------------------------------------------------------
// mm_ata_mfma (r6-verified): Kinv = Linv^T @ Linv, symmetric lower + mirror.
// ---------------------------------------------------------------------------
__global__ __launch_bounds__(256, 2)
void mm_ata_mfma(const float* __restrict__ Lg, float* __restrict__ C,
                 long sA, long sC)
{
    int p = blockIdx.x;
    int ir = 0;
    while (p >= ir + 1) { p -= ir + 1; ir++; }
    int my = ir, nx = p;
    int b = blockIdx.z;
    const float* A = Lg + (size_t)b * sA;    // Linv, [k][col] row-major in k
    float* Cb = C + (size_t)b * sC;
    int m0 = my * 64, n0 = nx * 64;
    int kBeg = m0;                           // my >= nx

    __shared__ __align__(16) unsigned short Fr[12][2][64][8];   // 24 KB

    int tid  = threadIdx.x;
    int lane = tid & 63;
    int wid  = tid >> 6;
    int wr = wid >> 1, wc = wid & 1;

    f32x16 acc;
    #pragma unroll
    for (int i = 0; i < 16; ++i) acc[i] = 0.0f;

    int sel  = tid >> 7;          // 0: A-frag (m cols), 1: B-frag (n cols)
    int q2   = tid & 127;
    int col  = q2 & 63;           // coalesced: lanes 0..63 -> consecutive cols
    int ssub = q2 >> 6;           // 16-k half
    int c0base = sel ? n0 : m0;
    int rreg = col >> 5;
    int rln  = col & 31;

    float av[16];

    auto loadF = [&](int k0) {
        const float* pp = A + (size_t)(k0 + ssub * 16) * 576 + c0base + col;
        #pragma unroll
        for (int j = 0; j < 16; ++j) av[j] = pp[(size_t)j * 576];
    };
    auto storeF = [&]() {
        unsigned short s0[16], s1[16], s2[16];
        #pragma unroll
        for (int j = 0; j < 16; ++j) split3(av[j], s0[j], s1[j], s2[j]);
        #pragma unroll
        for (int h = 0; h < 2; ++h) {
            int ln = rln + 32 * h;
            pack_store(&Fr[sel*6 + 0*2 + rreg][ssub][ln][0], &s0[8*h]);
            pack_store(&Fr[sel*6 + 1*2 + rreg][ssub][ln][0], &s1[8*h]);
            pack_store(&Fr[sel*6 + 2*2 + rreg][ssub][ln][0], &s2[8*h]);
        }
    };

    const short8v* Ff = (const short8v*)Fr;

    loadF(kBeg);
    for (int k0 = kBeg; k0 < 576; k0 += 32) {
        storeF();
        __syncthreads();
        if (k0 + 32 < 576) loadF(k0 + 32);
        #pragma unroll
        for (int sub = 0; sub < 2; ++sub) {
            short8v a0 = Ff[((0*2 + wr)*2 + sub)*64 + lane];
            short8v a1 = Ff[((1*2 + wr)*2 + sub)*64 + lane];
            short8v a2 = Ff[((2*2 + wr)*2 + sub)*64 + lane];
            short8v b0 = Ff[((6 + 0*2 + wc)*2 + sub)*64 + lane];
            short8v b1 = Ff[((6 + 1*2 + wc)*2 + sub)*64 + lane];
            short8v b2 = Ff[((6 + 2*2 + wc)*2 + sub)*64 + lane];
            acc = __builtin_amdgcn_mfma_f32_32x32x16_bf16(a0, b0, acc, 0, 0, 0);
            acc = __builtin_amdgcn_mfma_f32_32x32x16_bf16(a0, b1, acc, 0, 0, 0);
            acc = __builtin_amdgcn_mfma_f32_32x32x16_bf16(a1, b0, acc, 0, 0, 0);
            acc = __builtin_amdgcn_mfma_f32_32x32x16_bf16(a1, b1, acc, 0, 0, 0);
            acc = __builtin_amdgcn_mfma_f32_32x32x16_bf16(a0, b2, acc, 0, 0, 0);
            acc = __builtin_amdgcn_mfma_f32_32x32x16_bf16(a2, b0, acc, 0, 0, 0);
        }
        __syncthreads();
    }

    int colg = n0 + 32*wc + (lane & 31);
    int rowb = m0 + 32*wr + 4*(lane >> 5);
    #pragma unroll
    for (int reg = 0; reg < 16; ++reg) {
        int row = rowb + (reg & 3) + 8*(reg >> 2);
        float v = acc[reg];
        Cb[(size_t)row * 576 + colg] = v;
        Cb[(size_t)colg * 576 + row] = v;    // mirror (bit-identical value)
    }
}

// ---------------------------------------------------------------------------
// mm_ab_mfma (r6-verified): iW = Kin @ Kinv, direct write.
// ---------------------------------------------------------------------------
__global__ __launch_bounds__(256, 2)
void mm_ab_mfma(const float* __restrict__ Aall, const float* __restrict__ Ball,
                float* __restrict__ Call, long sA, long sB, long sC)
{
    int nx = blockIdx.x % 9, my = blockIdx.x / 9;
    int b = blockIdx.z;
    const float* A = Aall + (size_t)b * sA;   // [m][k]
    const float* B = Ball + (size_t)b * sB;   // [k][n]
    float* Cb = Call + (size_t)b * sC;
    int m0 = my * 64, n0 = nx * 64;

    __shared__ __align__(16) unsigned short Fr[12][2][64][8];   // 24 KB

    int tid  = threadIdx.x;
    int lane = tid & 63;
    int wid  = tid >> 6;
    int wr = wid >> 1, wc = wid & 1;

    f32x16 acc;
    #pragma unroll
    for (int i = 0; i < 16; ++i) acc[i] = 0.0f;

    int sel  = tid >> 7;          // 0: A rows (float4), 1: B cols (scalar)
    int q2   = tid & 127;
    int ar   = q2 >> 1;
    int asub = q2 & 1;
    int areg = ar >> 5, aln = ar & 31;
    int bcol = q2 & 63;
    int bssub = q2 >> 6;
    int breg = bcol >> 5, brln = bcol & 31;

    float av[16];

    auto loadF = [&](int k0) {
        if (sel == 0) {
            const float* pp = A + (size_t)(m0 + ar) * 576 + k0 + asub * 16;
            float4 t0 = *(const float4*)(pp);
            float4 t1 = *(const float4*)(pp + 4);
            float4 t2 = *(const float4*)(pp + 8);
            float4 t3 = *(const float4*)(pp + 12);
            av[0]=t0.x;  av[1]=t0.y;  av[2]=t0.z;  av[3]=t0.w;
            av[4]=t1.x;  av[5]=t1.y;  av[6]=t1.z;  av[7]=t1.w;
            av[8]=t2.x;  av[9]=t2.y;  av[10]=t2.z; av[11]=t2.w;
            av[12]=t3.x; av[13]=t3.y; av[14]=t3.z; av[15]=t3.w;
        } else {
            const float* pp = B + (size_t)(k0 + bssub * 16) * 576 + n0 + bcol;
            #pragma unroll
            for (int j = 0; j < 16; ++j) av[j] = pp[(size_t)j * 576];
        }
    };
    auto storeF = [&]() {
        unsigned short s0[16], s1[16], s2[16];
        #pragma unroll
        for (int j = 0; j < 16; ++j) split3(av[j], s0[j], s1[j], s2[j]);
        int reg0 = sel ? (6 + 0*2 + breg) : (0*2 + areg);
        int reg1 = sel ? (6 + 1*2 + breg) : (1*2 + areg);
        int reg2 = sel ? (6 + 2*2 + breg) : (2*2 + areg);
        int sb   = sel ? bssub : asub;
        int ln0  = sel ? brln : aln;
        #pragma unroll
        for (int h = 0; h < 2; ++h) {
            int ln = ln0 + 32 * h;
            pack_store(&Fr[reg0][sb][ln][0], &s0[8*h]);
            pack_store(&Fr[reg1][sb][ln][0], &s1[8*h]);
            pack_store(&Fr[reg2][sb][ln][0], &s2[8*h]);
        }
    };

    const short8v* Ff = (const short8v*)Fr;

    loadF(0);
    for (int k0 = 0; k0 < 576; k0 += 32) {
        storeF();
        __syncthreads();
        if (k0 + 32 < 576) loadF(k0 + 32);
        #pragma unroll
        for (int sub = 0; sub < 2; ++sub) {
            short8v a0 = Ff[((0*2 + wr)*2 + sub)*64 + lane];
            short8v a1 = Ff[((1*2 + wr)*2 + sub)*64 + lane];
            short8v a2 = Ff[((2*2 + wr)*2 + sub)*64 + lane];
            short8v b0 = Ff[((6 + 0*2 + wc)*2 + sub)*64 + lane];
            short8v b1 = Ff[((6 + 1*2 + wc)*2 + sub)*64 + lane];
            short8v b2 = Ff[((6 + 2*2 + wc)*2 + sub)*64 + lane];
            acc = __builtin_amdgcn_mfma_f32_32x32x16_bf16(a0, b0, acc, 0, 0, 0);
            acc = __builtin_amdgcn_mfma_f32_32x32x16_bf16(a0, b1, acc, 0, 0, 0);
            acc = __builtin_amdgcn_mfma_f32_32x32x16_bf16(a1, b0, acc, 0, 0, 0);
            acc = __builtin_amdgcn_mfma_f32_32x32x16_bf16(a1, b1, acc, 0, 0, 0);
            acc = __builtin_amdgcn_mfma_f32_32x32x16_bf16(a0, b2, acc, 0, 0, 0);
            acc = __builtin_amdgcn_mfma_f32_32x32x16_bf16(a2, b0, acc, 0, 0, 0);
        }
        __syncthreads();
    }

    int colg = n0 + 32*wc + (lane & 31);
    int rowb = m0 + 32*wr + 4*(lane >> 5);
    #pragma unroll
    for (int reg = 0; reg < 16; ++reg) {
        int row = rowb + (reg & 3) + 8*(reg >> 2);
        Cb[(size_t)row * 576 + colg] = acc[reg];
    }
}

// ---------------------------------------------------------------------------
// batched tiled matmul, 64x64 C-tile, 256 threads (4x4 micro), reg prefetch.
// (still used for the small skinny GEMMs: sol_mean, opimean)
// ---------------------------------------------------------------------------
template<int TA, int TB, int SK, int TRI, int SWZ, int EPIB, int TRIC>
__global__ __launch_bounds__(256)
void mm_kernel(const float* __restrict__ Aall, const float* __restrict__ Ball,
               float* __restrict__ Call,
               int M, int N, int K, int planeK,
               int lda, int ldb, int ldc,
               long sA, long sB, long sC, long pA, long pB, long sSplit, int MT)
{
    int nx, my, zz;
    if (TRIC) {
        int p = blockIdx.x;
        int ir = 0;
        while (p >= ir + 1) { p -= ir + 1; ir++; }
        my = ir; nx = p; zz = blockIdx.z;
    } else if (SWZ) {
        int id = blockIdx.x;
        int x8 = id & 7;
        int q  = id >> 3;
        nx = q % 9;
        int band = x8 + 8 * (q / 9);
        if (band >= MT * 4 * SK) return;
        my = band % MT;
        zz = band / MT;
    } else { nx = blockIdx.x; my = blockIdx.y; zz = blockIdx.z; }
    int sp = (SK > 1) ? (zz % SK) : 0;
    int b  = (SK > 1) ? (zz / SK) : zz;
    const float* A = Aall + (size_t)b * sA;
    const float* B = Ball + (size_t)b * sB;
    float* C = Call + (size_t)b * sC + (size_t)sp * sSplit;
    int n0 = nx * 64;
    int m0 = my * 64;

    __shared__ float As[16][68];
    __shared__ float Bs[16][68];

    int tid = threadIdx.x;
    int tx = tid & 15, ty = tid >> 4;

    float acc[4][4] = {};
    bool mFull = (m0 + 64 <= M);
    bool nFull = (n0 + 64 <= N);

    int triBeg = 0;
    if (TRI) { int mx = (m0 > n0 ? m0 : n0); triBeg = mx & ~15; }
    int kBeg = triBeg, kEnd = K;
    if (SK > 1) {
        int len = K - triBeg;
        int chunk = ((len / SK) + 15) & ~15;
        kBeg = triBeg + sp * chunk;
        if (kBeg > K) kBeg = K;
        kEnd = (sp == SK - 1) ? K : (kBeg + chunk < K ? kBeg + chunk : K);
    }

    float avr[4];
    float bvr[4];

    auto loadA = [&](int k0) {
        int plane = k0 / planeK;
        int koff  = k0 - plane * planeK;
        if (TA == 0) {
            const float* Ab = A + (size_t)pA * plane;
            int r = tid >> 2, c4 = (tid & 3) * 4;
            int gm = m0 + r;
            if (mFull || gm < M) {
                float4 t = *(const float4*)(Ab + (size_t)gm * lda + koff + c4);
                avr[0]=t.x; avr[1]=t.y; avr[2]=t.z; avr[3]=t.w;
            } else { avr[0]=avr[1]=avr[2]=avr[3]=0.0f; }
        } else {
            int r = tid >> 4, c4 = (tid & 15) * 4;
            const float* p = A + (size_t)(koff + r) * lda + m0 + c4;
            if (mFull) {
                float4 t = *(const float4*)p;
                avr[0]=t.x; avr[1]=t.y; avr[2]=t.z; avr[3]=t.w;
            } else {
                #pragma unroll
                for (int jj = 0; jj < 4; ++jj)
                    avr[jj] = (m0 + c4 + jj < M) ? p[jj] : 0.0f;
            }
        }
    };
    auto storeA = [&]() {
        if (TA == 0) {
            int r = tid >> 2, c4 = (tid & 3) * 4;
            #pragma unroll
            for (int q = 0; q < 4; ++q) As[c4+q][r] = avr[q];
        } else {
            int r = tid >> 4, c4 = (tid & 15) * 4;
            #pragma unroll
            for (int q = 0; q < 4; ++q) As[r][c4+q] = avr[q];
        }
    };
    auto loadB = [&](int k0) {
        int plane = k0 / planeK;
        int koff  = k0 - plane * planeK;
        if (TB == 0) {
            int r = tid >> 4, c4 = (tid & 15) * 4;
            const float* p = B + (size_t)(koff + r) * ldb + n0 + c4;
            if (nFull) {
                float4 t = *(const float4*)p;
                bvr[0]=t.x; bvr[1]=t.y; bvr[2]=t.z; bvr[3]=t.w;
            } else {
                #pragma unroll
                for (int jj = 0; jj < 4; ++jj)
                    bvr[jj] = (n0 + c4 + jj < N) ? p[jj] : 0.0f;
            }
            if (EPIB) {
                int gk = koff + r;
                #pragma unroll
                for (int jj = 0; jj < 4; ++jj)
                    if (gk == n0 + c4 + jj) bvr[jj] -= 1.0f;
            }
        } else {
            const float* Bb = B + (size_t)pB * plane;
            int r = tid >> 2, c4 = (tid & 3) * 4;
            int gp = n0 + r;
            if (nFull || gp < N) {
                float4 t = *(const float4*)(Bb + (size_t)gp * ldb + koff + c4);
                bvr[0]=t.x; bvr[1]=t.y; bvr[2]=t.z; bvr[3]=t.w;
            } else { bvr[0]=bvr[1]=bvr[2]=bvr[3]=0.0f; }
        }
    };
    auto storeB = [&]() {
        if (TB == 0) {
            int r = tid >> 4, c4 = (tid & 15) * 4;
            #pragma unroll
            for (int q = 0; q < 4; ++q) Bs[r][c4+q] = bvr[q];
        } else {
            int r = tid >> 2, c4 = (tid & 3) * 4;
            #pragma unroll
            for (int q = 0; q < 4; ++q) Bs[c4+q][r] = bvr[q];
        }
    };

    if (kBeg < kEnd) {
        loadA(kBeg); loadB(kBeg);
        for (int k0 = kBeg; k0 < kEnd; k0 += 16) {
            storeA(); storeB();
            __syncthreads();
            if (k0 + 16 < kEnd) { loadA(k0 + 16); loadB(k0 + 16); }
            #pragma unroll
            for (int kk = 0; kk < 16; ++kk) {
                float a[4], bb[4];
                *(float4*)a  = *(const float4*)&As[kk][ty*4];
                *(float4*)bb = *(const float4*)&Bs[kk][tx*4];
                #pragma unroll
                for (int i = 0; i < 4; ++i)
                    #pragma unroll
                    for (int j = 0; j < 4; ++j)
                        acc[i][j] += a[i] * bb[j];
            }
            __syncthreads();
        }
    }

    #pragma unroll
    for (int i = 0; i < 4; ++i) {
        int gm = m0 + ty*4 + i;
        if (gm >= M) continue;
        #pragma unroll
        for (int j = 0; j < 4; ++j) {
            int gn = n0 + tx*4 + j;
            if (gn >= N) continue;
            C[(size_t)gm * ldc + gn] = acc[i][j];
        }
    }
}

// ---------------------------------------------------------------------------
// symmetric combine: partials valid only for m>=n; prior symmetric; write both
// ---------------------------------------------------------------------------
__global__ void combine_prior4_sym(const float* __restrict__ p0,
                                   const float* __restrict__ xin,
                                   const float* __restrict__ W2g,
                                   float* __restrict__ o, long stride) {
    __shared__ float w[16];
    int tid = threadIdx.x;
    if (tid < 16) w[tid] = W2g[tid];
    __syncthreads();
    int idx = blockIdx.x * 256 + tid;           // over 4*N2
    int b = idx / N2;
    int rem = idx - b * N2;
    int m = rem / NPTS, n = rem - m * NPTS;
    if (m < n) return;
    const float* xb = xin + (size_t)b * NPTS * 2;
    float r0 = xb[m*2+0] - xb[n*2+0];
    float r1 = xb[m*2+1] - xb[n*2+1];
    float u = (r0*r0 + r1*r1) * INVL2;
    float Kv = expf(-0.5f * u);
    float i2 = INVL2 * INVL2;
    float gK0 = r0 * INVL2 * Kv;
    float gK1 = r1 * INVL2 * Kv;
    float lapK = (u - 2.0f) * INVL2 * Kv;
    float gg00 = (INVL2 - r0*r0*i2) * Kv;
    float gg01 = (-r0*r1*i2) * Kv;
    float gg11 = (INVL2 - r1*r1*i2) * Kv;
    float gl0 = r0 * i2 * (4.0f - u) * Kv;
    float gl1 = r1 * i2 * (4.0f - u) * Kv;
    float ll = ((u-2.0f)*(u-2.0f) - 4.0f*u + 4.0f) * i2 * Kv;
    float prior =
          w[0]*Kv + w[1]*gK0 + w[2]*gK1 + w[3]*lapK
        + w[4]*(-gK0) + w[5]*gg00 + w[6]*gg01 + w[7]*gl0
        + w[8]*(-gK1) + w[9]*gg01 + w[10]*gg11 + w[11]*gl1
        + w[12]*lapK + w[13]*(-gl0) + w[14]*(-gl1) + w[15]*ll;
    float v = p0[idx] + p0[idx + stride] + p0[idx + 2*stride] + p0[idx + 3*stride]
            + prior;
    if (m == n) v += 1.1e-4f;
    o[(size_t)b * N2 + (size_t)m * NPTS + n] = v;
    if (m != n)
        o[(size_t)b * N2 + (size_t)n * NPTS + m] = v;
}

// ---------------------------------------------------------------------------
// opiKW2[b][i] = sum_j W2[i][j] * opiK[b][j]  — safe in-place (per-element)
// ---------------------------------------------------------------------------
__global__ void opiw2_k(const float* __restrict__ opiK, const float* __restrict__ W2,
                        float* __restrict__ outB) {
    int idx = blockIdx.x * 256 + threadIdx.x;
    int b = idx / N2;
    int rem = idx - b * N2;
    size_t base = (size_t)b * 4 * N2 + rem;
    float k0 = opiK[base], k1 = opiK[base + N2], k2 = opiK[base + 2*N2], k3 = opiK[base + 3*N2];
    #pragma unroll
    for (int i = 0; i < 4; ++i)
        outB[base + (size_t)i * N2] = W2[i*4+0]*k0 + W2[i*4+1]*k1 + W2[i*4+2]*k2 + W2[i*4+3]*k3;
}

// ---------------------------------------------------------------------------
__global__ __launch_bounds__(256)
void amean_k(const float* __restrict__ opimean, const float* __restrict__ weight,
             const float* __restrict__ bias, float* __restrict__ out) {
    int b = blockIdx.y;
    int m0 = blockIdx.x * 32;
    __shared__ float Wl[64][128];
    __shared__ float om[32][128];
    int tid = threadIdx.x;
    for (int idx = tid; idx < 64*128; idx += 256) Wl[idx / 128][idx & 127] = weight[idx];
    for (int idx = tid; idx < 32*128; idx += 256) {
        int m = idx >> 7, ck = idx & 127, c = ck >> 2, kop = ck & 3;
        om[m][ck] = opimean[((size_t)b * 4 + kop) * NPTS * 32 + (size_t)(m0 + m) * 32 + c];
    }
    __syncthreads();
    int ml = tid >> 3, o0 = (tid & 7) * 8;
    float acc[8] = {};
    for (int ck = 0; ck < 128; ++ck) {
        float v = om[ml][ck];
        #pragma unroll
        for (int q = 0; q < 8; ++q) acc[q] += v * Wl[o0+q][ck];
    }
    #pragma unroll
    for (int q = 0; q < 8; ++q)
        out[4608 + ((size_t)b * NPTS + m0 + ml) * 64 + o0 + q] = acc[q] + bias[o0+q];
}

// ---------------------------------------------------------------------------
static inline int gridSwz(int MT, int Z) { return 8 * 9 * ((MT * Z + 7) / 8); }

extern "C" void kernel_launch(void* const* d_in, const int* in_sizes, int n_in,
                              void* d_out, int out_size, void* d_ws, size_t ws_size,
                              hipStream_t stream) {
    const float* xin    = (const float*)d_in[0];
    const float* meanin = (const float*)d_in[1];
    const float* Kin    = (const float*)d_in[2];
    const float* weight = (const float*)d_in[3];
    const float* bias   = (const float*)d_in[4];
    float* out = (float*)d_out;
    float* ws  = (float*)d_ws;

    const long N2L = N2;
    float* W2      = ws;                       // 16 (pad 64)
    float* LinvKK  = ws + 64;                  // 4*9*4096: diag inverses V
    float* VTKK    = LinvKK + 147456;          // 4*9*4096: V transposed
    float* R1 = VTKK + 147456;                 // 4*N2: Kxx/A; later iW (direct)
    float* R2 = R1 + 4*N2L;                    // 4*N2: Linv; later solm/opim
    float* R3 = R2 + 4*N2L;                    // 4*N2: Kinv (direct)
    float* R4 = R3 + 4*N2L;                    // 16*N2: opiK; later opiKW2 (in-place)
    float* R5 = R4 + 16*N2L;                   // 16*N2: LT (first 4N2, chol); KiO; final partials
    float* R6 = R5 + 16*N2L;                   // 16*N2: H'

    // build_k: Kxx + opiK + fused copy_xout + fused w2 (no memset needed:
    // trinv zero-fills Linv's upper triangle itself)
    build_k<<<dim3((BSZ*N2)/256), dim3(256), 0, stream>>>(
        xin, R1, R4, out, weight, W2);
    // Cholesky: 9 launches. LT panels -> R5 (transposed); V,V^T -> LinvKK/VTKK
    chol_diag0<<<dim3(BSZ), dim3(256), 0, stream>>>(R1, LinvKK, VTKK);
    for (int kb = 0; kb < NT - 1; ++kb) {
        int t = NT - 1 - kb;
        chol_step<<<dim3(t*(t+1)/2, BSZ), dim3(256), 0, stream>>>(
            R1, R5, LinvKK, VTKK, kb);
    }
    // triangular inverse (reg-prefetched staging from LT/VT) -> R2
    trinv_blk<<<dim3(4, NT, BSZ), dim3(256), 0, stream>>>(R5, LinvKK, VTKK, R2);
    // Kinv = Linv^T @ Linv  (bf16x3 MFMA, sym lower tiles + mirror, direct -> R3)
    mm_ata_mfma<<<dim3(45, 1, BSZ), dim3(256), 0, stream>>>(R2, R3, N2L, N2L);
    // sol_mean = Kinv @ meanin  (single dispatch, full K, direct -> R2)
    mm_kernel<0,0,1,0,0,0,0><<<dim3(1,9,BSZ), dim3(256), 0, stream>>>(
        R3, meanin, R2, 576,32,576,576, 576,32,32,
        N2L,18432,18432, 0,0, 0, 9);
    // opimean = opiK @ sol_mean -> R2+73728
    mm_kernel<0,0,1,0,0,0,0><<<dim3(1,36,BSZ), dim3(256), 0, stream>>>(
        R4, R2, R2 + 73728, 2304,32,576,576, 576,32,32,
        4*N2L,18432,73728, 0,0, 0, 9);
    amean_k<<<dim3(18,BSZ), dim3(256), 0, stream>>>(R2 + 73728, weight, bias, out);
    // iW = Kin @ Kinv  (bf16x3 MFMA, direct -> R1, no combine)
    mm_ab_mfma<<<dim3(81, 1, BSZ), dim3(256), 0, stream>>>(
        Kin, R3, R1, N2L, N2L, N2L);
    // KiO = opiK @ Kinv  (bf16x3 MFMA, full-K, direct write -> R5, no combine)
    // (overwrites LT region; trinv already complete on this serial stream)
    mm_p2_mfma<0><<<dim3(gridSwz(18,4)), dim3(256), 0, stream>>>(
        R4, R3, R5, 4*N2L, N2L, 4*N2L);
    // opiKW2 in-place on R4 (opiK no longer needed)
    opiw2_k<<<dim3((BSZ*N2)/256), dim3(256), 0, stream>>>(R4, W2, R4);
    // H' = KiO @ (iW - I)  (bf16x3 MFMA, -I fold) -> R6
    mm_p2_mfma<1><<<dim3(gridSwz(18,4)), dim3(256), 0, stream>>>(
        R5, R1, R6, 4*N2L, N2L, 4*N2L);
    // final AKA partial GEMM — SYMMETRIC lower tiles, MFMA, SK4 = plane-split.
    // partials -> R5 (sC=N2 batch plane, sSplit=4*N2 split plane)
    mm_abt_mfma<<<dim3(45,1,BSZ*4), dim3(256), 0, stream>>>(
        R6, R4, R5, 4*N2L, 4*N2L, N2L, 4*N2L);
    // output 2: combine 4 partials (m>=n) + analytic prior + jitter, mirrored
    combine_prior4_sym<<<dim3(5184), dim3(256), 0, stream>>>(
        R5, xin, W2, out + 152064, 4*N2L);
}

// Round 9
// 888.958 us; speedup vs baseline: 1.0284x; 1.0284x over previous
//
#include <hip/hip_runtime.h>
#include <math.h>

#define NPTS 576
#define N2 331776           // 576*576
#define BSZ 4
#define NB 64               // cholesky block
#define NT 9                // 576/64

#define INVL2 (1.0f/0.29311396f)

typedef __attribute__((ext_vector_type(8))) short short8v;   // 8 bf16 (4 VGPRs)
typedef __attribute__((ext_vector_type(16))) float f32x16;   // MFMA 32x32 acc

// ---------------------------------------------------------------------------
__global__ void copy_xout(const float* __restrict__ xin, float* __restrict__ out) {
    int idx = blockIdx.x * 256 + threadIdx.x;   // 18*256 = 4608 exact
    out[idx] = xin[idx];
}

// ---------------------------------------------------------------------------
// build Kxx (+jitter) and opiK (4 planes) from xin
// ---------------------------------------------------------------------------
__global__ void build_k(const float* __restrict__ xin,
                        float* __restrict__ Kxx, float* __restrict__ opiK) {
    int idx = blockIdx.x * 256 + threadIdx.x;
    int b = idx / N2;
    int rem = idx - b * N2;
    int m = rem / NPTS;
    int nn = rem - m * NPTS;
    const float* xb = xin + (size_t)b * NPTS * 2;
    float xm0 = xb[m*2],  xm1 = xb[m*2+1];
    float xn0 = xb[nn*2], xn1 = xb[nn*2+1];
    float r0 = xm0 - xn0, r1 = xm1 - xn1;
    float u = (r0*r0 + r1*r1) * INVL2;
    float Kv = expf(-0.5f * u);
    Kxx[idx] = Kv + ((m == nn) ? 1e-5f : 0.0f);
    size_t base = (size_t)b * 4 * N2 + rem;
    opiK[base]          = Kv;
    opiK[base + N2]     = -r0 * INVL2 * Kv;
    opiK[base + 2*N2]   = -r1 * INVL2 * Kv;
    opiK[base + 3*N2]   = (u - 2.0f) * INVL2 * Kv;
}

// ---------------------------------------------------------------------------
__global__ void w2_k(const float* __restrict__ w, float* __restrict__ W2) {
    __shared__ float red[256];
    int tid = threadIdx.x;
    int pair = tid & 15;
    int slice = tid >> 4;
    int i = pair >> 2, j = pair & 3;
    float s = 0.0f;
    for (int o = slice * 4; o < slice * 4 + 4; ++o)
        for (int c = 0; c < 32; ++c)
            s += w[o*128 + c*4 + i] * w[o*128 + c*4 + j];
    red[tid] = s;
    __syncthreads();
    if (tid < 16) {
        float t = 0.0f;
        #pragma unroll
        for (int k = 0; k < 16; ++k) t += red[pair + 16*k];
        W2[pair] = t * (1.0f/64.0f);
    }
}

// ---------------------------------------------------------------------------
// factor 64x64 SPD block in T (lower), produce V = T^{-1} (lower).
// r4: panel factor row-per-lane in registers + __shfl (no LDS on the chain).
// r5: diag 16x16 inverse also register+shuffle. Block-solve r0 verbatim.
// ---------------------------------------------------------------------------
__device__ void factor_invert_64(float (*T)[NB+1], float (*V)[NB+1],
                                 float (*tmp)[17], int tid) {
    for (int p = 0; p < 4; ++p) {
        int cp = p * 16;
        if (tid < 64) {
            int r = tid;
            float reg[16];
            #pragma unroll
            for (int q = 0; q < 16; ++q) reg[q] = T[r][cp + q];
            #pragma unroll
            for (int j = 0; j < 16; ++j) {
                int col = cp + j;
                float d2 = __shfl(reg[j], col);          // pivot (pre-sqrt)
                float d = sqrtf(fmaxf(d2, 1e-12f));
                float lr = (r == col) ? d : reg[j] / d;  // junk for r<col, unused
                reg[j] = lr;
                #pragma unroll
                for (int q = j + 1; q < 16; ++q) {
                    float lc = __shfl(lr, cp + q);       // L[cp+q][col]
                    if (r >= cp + q) reg[q] -= lr * lc;
                }
            }
            #pragma unroll
            for (int q = 0; q < 16; ++q) T[r][cp + q] = reg[q];
        }
        __syncthreads();
        int tr = 48 - cp;
        if (tr > 0) {
            for (int idx = tid; idx < tr * tr; idx += 256) {
                int r = cp + 16 + idx / tr;
                int c = cp + 16 + idx % tr;
                if (c <= r) {
                    float s = 0.0f;
                    #pragma unroll
                    for (int k = 0; k < 16; ++k) s += T[r][cp+k] * T[c][cp+k];
                    T[r][c] -= s;
                }
            }
        }
        __syncthreads();
    }
    // diag 16x16 inverses: column-per-lane forward substitution in registers.
    if (tid < 64) {
        int I = tid >> 4, c = tid & 15, base = I * 16;
        float tcol[16];
        #pragma unroll
        for (int i = 0; i < 16; ++i) tcol[i] = T[base + i][base + c];
        float v[16];
        #pragma unroll
        for (int i = 0; i < 16; ++i) {
            float s = (i == c) ? 1.0f : 0.0f;
            #pragma unroll
            for (int k = 0; k < 16; ++k) {
                if (k < i) {                              // compile-time mask
                    float tik = __shfl(tcol[i], base + k);
                    s -= tik * v[k];
                }
            }
            float tii = __shfl(tcol[i], base + i);
            v[i] = s / tii;                               // exact 0 for i<c
        }
        #pragma unroll
        for (int i = 0; i < 16; ++i) V[base + i][base + c] = v[i];
    }
    __syncthreads();
    const int PI[6] = {1,2,3,2,3,3};
    const int PJ[6] = {0,1,2,0,1,0};
    int rr16 = tid >> 4, cc16 = tid & 15;
    for (int p = 0; p < 6; ++p) {
        int I = PI[p], J = PJ[p];
        float s = 0.0f;
        for (int K = J; K < I; ++K)
            #pragma unroll
            for (int t = 0; t < 16; ++t)
                s += T[I*16+rr16][K*16+t] * V[K*16+t][J*16+cc16];
        tmp[rr16][cc16] = s;
        __syncthreads();
        float s2 = 0.0f;
        for (int t = 0; t <= rr16; ++t) s2 += V[I*16+rr16][I*16+t] * tmp[t][cc16];
        __syncthreads();
        V[I*16+rr16][J*16+cc16] = -s2;
        __syncthreads();
    }
}

// ---------------------------------------------------------------------------
__global__ void chol_diag0(const float* __restrict__ A, float* __restrict__ LinvKK) {
    int b = blockIdx.x;
    const float* Ab = A + (size_t)b * N2;
    __shared__ float T[NB][NB+1];
    __shared__ float V[NB][NB+1];
    __shared__ float tmp[16][17];
    int tid = threadIdx.x;
    for (int idx = tid; idx < NB*NB; idx += 256) {
        int r = idx >> 6, c = idx & 63;
        T[r][c] = Ab[(size_t)r * NPTS + c];
        V[r][c] = 0.0f;
    }
    __syncthreads();
    factor_invert_64(T, V, tmp, tid);
    float* Vg = LinvKK + (size_t)b * NT * NB * NB;
    for (int idx = tid; idx < NB*NB; idx += 256) Vg[idx] = V[idx >> 6][idx & 63];
}

// ---------------------------------------------------------------------------
// fused Cholesky step for panel kb. 9 total launches.
// ---------------------------------------------------------------------------
__global__ __launch_bounds__(256)
void chol_step(float* __restrict__ A, float* __restrict__ LL,
               float* __restrict__ LinvKK, int kb) {
    int b = blockIdx.y;
    int p = blockIdx.x;
    int ir = 0;
    while (p >= ir + 1) { p -= ir + 1; ir++; }
    int ib = kb + 1 + ir, jb = kb + 1 + p;
    float* Ab = A + (size_t)b * N2;
    float* LLb = LL + (size_t)b * N2;
    __shared__ float Ai[NB][NB+1];
    __shared__ float Aj[NB][NB+1];
    __shared__ float Vs[NB][NB+1];
    __shared__ float tmp[16][17];
    int tid = threadIdx.x;
    int tx = tid & 15, ty = tid >> 4;
    const float* Vg = LinvKK + ((size_t)b * NT + kb) * NB * NB;
    bool diag = (ib == jb);
    for (int idx = tid; idx < NB*NB; idx += 256) {
        int r = idx >> 6, c = idx & 63;
        Ai[r][c] = Ab[(size_t)(ib*NB + r) * NPTS + kb*NB + c];
        Aj[r][c] = diag ? 0.0f : Ab[(size_t)(jb*NB + r) * NPTS + kb*NB + c];
        Vs[r][c] = Vg[idx];
    }
    float U[4][4];
    #pragma unroll
    for (int i = 0; i < 4; ++i)
        #pragma unroll
        for (int j = 0; j < 4; ++j)
            U[i][j] = Ab[(size_t)(ib*NB + ty*4+i) * NPTS + jb*NB + tx*4+j];
    __syncthreads();
    float Li[4][4] = {}, Lj[4][4] = {};
    for (int k = 0; k < NB; ++k) {
        float a[4], v[4];
        #pragma unroll
        for (int i = 0; i < 4; ++i) a[i] = Ai[ty*4+i][k];
        #pragma unroll
        for (int j = 0; j < 4; ++j) v[j] = Vs[tx*4+j][k];
        #pragma unroll
        for (int i = 0; i < 4; ++i)
            #pragma unroll
            for (int j = 0; j < 4; ++j) Li[i][j] += a[i] * v[j];
        if (!diag) {
            float aj[4];
            #pragma unroll
            for (int i = 0; i < 4; ++i) aj[i] = Aj[ty*4+i][k];
            #pragma unroll
            for (int i = 0; i < 4; ++i)
                #pragma unroll
                for (int j = 0; j < 4; ++j) Lj[i][j] += aj[i] * v[j];
        }
    }
    __syncthreads();
    #pragma unroll
    for (int i = 0; i < 4; ++i)
        #pragma unroll
        for (int j = 0; j < 4; ++j) {
            Ai[ty*4+i][tx*4+j] = Li[i][j];
            Aj[ty*4+i][tx*4+j] = diag ? Li[i][j] : Lj[i][j];
        }
    if (diag) {
        #pragma unroll
        for (int i = 0; i < 4; ++i)
            #pragma unroll
            for (int j = 0; j < 4; ++j)
                LLb[(size_t)(ib*NB + ty*4+i) * NPTS + kb*NB + tx*4+j] = Li[i][j];
    }
    __syncthreads();
    float s[4][4] = {};
    for (int k = 0; k < NB; ++k) {
        float a[4], v[4];
        #pragma unroll
        for (int i = 0; i < 4; ++i) a[i] = Ai[ty*4+i][k];
        #pragma unroll
        for (int j = 0; j < 4; ++j) v[j] = Aj[tx*4+j][k];
        #pragma unroll
        for (int i = 0; i < 4; ++i)
            #pragma unroll
            for (int j = 0; j < 4; ++j) s[i][j] += a[i] * v[j];
    }
    #pragma unroll
    for (int i = 0; i < 4; ++i)
        #pragma unroll
        for (int j = 0; j < 4; ++j) U[i][j] -= s[i][j];
    if (blockIdx.x != 0) {
        #pragma unroll
        for (int i = 0; i < 4; ++i)
            #pragma unroll
            for (int j = 0; j < 4; ++j)
                Ab[(size_t)(ib*NB + ty*4+i) * NPTS + jb*NB + tx*4+j] = U[i][j];
        return;
    }
    __syncthreads();
    #pragma unroll
    for (int i = 0; i < 4; ++i)
        #pragma unroll
        for (int j = 0; j < 4; ++j) Ai[ty*4+i][tx*4+j] = U[i][j];
    for (int idx = tid; idx < NB*NB; idx += 256) Aj[idx >> 6][idx & 63] = 0.0f;
    __syncthreads();
    factor_invert_64(Ai, Aj, tmp, tid);
    float* Vo = LinvKK + ((size_t)b * NT + (kb + 1)) * NB * NB;
    for (int idx = tid; idx < NB*NB; idx += 256) Vo[idx] = Aj[idx >> 6][idx & 63];
}

// ---------------------------------------------------------------------------
// blocked triangular inverse. grid (4 col-splits, 9 block-cols, 4 batch)
// r8 post-mortem: staging-latency fixes (r7 float4-from-LT, r8 reg-prefetch)
// both regressed; the floor is the compute loop's LDS throughput (~1.1us per
// stage x ~40-stage jb=0 chain). This r6 form is the measured optimum.
// ---------------------------------------------------------------------------
__global__ __launch_bounds__(256)
void trinv_blk(const float* __restrict__ L, const float* __restrict__ LinvKK,
               float* __restrict__ Linv) {
    int sp = blockIdx.x, jb = blockIdx.y, b = blockIdx.z;
    const float* Lb = L + (size_t)b * N2;
    float* Xg = Linv + (size_t)b * N2;
    const float* Vg = LinvKK + (size_t)b * NT * NB * NB;
    int c0 = jb * NB + sp * 16;

    __shared__ float LsT[64][72];
    __shared__ float Xc[576][17];
    __shared__ float Ss[64][17];

    int tid = threadIdx.x;
    int tx = tid & 15, ty = tid >> 4;

    {
        const float* Vjj = Vg + (size_t)jb * NB * NB;
        int r = tid >> 2, c4 = (tid & 3) * 4;
        float4 v = *(const float4*)(Vjj + r * NB + sp * 16 + c4);
        Xc[r][c4+0] = v.x; Xc[r][c4+1] = v.y; Xc[r][c4+2] = v.z; Xc[r][c4+3] = v.w;
        *(float4*)(Xg + (size_t)(jb * NB + r) * NPTS + c0 + c4) = v;
    }
    __syncthreads();

    for (int ib = jb + 1; ib < NT; ++ib) {
        float acc[4] = {};
        for (int kb = jb; kb < ib; ++kb) {
            {
                int r = tid >> 2, t0 = (tid & 3) * 16;
                const float* src = Lb + (size_t)(ib * NB + r) * NPTS + kb * NB + t0;
                #pragma unroll
                for (int q = 0; q < 4; ++q) {
                    float4 v = *(const float4*)(src + q * 4);
                    LsT[t0 + q*4 + 0][r] = v.x;
                    LsT[t0 + q*4 + 1][r] = v.y;
                    LsT[t0 + q*4 + 2][r] = v.z;
                    LsT[t0 + q*4 + 3][r] = v.w;
                }
            }
            __syncthreads();
            int xbase = (kb - jb) * 64;
            #pragma unroll 8
            for (int t = 0; t < 64; ++t) {
                float a4[4]; *(float4*)a4 = *(const float4*)&LsT[t][ty*4];
                float xv = Xc[xbase + t][tx];
                #pragma unroll
                for (int i = 0; i < 4; ++i) acc[i] += a4[i] * xv;
            }
            __syncthreads();
        }
        #pragma unroll
        for (int i = 0; i < 4; ++i) Ss[ty*4+i][tx] = acc[i];
        {
            const float* Vii = Vg + (size_t)ib * NB * NB;
            int r = tid >> 2, t0 = (tid & 3) * 16;
            #pragma unroll
            for (int q = 0; q < 4; ++q) {
                float4 v = *(const float4*)(Vii + r * NB + t0 + q * 4);
                LsT[t0 + q*4 + 0][r] = v.x;
                LsT[t0 + q*4 + 1][r] = v.y;
                LsT[t0 + q*4 + 2][r] = v.z;
                LsT[t0 + q*4 + 3][r] = v.w;
            }
        }
        __syncthreads();
        float acc2[4] = {};
        #pragma unroll 8
        for (int t = 0; t < 64; ++t) {
            float a4[4]; *(float4*)a4 = *(const float4*)&LsT[t][ty*4];
            float sv = Ss[t][tx];
            #pragma unroll
            for (int i = 0; i < 4; ++i) acc2[i] += a4[i] * sv;
        }
        int obase = (ib - jb) * 64;
        #pragma unroll
        for (int i = 0; i < 4; ++i) {
            float v = -acc2[i];
            Xc[obase + ty*4 + i][tx] = v;
            Xg[(size_t)(ib * NB + ty*4 + i) * NPTS + c0 + tx] = v;
        }
        __syncthreads();
    }
}

// ---------------------------------------------------------------------------
// bf16x3 split helpers for fp32-precision MFMA GEMM.
// ---------------------------------------------------------------------------
__device__ inline void split3(float v, unsigned short& h0, unsigned short& h1,
                              unsigned short& h2) {
    unsigned u0 = __float_as_uint(v) & 0xffff0000u;
    float f0 = __uint_as_float(u0);
    float r1 = v - f0;                       // exact
    unsigned u1 = __float_as_uint(r1) & 0xffff0000u;
    float f1 = __uint_as_float(u1);
    float r2 = r1 - f1;                      // exact
    h0 = (unsigned short)(u0 >> 16);
    h1 = (unsigned short)(u1 >> 16);
    h2 = (unsigned short)((__float_as_uint(r2) + 0x8000u) >> 16);  // RNE-ish
}

__device__ inline void pack_store(unsigned short* dst, const unsigned short* v) {
    uint4 w;
    w.x = (unsigned)v[0] | ((unsigned)v[1] << 16);
    w.y = (unsigned)v[2] | ((unsigned)v[3] << 16);
    w.z = (unsigned)v[4] | ((unsigned)v[5] << 16);
    w.w = (unsigned)v[6] | ((unsigned)v[7] << 16);
    *(uint4*)dst = w;
}

// ---------------------------------------------------------------------------
// mm_p2_mfma: plane-pair GEMM C[p] = A[p] @ B (bf16x3, 6 MFMAs/product).
// ---------------------------------------------------------------------------
template<int EPIB>
__global__ __launch_bounds__(256, 2)
void mm_p2_mfma(const float* __restrict__ Aall, const float* __restrict__ Ball,
                float* __restrict__ Call, long sA, long sB, long sC)
{
    int id = blockIdx.x;
    int x8 = id & 7, qq = id >> 3;
    int nx = qq % 9;
    int band = x8 + 8 * (qq / 9);
    if (band >= 18 * BSZ) return;
    int t  = band % 18;
    int b  = band / 18;
    int pp = t / 9, my = t % 9;
    const float* A0 = Aall + (size_t)b * sA + (size_t)(pp * 2) * N2;
    const float* A1 = A0 + N2;
    const float* B  = Ball + (size_t)b * sB;
    float* C0 = Call + (size_t)b * sC + (size_t)(pp * 2) * N2;
    float* C1 = C0 + N2;
    int n0 = nx * 64, m0 = my * 64;

    __shared__ __align__(16) unsigned short As[12][2][64][8];   // 24 KB
    __shared__ __align__(16) unsigned short Bs[6][2][64][8];    // 12 KB

    int tid  = threadIdx.x;
    int lane = tid & 63;
    int wid  = tid >> 6;
    int wr = wid >> 1, wc = wid & 1;

    f32x16 acc0, acc1;
    #pragma unroll
    for (int i = 0; i < 16; ++i) { acc0[i] = 0.0f; acc1[i] = 0.0f; }

    int ap   = tid >> 7;
    int aq   = tid & 127;
    int ar   = aq >> 1;
    int asub = aq & 1;
    const float* Apl = ap ? A1 : A0;
    int areg = ar >> 5;
    int aln  = ar & 31;

    int bc   = tid & 63;
    int bkg  = tid >> 6;
    int bsub = bkg >> 1;
    int bln  = (bc & 31) + 32 * (bkg & 1);
    int bwc  = bc >> 5;

    float av[16];
    float bv[8];

    auto loadA = [&](int k0) {
        const float* p = Apl + (size_t)(m0 + ar) * 576 + k0 + asub * 16;
        float4 t0 = *(const float4*)(p);
        float4 t1 = *(const float4*)(p + 4);
        float4 t2 = *(const float4*)(p + 8);
        float4 t3 = *(const float4*)(p + 12);
        av[0]=t0.x;  av[1]=t0.y;  av[2]=t0.z;  av[3]=t0.w;
        av[4]=t1.x;  av[5]=t1.y;  av[6]=t1.z;  av[7]=t1.w;
        av[8]=t2.x;  av[9]=t2.y;  av[10]=t2.z; av[11]=t2.w;
        av[12]=t3.x; av[13]=t3.y; av[14]=t3.z; av[15]=t3.w;
    };
    auto loadB = [&](int k0) {
        const float* p = B + (size_t)(k0 + bkg * 8) * 576 + n0 + bc;
        #pragma unroll
        for (int j = 0; j < 8; ++j) {
            float v = p[(size_t)j * 576];
            if (EPIB) { if (k0 + bkg * 8 + j == n0 + bc) v -= 1.0f; }
            bv[j] = v;
        }
    };
    auto storeA = [&]() {
        unsigned short s0[16], s1[16], s2[16];
        #pragma unroll
        for (int j = 0; j < 16; ++j) split3(av[j], s0[j], s1[j], s2[j]);
        #pragma unroll
        for (int h = 0; h < 2; ++h) {
            int ln = aln + 32 * h;
            pack_store(&As[(ap*3 + 0)*2 + areg][asub][ln][0], &s0[8*h]);
            pack_store(&As[(ap*3 + 1)*2 + areg][asub][ln][0], &s1[8*h]);
            pack_store(&As[(ap*3 + 2)*2 + areg][asub][ln][0], &s2[8*h]);
        }
    };
    auto storeB = [&]() {
        unsigned short s0[8], s1[8], s2[8];
        #pragma unroll
        for (int j = 0; j < 8; ++j) split3(bv[j], s0[j], s1[j], s2[j]);
        pack_store(&Bs[0*2 + bwc][bsub][bln][0], s0);
        pack_store(&Bs[1*2 + bwc][bsub][bln][0], s1);
        pack_store(&Bs[2*2 + bwc][bsub][bln][0], s2);
    };

    const short8v* Af = (const short8v*)As;
    const short8v* Bf = (const short8v*)Bs;

    loadA(0); loadB(0);
    for (int k0 = 0; k0 < 576; k0 += 32) {
        storeA(); storeB();
        __syncthreads();
        if (k0 + 32 < 576) { loadA(k0 + 32); loadB(k0 + 32); }
        #pragma unroll
        for (int sub = 0; sub < 2; ++sub) {
            short8v b0 = Bf[((0*2 + wc)*2 + sub)*64 + lane];
            short8v b1 = Bf[((1*2 + wc)*2 + sub)*64 + lane];
            short8v b2 = Bf[((2*2 + wc)*2 + sub)*64 + lane];
            short8v a0 = Af[((0*3 + 0)*2 + wr)*128 + sub*64 + lane];
            short8v a1 = Af[((0*3 + 1)*2 + wr)*128 + sub*64 + lane];
            short8v a2 = Af[((0*3 + 2)*2 + wr)*128 + sub*64 + lane];
            acc0 = __builtin_amdgcn_mfma_f32_32x32x16_bf16(a0, b0, acc0, 0, 0, 0);
            acc0 = __builtin_amdgcn_mfma_f32_32x32x16_bf16(a0, b1, acc0, 0, 0, 0);
            acc0 = __builtin_amdgcn_mfma_f32_32x32x16_bf16(a1, b0, acc0, 0, 0, 0);
            acc0 = __builtin_amdgcn_mfma_f32_32x32x16_bf16(a1, b1, acc0, 0, 0, 0);
            acc0 = __builtin_amdgcn_mfma_f32_32x32x16_bf16(a0, b2, acc0, 0, 0, 0);
            acc0 = __builtin_amdgcn_mfma_f32_32x32x16_bf16(a2, b0, acc0, 0, 0, 0);
            a0 = Af[((1*3 + 0)*2 + wr)*128 + sub*64 + lane];
            a1 = Af[((1*3 + 1)*2 + wr)*128 + sub*64 + lane];
            a2 = Af[((1*3 + 2)*2 + wr)*128 + sub*64 + lane];
            acc1 = __builtin_amdgcn_mfma_f32_32x32x16_bf16(a0, b0, acc1, 0, 0, 0);
            acc1 = __builtin_amdgcn_mfma_f32_32x32x16_bf16(a0, b1, acc1, 0, 0, 0);
            acc1 = __builtin_amdgcn_mfma_f32_32x32x16_bf16(a1, b0, acc1, 0, 0, 0);
            acc1 = __builtin_amdgcn_mfma_f32_32x32x16_bf16(a1, b1, acc1, 0, 0, 0);
            acc1 = __builtin_amdgcn_mfma_f32_32x32x16_bf16(a0, b2, acc1, 0, 0, 0);
            acc1 = __builtin_amdgcn_mfma_f32_32x32x16_bf16(a2, b0, acc1, 0, 0, 0);
        }
        __syncthreads();
    }

    int colg = n0 + 32*wc + (lane & 31);
    int rowb = m0 + 32*wr + 4*(lane >> 5);
    #pragma unroll
    for (int reg = 0; reg < 16; ++reg) {
        int row = rowb + (reg & 3) + 8*(reg >> 2);
        C0[(size_t)row * 576 + colg] = acc0[reg];
        C1[(size_t)row * 576 + colg] = acc1[reg];
    }
}

// ---------------------------------------------------------------------------
// mm_abt_mfma: final AKA partial GEMM (C = A @ B^T per plane), r5-verified.
// ---------------------------------------------------------------------------
__global__ __launch_bounds__(256, 2)
void mm_abt_mfma(const float* __restrict__ Aall, const float* __restrict__ Ball,
                 float* __restrict__ Call, long sA, long sB, long sC, long sSplit)
{
    int p = blockIdx.x;
    int ir = 0;
    while (p >= ir + 1) { p -= ir + 1; ir++; }
    int my = ir, nx = p;
    int zz = blockIdx.z;
    int sp = zz & 3, b = zz >> 2;
    const float* A = Aall + (size_t)b * sA + (size_t)sp * N2;   // [m][k]
    const float* B = Ball + (size_t)b * sB + (size_t)sp * N2;   // [n][k]
    float* Cp = Call + (size_t)b * sC + (size_t)sp * sSplit;
    int m0 = my * 64, n0 = nx * 64;

    __shared__ __align__(16) unsigned short Fr[12][2][64][8];   // 24 KB

    int tid  = threadIdx.x;
    int lane = tid & 63;
    int wid  = tid >> 6;
    int wr = wid >> 1, wc = wid & 1;

    f32x16 acc;
    #pragma unroll
    for (int i = 0; i < 16; ++i) acc[i] = 0.0f;

    int sel  = tid >> 7;          // 0: stage A, 1: stage B
    int q2   = tid & 127;
    int r    = q2 >> 1;           // row 0..63 (m for A, n for B)
    int ssub = q2 & 1;            // 16-k half
    const float* Src = sel ? B : A;
    int base0 = sel ? n0 : m0;
    int rreg = r >> 5;
    int rln  = r & 31;

    float av[16];

    auto loadF = [&](int k0) {
        const float* pp = Src + (size_t)(base0 + r) * 576 + k0 + ssub * 16;
        float4 t0 = *(const float4*)(pp);
        float4 t1 = *(const float4*)(pp + 4);
        float4 t2 = *(const float4*)(pp + 8);
        float4 t3 = *(const float4*)(pp + 12);
        av[0]=t0.x;  av[1]=t0.y;  av[2]=t0.z;  av[3]=t0.w;
        av[4]=t1.x;  av[5]=t1.y;  av[6]=t1.z;  av[7]=t1.w;
        av[8]=t2.x;  av[9]=t2.y;  av[10]=t2.z; av[11]=t2.w;
        av[12]=t3.x; av[13]=t3.y; av[14]=t3.z; av[15]=t3.w;
    };
    auto storeF = [&]() {
        unsigned short s0[16], s1[16], s2[16];
        #pragma unroll
        for (int j = 0; j < 16; ++j) split3(av[j], s0[j], s1[j], s2[j]);
        #pragma unroll
        for (int h = 0; h < 2; ++h) {
            int ln = rln + 32 * h;
            pack_store(&Fr[sel*6 + 0*2 + rreg][ssub][ln][0], &s0[8*h]);
            pack_store(&Fr[sel*6 + 1*2 + rreg][ssub][ln][0], &s1[8*h]);
            pack_store(&Fr[sel*6 + 2*2 + rreg][ssub][ln][0], &s2[8*h]);
        }
    };

    const short8v* Ff = (const short8v*)Fr;   // region*128 + sub*64 + lane

    loadF(0);
    for (int k0 = 0; k0 < 576; k0 += 32) {
        storeF();
        __syncthreads();
        if (k0 + 32 < 576) loadF(k0 + 32);
        #pragma unroll
        for (int sub = 0; sub < 2; ++sub) {
            short8v a0 = Ff[((0*2 + wr)*2 + sub)*64 + lane];
            short8v a1 = Ff[((1*2 + wr)*2 + sub)*64 + lane];
            short8v a2 = Ff[((2*2 + wr)*2 + sub)*64 + lane];
            short8v b0 = Ff[((6 + 0*2 + wc)*2 + sub)*64 + lane];
            short8v b1 = Ff[((6 + 1*2 + wc)*2 + sub)*64 + lane];
            short8v b2 = Ff[((6 + 2*2 + wc)*2 + sub)*64 + lane];
            acc = __builtin_amdgcn_mfma_f32_32x32x16_bf16(a0, b0, acc, 0, 0, 0);
            acc = __builtin_amdgcn_mfma_f32_32x32x16_bf16(a0, b1, acc, 0, 0, 0);
            acc = __builtin_amdgcn_mfma_f32_32x32x16_bf16(a1, b0, acc, 0, 0, 0);
            acc = __builtin_amdgcn_mfma_f32_32x32x16_bf16(a1, b1, acc, 0, 0, 0);
            acc = __builtin_amdgcn_mfma_f32_32x32x16_bf16(a0, b2, acc, 0, 0, 0);
            acc = __builtin_amdgcn_mfma_f32_32x32x16_bf16(a2, b0, acc, 0, 0, 0);
        }
        __syncthreads();
    }

    int colg = n0 + 32*wc + (lane & 31);
    int rowb = m0 + 32*wr + 4*(lane >> 5);
    #pragma unroll
    for (int reg = 0; reg < 16; ++reg) {
        int row = rowb + (reg & 3) + 8*(reg >> 2);
        Cp[(size_t)row * 576 + colg] = acc[reg];
    }
}

// ---------------------------------------------------------------------------
// mm_ata_mfma (r6-verified): Kinv = Linv^T @ Linv, symmetric lower + mirror.
// ---------------------------------------------------------------------------
__global__ __launch_bounds__(256, 2)
void mm_ata_mfma(const float* __restrict__ Lg, float* __restrict__ C,
                 long sA, long sC)
{
    int p = blockIdx.x;
    int ir = 0;
    while (p >= ir + 1) { p -= ir + 1; ir++; }
    int my = ir, nx = p;
    int b = blockIdx.z;
    const float* A = Lg + (size_t)b * sA;    // Linv, [k][col] row-major in k
    float* Cb = C + (size_t)b * sC;
    int m0 = my * 64, n0 = nx * 64;
    int kBeg = m0;                           // my >= nx

    __shared__ __align__(16) unsigned short Fr[12][2][64][8];   // 24 KB

    int tid  = threadIdx.x;
    int lane = tid & 63;
    int wid  = tid >> 6;
    int wr = wid >> 1, wc = wid & 1;

    f32x16 acc;
    #pragma unroll
    for (int i = 0; i < 16; ++i) acc[i] = 0.0f;

    int sel  = tid >> 7;          // 0: A-frag (m cols), 1: B-frag (n cols)
    int q2   = tid & 127;
    int col  = q2 & 63;           // coalesced: lanes 0..63 -> consecutive cols
    int ssub = q2 >> 6;           // 16-k half
    int c0base = sel ? n0 : m0;
    int rreg = col >> 5;
    int rln  = col & 31;

    float av[16];

    auto loadF = [&](int k0) {
        const float* pp = A + (size_t)(k0 + ssub * 16) * 576 + c0base + col;
        #pragma unroll
        for (int j = 0; j < 16; ++j) av[j] = pp[(size_t)j * 576];
    };
    auto storeF = [&]() {
        unsigned short s0[16], s1[16], s2[16];
        #pragma unroll
        for (int j = 0; j < 16; ++j) split3(av[j], s0[j], s1[j], s2[j]);
        #pragma unroll
        for (int h = 0; h < 2; ++h) {
            int ln = rln + 32 * h;
            pack_store(&Fr[sel*6 + 0*2 + rreg][ssub][ln][0], &s0[8*h]);
            pack_store(&Fr[sel*6 + 1*2 + rreg][ssub][ln][0], &s1[8*h]);
            pack_store(&Fr[sel*6 + 2*2 + rreg][ssub][ln][0], &s2[8*h]);
        }
    };

    const short8v* Ff = (const short8v*)Fr;

    loadF(kBeg);
    for (int k0 = kBeg; k0 < 576; k0 += 32) {
        storeF();
        __syncthreads();
        if (k0 + 32 < 576) loadF(k0 + 32);
        #pragma unroll
        for (int sub = 0; sub < 2; ++sub) {
            short8v a0 = Ff[((0*2 + wr)*2 + sub)*64 + lane];
            short8v a1 = Ff[((1*2 + wr)*2 + sub)*64 + lane];
            short8v a2 = Ff[((2*2 + wr)*2 + sub)*64 + lane];
            short8v b0 = Ff[((6 + 0*2 + wc)*2 + sub)*64 + lane];
            short8v b1 = Ff[((6 + 1*2 + wc)*2 + sub)*64 + lane];
            short8v b2 = Ff[((6 + 2*2 + wc)*2 + sub)*64 + lane];
            acc = __builtin_amdgcn_mfma_f32_32x32x16_bf16(a0, b0, acc, 0, 0, 0);
            acc = __builtin_amdgcn_mfma_f32_32x32x16_bf16(a0, b1, acc, 0, 0, 0);
            acc = __builtin_amdgcn_mfma_f32_32x32x16_bf16(a1, b0, acc, 0, 0, 0);
            acc = __builtin_amdgcn_mfma_f32_32x32x16_bf16(a1, b1, acc, 0, 0, 0);
            acc = __builtin_amdgcn_mfma_f32_32x32x16_bf16(a0, b2, acc, 0, 0, 0);
            acc = __builtin_amdgcn_mfma_f32_32x32x16_bf16(a2, b0, acc, 0, 0, 0);
        }
        __syncthreads();
    }

    int colg = n0 + 32*wc + (lane & 31);
    int rowb = m0 + 32*wr + 4*(lane >> 5);
    #pragma unroll
    for (int reg = 0; reg < 16; ++reg) {
        int row = rowb + (reg & 3) + 8*(reg >> 2);
        float v = acc[reg];
        Cb[(size_t)row * 576 + colg] = v;
        Cb[(size_t)colg * 576 + row] = v;    // mirror (bit-identical value)
    }
}

// ---------------------------------------------------------------------------
// mm_ab_mfma (r6-verified): iW = Kin @ Kinv, direct write.
// ---------------------------------------------------------------------------
__global__ __launch_bounds__(256, 2)
void mm_ab_mfma(const float* __restrict__ Aall, const float* __restrict__ Ball,
                float* __restrict__ Call, long sA, long sB, long sC)
{
    int nx = blockIdx.x % 9, my = blockIdx.x / 9;
    int b = blockIdx.z;
    const float* A = Aall + (size_t)b * sA;   // [m][k]
    const float* B = Ball + (size_t)b * sB;   // [k][n]
    float* Cb = Call + (size_t)b * sC;
    int m0 = my * 64, n0 = nx * 64;

    __shared__ __align__(16) unsigned short Fr[12][2][64][8];   // 24 KB

    int tid  = threadIdx.x;
    int lane = tid & 63;
    int wid  = tid >> 6;
    int wr = wid >> 1, wc = wid & 1;

    f32x16 acc;
    #pragma unroll
    for (int i = 0; i < 16; ++i) acc[i] = 0.0f;

    int sel  = tid >> 7;          // 0: A rows (float4), 1: B cols (scalar)
    int q2   = tid & 127;
    int ar   = q2 >> 1;
    int asub = q2 & 1;
    int areg = ar >> 5, aln = ar & 31;
    int bcol = q2 & 63;
    int bssub = q2 >> 6;
    int breg = bcol >> 5, brln = bcol & 31;

    float av[16];

    auto loadF = [&](int k0) {
        if (sel == 0) {
            const float* pp = A + (size_t)(m0 + ar) * 576 + k0 + asub * 16;
            float4 t0 = *(const float4*)(pp);
            float4 t1 = *(const float4*)(pp + 4);
            float4 t2 = *(const float4*)(pp + 8);
            float4 t3 = *(const float4*)(pp + 12);
            av[0]=t0.x;  av[1]=t0.y;  av[2]=t0.z;  av[3]=t0.w;
            av[4]=t1.x;  av[5]=t1.y;  av[6]=t1.z;  av[7]=t1.w;
            av[8]=t2.x;  av[9]=t2.y;  av[10]=t2.z; av[11]=t2.w;
            av[12]=t3.x; av[13]=t3.y; av[14]=t3.z; av[15]=t3.w;
        } else {
            const float* pp = B + (size_t)(k0 + bssub * 16) * 576 + n0 + bcol;
            #pragma unroll
            for (int j = 0; j < 16; ++j) av[j] = pp[(size_t)j * 576];
        }
    };
    auto storeF = [&]() {
        unsigned short s0[16], s1[16], s2[16];
        #pragma unroll
        for (int j = 0; j < 16; ++j) split3(av[j], s0[j], s1[j], s2[j]);
        int reg0 = sel ? (6 + 0*2 + breg) : (0*2 + areg);
        int reg1 = sel ? (6 + 1*2 + breg) : (1*2 + areg);
        int reg2 = sel ? (6 + 2*2 + breg) : (2*2 + areg);
        int sb   = sel ? bssub : asub;
        int ln0  = sel ? brln : aln;
        #pragma unroll
        for (int h = 0; h < 2; ++h) {
            int ln = ln0 + 32 * h;
            pack_store(&Fr[reg0][sb][ln][0], &s0[8*h]);
            pack_store(&Fr[reg1][sb][ln][0], &s1[8*h]);
            pack_store(&Fr[reg2][sb][ln][0], &s2[8*h]);
        }
    };

    const short8v* Ff = (const short8v*)Fr;

    loadF(0);
    for (int k0 = 0; k0 < 576; k0 += 32) {
        storeF();
        __syncthreads();
        if (k0 + 32 < 576) loadF(k0 + 32);
        #pragma unroll
        for (int sub = 0; sub < 2; ++sub) {
            short8v a0 = Ff[((0*2 + wr)*2 + sub)*64 + lane];
            short8v a1 = Ff[((1*2 + wr)*2 + sub)*64 + lane];
            short8v a2 = Ff[((2*2 + wr)*2 + sub)*64 + lane];
            short8v b0 = Ff[((6 + 0*2 + wc)*2 + sub)*64 + lane];
            short8v b1 = Ff[((6 + 1*2 + wc)*2 + sub)*64 + lane];
            short8v b2 = Ff[((6 + 2*2 + wc)*2 + sub)*64 + lane];
            acc = __builtin_amdgcn_mfma_f32_32x32x16_bf16(a0, b0, acc, 0, 0, 0);
            acc = __builtin_amdgcn_mfma_f32_32x32x16_bf16(a0, b1, acc, 0, 0, 0);
            acc = __builtin_amdgcn_mfma_f32_32x32x16_bf16(a1, b0, acc, 0, 0, 0);
            acc = __builtin_amdgcn_mfma_f32_32x32x16_bf16(a1, b1, acc, 0, 0, 0);
            acc = __builtin_amdgcn_mfma_f32_32x32x16_bf16(a0, b2, acc, 0, 0, 0);
            acc = __builtin_amdgcn_mfma_f32_32x32x16_bf16(a2, b0, acc, 0, 0, 0);
        }
        __syncthreads();
    }

    int colg = n0 + 32*wc + (lane & 31);
    int rowb = m0 + 32*wr + 4*(lane >> 5);
    #pragma unroll
    for (int reg = 0; reg < 16; ++reg) {
        int row = rowb + (reg & 3) + 8*(reg >> 2);
        Cb[(size_t)row * 576 + colg] = acc[reg];
    }
}

// ---------------------------------------------------------------------------
// batched tiled matmul, 64x64 C-tile, 256 threads (4x4 micro), reg prefetch.
// (still used for the small skinny GEMMs: sol_mean, opimean)
// ---------------------------------------------------------------------------
template<int TA, int TB, int SK, int TRI, int SWZ, int EPIB, int TRIC>
__global__ __launch_bounds__(256)
void mm_kernel(const float* __restrict__ Aall, const float* __restrict__ Ball,
               float* __restrict__ Call,
               int M, int N, int K, int planeK,
               int lda, int ldb, int ldc,
               long sA, long sB, long sC, long pA, long pB, long sSplit, int MT)
{
    int nx, my, zz;
    if (TRIC) {
        int p = blockIdx.x;
        int ir = 0;
        while (p >= ir + 1) { p -= ir + 1; ir++; }
        my = ir; nx = p; zz = blockIdx.z;
    } else if (SWZ) {
        int id = blockIdx.x;
        int x8 = id & 7;
        int q  = id >> 3;
        nx = q % 9;
        int band = x8 + 8 * (q / 9);
        if (band >= MT * 4 * SK) return;
        my = band % MT;
        zz = band / MT;
    } else { nx = blockIdx.x; my = blockIdx.y; zz = blockIdx.z; }
    int sp = (SK > 1) ? (zz % SK) : 0;
    int b  = (SK > 1) ? (zz / SK) : zz;
    const float* A = Aall + (size_t)b * sA;
    const float* B = Ball + (size_t)b * sB;
    float* C = Call + (size_t)b * sC + (size_t)sp * sSplit;
    int n0 = nx * 64;
    int m0 = my * 64;

    __shared__ float As[16][68];
    __shared__ float Bs[16][68];

    int tid = threadIdx.x;
    int tx = tid & 15, ty = tid >> 4;

    float acc[4][4] = {};
    bool mFull = (m0 + 64 <= M);
    bool nFull = (n0 + 64 <= N);

    int triBeg = 0;
    if (TRI) { int mx = (m0 > n0 ? m0 : n0); triBeg = mx & ~15; }
    int kBeg = triBeg, kEnd = K;
    if (SK > 1) {
        int len = K - triBeg;
        int chunk = ((len / SK) + 15) & ~15;
        kBeg = triBeg + sp * chunk;
        if (kBeg > K) kBeg = K;
        kEnd = (sp == SK - 1) ? K : (kBeg + chunk < K ? kBeg + chunk : K);
    }

    float avr[4];
    float bvr[4];

    auto loadA = [&](int k0) {
        int plane = k0 / planeK;
        int koff  = k0 - plane * planeK;
        if (TA == 0) {
            const float* Ab = A + (size_t)pA * plane;
            int r = tid >> 2, c4 = (tid & 3) * 4;
            int gm = m0 + r;
            if (mFull || gm < M) {
                float4 t = *(const float4*)(Ab + (size_t)gm * lda + koff + c4);
                avr[0]=t.x; avr[1]=t.y; avr[2]=t.z; avr[3]=t.w;
            } else { avr[0]=avr[1]=avr[2]=avr[3]=0.0f; }
        } else {
            int r = tid >> 4, c4 = (tid & 15) * 4;
            const float* p = A + (size_t)(koff + r) * lda + m0 + c4;
            if (mFull) {
                float4 t = *(const float4*)p;
                avr[0]=t.x; avr[1]=t.y; avr[2]=t.z; avr[3]=t.w;
            } else {
                #pragma unroll
                for (int jj = 0; jj < 4; ++jj)
                    avr[jj] = (m0 + c4 + jj < M) ? p[jj] : 0.0f;
            }
        }
    };
    auto storeA = [&]() {
        if (TA == 0) {
            int r = tid >> 2, c4 = (tid & 3) * 4;
            #pragma unroll
            for (int q = 0; q < 4; ++q) As[c4+q][r] = avr[q];
        } else {
            int r = tid >> 4, c4 = (tid & 15) * 4;
            #pragma unroll
            for (int q = 0; q < 4; ++q) As[r][c4+q] = avr[q];
        }
    };
    auto loadB = [&](int k0) {
        int plane = k0 / planeK;
        int koff  = k0 - plane * planeK;
        if (TB == 0) {
            int r = tid >> 4, c4 = (tid & 15) * 4;
            const float* p = B + (size_t)(koff + r) * ldb + n0 + c4;
            if (nFull) {
                float4 t = *(const float4*)p;
                bvr[0]=t.x; bvr[1]=t.y; bvr[2]=t.z; bvr[3]=t.w;
            } else {
                #pragma unroll
                for (int jj = 0; jj < 4; ++jj)
                    bvr[jj] = (n0 + c4 + jj < N) ? p[jj] : 0.0f;
            }
            if (EPIB) {
                int gk = koff + r;
                #pragma unroll
                for (int jj = 0; jj < 4; ++jj)
                    if (gk == n0 + c4 + jj) bvr[jj] -= 1.0f;
            }
        } else {
            const float* Bb = B + (size_t)pB * plane;
            int r = tid >> 2, c4 = (tid & 3) * 4;
            int gp = n0 + r;
            if (nFull || gp < N) {
                float4 t = *(const float4*)(Bb + (size_t)gp * ldb + koff + c4);
                bvr[0]=t.x; bvr[1]=t.y; bvr[2]=t.z; bvr[3]=t.w;
            } else { bvr[0]=bvr[1]=bvr[2]=bvr[3]=0.0f; }
        }
    };
    auto storeB = [&]() {
        if (TB == 0) {
            int r = tid >> 4, c4 = (tid & 15) * 4;
            #pragma unroll
            for (int q = 0; q < 4; ++q) Bs[r][c4+q] = bvr[q];
        } else {
            int r = tid >> 2, c4 = (tid & 3) * 4;
            #pragma unroll
            for (int q = 0; q < 4; ++q) Bs[c4+q][r] = bvr[q];
        }
    };

    if (kBeg < kEnd) {
        loadA(kBeg); loadB(kBeg);
        for (int k0 = kBeg; k0 < kEnd; k0 += 16) {
            storeA(); storeB();
            __syncthreads();
            if (k0 + 16 < kEnd) { loadA(k0 + 16); loadB(k0 + 16); }
            #pragma unroll
            for (int kk = 0; kk < 16; ++kk) {
                float a[4], bb[4];
                *(float4*)a  = *(const float4*)&As[kk][ty*4];
                *(float4*)bb = *(const float4*)&Bs[kk][tx*4];
                #pragma unroll
                for (int i = 0; i < 4; ++i)
                    #pragma unroll
                    for (int j = 0; j < 4; ++j)
                        acc[i][j] += a[i] * bb[j];
            }
            __syncthreads();
        }
    }

    #pragma unroll
    for (int i = 0; i < 4; ++i) {
        int gm = m0 + ty*4 + i;
        if (gm >= M) continue;
        #pragma unroll
        for (int j = 0; j < 4; ++j) {
            int gn = n0 + tx*4 + j;
            if (gn >= N) continue;
            C[(size_t)gm * ldc + gn] = acc[i][j];
        }
    }
}

// ---------------------------------------------------------------------------
// combine kernels
// ---------------------------------------------------------------------------
__global__ void combine_solm4(const float* __restrict__ p, float* __restrict__ o) {
    int i = blockIdx.x * 256 + threadIdx.x;   // 73728 elems -> 288 WGs
    o[i] = p[i] + p[i + 73728] + p[i + 2*73728] + p[i + 3*73728];
}

// symmetric combine: partials valid only for m>=n; prior symmetric; write both
__global__ void combine_prior4_sym(const float* __restrict__ p0,
                                   const float* __restrict__ xin,
                                   const float* __restrict__ W2g,
                                   float* __restrict__ o, long stride) {
    __shared__ float w[16];
    int tid = threadIdx.x;
    if (tid < 16) w[tid] = W2g[tid];
    __syncthreads();
    int idx = blockIdx.x * 256 + tid;           // over 4*N2
    int b = idx / N2;
    int rem = idx - b * N2;
    int m = rem / NPTS, n = rem - m * NPTS;
    if (m < n) return;
    const float* xb = xin + (size_t)b * NPTS * 2;
    float r0 = xb[m*2+0] - xb[n*2+0];
    float r1 = xb[m*2+1] - xb[n*2+1];
    float u = (r0*r0 + r1*r1) * INVL2;
    float Kv = expf(-0.5f * u);
    float i2 = INVL2 * INVL2;
    float gK0 = r0 * INVL2 * Kv;
    float gK1 = r1 * INVL2 * Kv;
    float lapK = (u - 2.0f) * INVL2 * Kv;
    float gg00 = (INVL2 - r0*r0*i2) * Kv;
    float gg01 = (-r0*r1*i2) * Kv;
    float gg11 = (INVL2 - r1*r1*i2) * Kv;
    float gl0 = r0 * i2 * (4.0f - u) * Kv;
    float gl1 = r1 * i2 * (4.0f - u) * Kv;
    float ll = ((u-2.0f)*(u-2.0f) - 4.0f*u + 4.0f) * i2 * Kv;
    float prior =
          w[0]*Kv + w[1]*gK0 + w[2]*gK1 + w[3]*lapK
        + w[4]*(-gK0) + w[5]*gg00 + w[6]*gg01 + w[7]*gl0
        + w[8]*(-gK1) + w[9]*gg01 + w[10]*gg11 + w[11]*gl1
        + w[12]*lapK + w[13]*(-gl0) + w[14]*(-gl1) + w[15]*ll;
    float v = p0[idx] + p0[idx + stride] + p0[idx + 2*stride] + p0[idx + 3*stride]
            + prior;
    if (m == n) v += 1.1e-4f;
    o[(size_t)b * N2 + (size_t)m * NPTS + n] = v;
    if (m != n)
        o[(size_t)b * N2 + (size_t)n * NPTS + m] = v;
}

// ---------------------------------------------------------------------------
// opiKW2[b][i] = sum_j W2[i][j] * opiK[b][j]  — safe in-place (per-element)
// ---------------------------------------------------------------------------
__global__ void opiw2_k(const float* __restrict__ opiK, const float* __restrict__ W2,
                        float* __restrict__ outB) {
    int idx = blockIdx.x * 256 + threadIdx.x;
    int b = idx / N2;
    int rem = idx - b * N2;
    size_t base = (size_t)b * 4 * N2 + rem;
    float k0 = opiK[base], k1 = opiK[base + N2], k2 = opiK[base + 2*N2], k3 = opiK[base + 3*N2];
    #pragma unroll
    for (int i = 0; i < 4; ++i)
        outB[base + (size_t)i * N2] = W2[i*4+0]*k0 + W2[i*4+1]*k1 + W2[i*4+2]*k2 + W2[i*4+3]*k3;
}

// ---------------------------------------------------------------------------
__global__ __launch_bounds__(256)
void amean_k(const float* __restrict__ opimean, const float* __restrict__ weight,
             const float* __restrict__ bias, float* __restrict__ out) {
    int b = blockIdx.y;
    int m0 = blockIdx.x * 32;
    __shared__ float Wl[64][128];
    __shared__ float om[32][128];
    int tid = threadIdx.x;
    for (int idx = tid; idx < 64*128; idx += 256) Wl[idx / 128][idx & 127] = weight[idx];
    for (int idx = tid; idx < 32*128; idx += 256) {
        int m = idx >> 7, ck = idx & 127, c = ck >> 2, kop = ck & 3;
        om[m][ck] = opimean[((size_t)b * 4 + kop) * NPTS * 32 + (size_t)(m0 + m) * 32 + c];
    }
    __syncthreads();
    int ml = tid >> 3, o0 = (tid & 7) * 8;
    float acc[8] = {};
    for (int ck = 0; ck < 128; ++ck) {
        float v = om[ml][ck];
        #pragma unroll
        for (int q = 0; q < 8; ++q) acc[q] += v * Wl[o0+q][ck];
    }
    #pragma unroll
    for (int q = 0; q < 8; ++q)
        out[4608 + ((size_t)b * NPTS + m0 + ml) * 64 + o0 + q] = acc[q] + bias[o0+q];
}

// ---------------------------------------------------------------------------
static inline int gridSwz(int MT, int Z) { return 8 * 9 * ((MT * Z + 7) / 8); }

extern "C" void kernel_launch(void* const* d_in, const int* in_sizes, int n_in,
                              void* d_out, int out_size, void* d_ws, size_t ws_size,
                              hipStream_t stream) {
    const float* xin    = (const float*)d_in[0];
    const float* meanin = (const float*)d_in[1];
    const float* Kin    = (const float*)d_in[2];
    const float* weight = (const float*)d_in[3];
    const float* bias   = (const float*)d_in[4];
    float* out = (float*)d_out;
    float* ws  = (float*)d_ws;

    const long N2L = N2;
    float* W2      = ws;                       // 16 (pad 64)
    float* LinvKK  = ws + 64;                  // 4*9*4096
    float* R1 = LinvKK + 147456;               // 4*N2: Kxx/A; later iW (direct)
    float* R2 = R1 + 4*N2L;                    // 4*N2: Linv; later solm/opim
    float* R3 = R2 + 4*N2L;                    // 4*N2: L panels; later Kinv (direct)
    float* R4 = R3 + 4*N2L;                    // 16*N2: opiK; later opiKW2 (in-place)
    float* R5 = R4 + 16*N2L;                   // 16*N2: KiO (direct); final partials
    float* R6 = R5 + 16*N2L;                   // 16*N2: solm partials; H'

    // zero Linv (upper triangle must be 0)
    hipMemsetAsync(R2, 0, (size_t)4 * N2 * sizeof(float), stream);
    copy_xout<<<dim3(18), dim3(256), 0, stream>>>(xin, out);
    build_k<<<dim3((BSZ*N2)/256), dim3(256), 0, stream>>>(xin, R1, R4);
    w2_k<<<dim3(1), dim3(256), 0, stream>>>(weight, W2);
    // Cholesky: 9 launches. L panels -> R3; diag inverses -> LinvKK
    chol_diag0<<<dim3(BSZ), dim3(256), 0, stream>>>(R1, LinvKK);
    for (int kb = 0; kb < NT - 1; ++kb) {
        int t = NT - 1 - kb;
        chol_step<<<dim3(t*(t+1)/2, BSZ), dim3(256), 0, stream>>>(R1, R3, LinvKK, kb);
    }
    // triangular inverse -> R2
    trinv_blk<<<dim3(4, NT, BSZ), dim3(256), 0, stream>>>(R3, LinvKK, R2);
    // Kinv = Linv^T @ Linv  (bf16x3 MFMA, sym lower tiles + mirror, direct -> R3)
    mm_ata_mfma<<<dim3(45, 1, BSZ), dim3(256), 0, stream>>>(R2, R3, N2L, N2L);
    // sol_mean = Kinv @ meanin  (SK4 partials -> R6; combine -> R2)
    mm_kernel<0,0,4,0,0,0,0><<<dim3(1,9,16), dim3(256), 0, stream>>>(
        R3, meanin, R6, 576,32,576,576, 576,32,32,
        N2L,18432,18432, 0,0, 73728, 9);
    combine_solm4<<<dim3(288), dim3(256), 0, stream>>>(R6, R2);
    // opimean = opiK @ sol_mean -> R2+73728
    mm_kernel<0,0,1,0,0,0,0><<<dim3(1,36,BSZ), dim3(256), 0, stream>>>(
        R4, R2, R2 + 73728, 2304,32,576,576, 576,32,32,
        4*N2L,18432,73728, 0,0, 0, 9);
    amean_k<<<dim3(18,BSZ), dim3(256), 0, stream>>>(R2 + 73728, weight, bias, out);
    // iW = Kin @ Kinv  (bf16x3 MFMA, direct -> R1, no combine)
    mm_ab_mfma<<<dim3(81, 1, BSZ), dim3(256), 0, stream>>>(
        Kin, R3, R1, N2L, N2L, N2L);
    // KiO = opiK @ Kinv  (bf16x3 MFMA, full-K, direct write -> R5, no combine)
    mm_p2_mfma<0><<<dim3(gridSwz(18,4)), dim3(256), 0, stream>>>(
        R4, R3, R5, 4*N2L, N2L, 4*N2L);
    // opiKW2 in-place on R4 (opiK no longer needed)
    opiw2_k<<<dim3((BSZ*N2)/256), dim3(256), 0, stream>>>(R4, W2, R4);
    // H' = KiO @ (iW - I)  (bf16x3 MFMA, -I fold) -> R6
    mm_p2_mfma<1><<<dim3(gridSwz(18,4)), dim3(256), 0, stream>>>(
        R5, R1, R6, 4*N2L, N2L, 4*N2L);
    // final AKA partial GEMM — SYMMETRIC lower tiles, MFMA, SK4 = plane-split.
    // partials -> R5 (sC=N2 batch plane, sSplit=4*N2 split plane)
    mm_abt_mfma<<<dim3(45,1,BSZ*4), dim3(256), 0, stream>>>(
        R6, R4, R5, 4*N2L, 4*N2L, N2L, 4*N2L);
    // output 2: combine 4 partials (m>=n) + analytic prior + jitter, mirrored
    combine_prior4_sym<<<dim3(5184), dim3(256), 0, stream>>>(
        R5, xin, W2, out + 152064, 4*N2L);
}

// Round 10
// 874.472 us; speedup vs baseline: 1.0454x; 1.0166x over previous
//
#include <hip/hip_runtime.h>
#include <math.h>

#define NPTS 576
#define N2 331776           // 576*576
#define BSZ 4
#define NB 64               // cholesky block
#define NT 9                // 576/64

#define INVL2 (1.0f/0.29311396f)

typedef __attribute__((ext_vector_type(8))) short short8v;   // 8 bf16 (4 VGPRs)
typedef __attribute__((ext_vector_type(16))) float f32x16;   // MFMA 32x32 acc

// ---------------------------------------------------------------------------
// build Kxx (+jitter) and opiK (4 planes) from xin; fused copy_xout + w2.
// (fusion verified correct in r8's bundle; isolated here)
// ---------------------------------------------------------------------------
__global__ void build_k(const float* __restrict__ xin,
                        float* __restrict__ Kxx, float* __restrict__ opiK,
                        float* __restrict__ out,
                        const float* __restrict__ w, float* __restrict__ W2) {
    int idx = blockIdx.x * 256 + threadIdx.x;
    if (idx < 4608) out[idx] = xin[idx];     // fused copy_xout
    int b = idx / N2;
    int rem = idx - b * N2;
    int m = rem / NPTS;
    int nn = rem - m * NPTS;
    const float* xb = xin + (size_t)b * NPTS * 2;
    float xm0 = xb[m*2],  xm1 = xb[m*2+1];
    float xn0 = xb[nn*2], xn1 = xb[nn*2+1];
    float r0 = xm0 - xn0, r1 = xm1 - xn1;
    float u = (r0*r0 + r1*r1) * INVL2;
    float Kv = expf(-0.5f * u);
    Kxx[idx] = Kv + ((m == nn) ? 1e-5f : 0.0f);
    size_t base = (size_t)b * 4 * N2 + rem;
    opiK[base]          = Kv;
    opiK[base + N2]     = -r0 * INVL2 * Kv;
    opiK[base + 2*N2]   = -r1 * INVL2 * Kv;
    opiK[base + 3*N2]   = (u - 2.0f) * INVL2 * Kv;
    // fused w2 (one WG): W2[i][j] = mean_o sum_c w[o][c][i] w[o][c][j]
    if (blockIdx.x == 5183) {
        __shared__ float red[256];
        int tid = threadIdx.x;
        int pair = tid & 15;
        int slice = tid >> 4;
        int i = pair >> 2, j = pair & 3;
        float s = 0.0f;
        for (int o = slice * 4; o < slice * 4 + 4; ++o)
            for (int c = 0; c < 32; ++c)
                s += w[o*128 + c*4 + i] * w[o*128 + c*4 + j];
        red[tid] = s;
        __syncthreads();
        if (tid < 16) {
            float t = 0.0f;
            #pragma unroll
            for (int k = 0; k < 16; ++k) t += red[pair + 16*k];
            W2[pair] = t * (1.0f/64.0f);
        }
    }
}

// ---------------------------------------------------------------------------
// factor 64x64 SPD block in T (lower), produce V = T^{-1} (lower).
// r4: panel factor row-per-lane in registers + __shfl (no LDS on the chain).
// r5: diag 16x16 inverse also register+shuffle. Block-solve r0 verbatim.
// ---------------------------------------------------------------------------
__device__ void factor_invert_64(float (*T)[NB+1], float (*V)[NB+1],
                                 float (*tmp)[17], int tid) {
    for (int p = 0; p < 4; ++p) {
        int cp = p * 16;
        if (tid < 64) {
            int r = tid;
            float reg[16];
            #pragma unroll
            for (int q = 0; q < 16; ++q) reg[q] = T[r][cp + q];
            #pragma unroll
            for (int j = 0; j < 16; ++j) {
                int col = cp + j;
                float d2 = __shfl(reg[j], col);          // pivot (pre-sqrt)
                float d = sqrtf(fmaxf(d2, 1e-12f));
                float lr = (r == col) ? d : reg[j] / d;  // junk for r<col, unused
                reg[j] = lr;
                #pragma unroll
                for (int q = j + 1; q < 16; ++q) {
                    float lc = __shfl(lr, cp + q);       // L[cp+q][col]
                    if (r >= cp + q) reg[q] -= lr * lc;
                }
            }
            #pragma unroll
            for (int q = 0; q < 16; ++q) T[r][cp + q] = reg[q];
        }
        __syncthreads();
        int tr = 48 - cp;
        if (tr > 0) {
            for (int idx = tid; idx < tr * tr; idx += 256) {
                int r = cp + 16 + idx / tr;
                int c = cp + 16 + idx % tr;
                if (c <= r) {
                    float s = 0.0f;
                    #pragma unroll
                    for (int k = 0; k < 16; ++k) s += T[r][cp+k] * T[c][cp+k];
                    T[r][c] -= s;
                }
            }
        }
        __syncthreads();
    }
    // diag 16x16 inverses: column-per-lane forward substitution in registers.
    if (tid < 64) {
        int I = tid >> 4, c = tid & 15, base = I * 16;
        float tcol[16];
        #pragma unroll
        for (int i = 0; i < 16; ++i) tcol[i] = T[base + i][base + c];
        float v[16];
        #pragma unroll
        for (int i = 0; i < 16; ++i) {
            float s = (i == c) ? 1.0f : 0.0f;
            #pragma unroll
            for (int k = 0; k < 16; ++k) {
                if (k < i) {                              // compile-time mask
                    float tik = __shfl(tcol[i], base + k);
                    s -= tik * v[k];
                }
            }
            float tii = __shfl(tcol[i], base + i);
            v[i] = s / tii;                               // exact 0 for i<c
        }
        #pragma unroll
        for (int i = 0; i < 16; ++i) V[base + i][base + c] = v[i];
    }
    __syncthreads();
    const int PI[6] = {1,2,3,2,3,3};
    const int PJ[6] = {0,1,2,0,1,0};
    int rr16 = tid >> 4, cc16 = tid & 15;
    for (int p = 0; p < 6; ++p) {
        int I = PI[p], J = PJ[p];
        float s = 0.0f;
        for (int K = J; K < I; ++K)
            #pragma unroll
            for (int t = 0; t < 16; ++t)
                s += T[I*16+rr16][K*16+t] * V[K*16+t][J*16+cc16];
        tmp[rr16][cc16] = s;
        __syncthreads();
        float s2 = 0.0f;
        for (int t = 0; t <= rr16; ++t) s2 += V[I*16+rr16][I*16+t] * tmp[t][cc16];
        __syncthreads();
        V[I*16+rr16][J*16+cc16] = -s2;
        __syncthreads();
    }
}

// ---------------------------------------------------------------------------
__global__ void chol_diag0(const float* __restrict__ A, float* __restrict__ LinvKK) {
    int b = blockIdx.x;
    const float* Ab = A + (size_t)b * N2;
    __shared__ float T[NB][NB+1];
    __shared__ float V[NB][NB+1];
    __shared__ float tmp[16][17];
    int tid = threadIdx.x;
    for (int idx = tid; idx < NB*NB; idx += 256) {
        int r = idx >> 6, c = idx & 63;
        T[r][c] = Ab[(size_t)r * NPTS + c];
        V[r][c] = 0.0f;
    }
    __syncthreads();
    factor_invert_64(T, V, tmp, tid);
    float* Vg = LinvKK + (size_t)b * NT * NB * NB;
    for (int idx = tid; idx < NB*NB; idx += 256) Vg[idx] = V[idx >> 6][idx & 63];
}

// ---------------------------------------------------------------------------
// fused Cholesky step for panel kb. 9 total launches.
// ---------------------------------------------------------------------------
__global__ __launch_bounds__(256)
void chol_step(float* __restrict__ A, float* __restrict__ LL,
               float* __restrict__ LinvKK, int kb) {
    int b = blockIdx.y;
    int p = blockIdx.x;
    int ir = 0;
    while (p >= ir + 1) { p -= ir + 1; ir++; }
    int ib = kb + 1 + ir, jb = kb + 1 + p;
    float* Ab = A + (size_t)b * N2;
    float* LLb = LL + (size_t)b * N2;
    __shared__ float Ai[NB][NB+1];
    __shared__ float Aj[NB][NB+1];
    __shared__ float Vs[NB][NB+1];
    __shared__ float tmp[16][17];
    int tid = threadIdx.x;
    int tx = tid & 15, ty = tid >> 4;
    const float* Vg = LinvKK + ((size_t)b * NT + kb) * NB * NB;
    bool diag = (ib == jb);
    for (int idx = tid; idx < NB*NB; idx += 256) {
        int r = idx >> 6, c = idx & 63;
        Ai[r][c] = Ab[(size_t)(ib*NB + r) * NPTS + kb*NB + c];
        Aj[r][c] = diag ? 0.0f : Ab[(size_t)(jb*NB + r) * NPTS + kb*NB + c];
        Vs[r][c] = Vg[idx];
    }
    float U[4][4];
    #pragma unroll
    for (int i = 0; i < 4; ++i)
        #pragma unroll
        for (int j = 0; j < 4; ++j)
            U[i][j] = Ab[(size_t)(ib*NB + ty*4+i) * NPTS + jb*NB + tx*4+j];
    __syncthreads();
    float Li[4][4] = {}, Lj[4][4] = {};
    for (int k = 0; k < NB; ++k) {
        float a[4], v[4];
        #pragma unroll
        for (int i = 0; i < 4; ++i) a[i] = Ai[ty*4+i][k];
        #pragma unroll
        for (int j = 0; j < 4; ++j) v[j] = Vs[tx*4+j][k];
        #pragma unroll
        for (int i = 0; i < 4; ++i)
            #pragma unroll
            for (int j = 0; j < 4; ++j) Li[i][j] += a[i] * v[j];
        if (!diag) {
            float aj[4];
            #pragma unroll
            for (int i = 0; i < 4; ++i) aj[i] = Aj[ty*4+i][k];
            #pragma unroll
            for (int i = 0; i < 4; ++i)
                #pragma unroll
                for (int j = 0; j < 4; ++j) Lj[i][j] += aj[i] * v[j];
        }
    }
    __syncthreads();
    #pragma unroll
    for (int i = 0; i < 4; ++i)
        #pragma unroll
        for (int j = 0; j < 4; ++j) {
            Ai[ty*4+i][tx*4+j] = Li[i][j];
            Aj[ty*4+i][tx*4+j] = diag ? Li[i][j] : Lj[i][j];
        }
    if (diag) {
        #pragma unroll
        for (int i = 0; i < 4; ++i)
            #pragma unroll
            for (int j = 0; j < 4; ++j)
                LLb[(size_t)(ib*NB + ty*4+i) * NPTS + kb*NB + tx*4+j] = Li[i][j];
    }
    __syncthreads();
    float s[4][4] = {};
    for (int k = 0; k < NB; ++k) {
        float a[4], v[4];
        #pragma unroll
        for (int i = 0; i < 4; ++i) a[i] = Ai[ty*4+i][k];
        #pragma unroll
        for (int j = 0; j < 4; ++j) v[j] = Aj[tx*4+j][k];
        #pragma unroll
        for (int i = 0; i < 4; ++i)
            #pragma unroll
            for (int j = 0; j < 4; ++j) s[i][j] += a[i] * v[j];
    }
    #pragma unroll
    for (int i = 0; i < 4; ++i)
        #pragma unroll
        for (int j = 0; j < 4; ++j) U[i][j] -= s[i][j];
    if (blockIdx.x != 0) {
        #pragma unroll
        for (int i = 0; i < 4; ++i)
            #pragma unroll
            for (int j = 0; j < 4; ++j)
                Ab[(size_t)(ib*NB + ty*4+i) * NPTS + jb*NB + tx*4+j] = U[i][j];
        return;
    }
    __syncthreads();
    #pragma unroll
    for (int i = 0; i < 4; ++i)
        #pragma unroll
        for (int j = 0; j < 4; ++j) Ai[ty*4+i][tx*4+j] = U[i][j];
    for (int idx = tid; idx < NB*NB; idx += 256) Aj[idx >> 6][idx & 63] = 0.0f;
    __syncthreads();
    factor_invert_64(Ai, Aj, tmp, tid);
    float* Vo = LinvKK + ((size_t)b * NT + (kb + 1)) * NB * NB;
    for (int idx = tid; idx < NB*NB; idx += 256) Vo[idx] = Aj[idx >> 6][idx & 63];
}

// ---------------------------------------------------------------------------
// blocked triangular inverse. grid (4 col-splits, 9 block-cols, 4 batch)
// r10: register prefetch of the NEXT stage's L/V tile with NAMED float4
// registers, fully inlined (r8's pf[4]+lambdas spilled to LDS: block size
// 61952->78336 = exactly 256x64B; rule-#20 failure). Layout/values are r6
// bit-identical; only the load issue point moves (overlaps compute).
// Validation signal: LDS_Block_Size must remain 61952.
// ---------------------------------------------------------------------------
__global__ __launch_bounds__(256)
void trinv_blk(const float* __restrict__ L, const float* __restrict__ LinvKK,
               float* __restrict__ Linv) {
    int sp = blockIdx.x, jb = blockIdx.y, b = blockIdx.z;
    const float* Lb = L + (size_t)b * N2;
    float* Xg = Linv + (size_t)b * N2;
    const float* Vg = LinvKK + (size_t)b * NT * NB * NB;
    int c0 = jb * NB + sp * 16;

    __shared__ float LsT[64][72];
    __shared__ float Xc[576][17];
    __shared__ float Ss[64][17];

    int tid = threadIdx.x;
    int tx = tid & 15, ty = tid >> 4;
    int sr = tid >> 2, st0 = (tid & 3) * 16;   // staging: row sr, k-span st0..st0+15

    float4 pf0, pf1, pf2, pf3;                 // named regs (NOT an array)

#define TRINV_ISSUE_L(ibv, kbv)                                               \
    { const float* src_ = Lb + (size_t)((ibv) * NB + sr) * NPTS + (kbv) * NB + st0; \
      pf0 = *(const float4*)(src_ + 0);  pf1 = *(const float4*)(src_ + 4);    \
      pf2 = *(const float4*)(src_ + 8);  pf3 = *(const float4*)(src_ + 12); }

#define TRINV_ISSUE_V(ibv)                                                    \
    { const float* src_ = Vg + (size_t)(ibv) * NB * NB + sr * NB + st0;       \
      pf0 = *(const float4*)(src_ + 0);  pf1 = *(const float4*)(src_ + 4);    \
      pf2 = *(const float4*)(src_ + 8);  pf3 = *(const float4*)(src_ + 12); }

#define TRINV_COMMIT()                                                        \
    { LsT[st0 + 0][sr]  = pf0.x; LsT[st0 + 1][sr]  = pf0.y;                   \
      LsT[st0 + 2][sr]  = pf0.z; LsT[st0 + 3][sr]  = pf0.w;                   \
      LsT[st0 + 4][sr]  = pf1.x; LsT[st0 + 5][sr]  = pf1.y;                   \
      LsT[st0 + 6][sr]  = pf1.z; LsT[st0 + 7][sr]  = pf1.w;                   \
      LsT[st0 + 8][sr]  = pf2.x; LsT[st0 + 9][sr]  = pf2.y;                   \
      LsT[st0 + 10][sr] = pf2.z; LsT[st0 + 11][sr] = pf2.w;                   \
      LsT[st0 + 12][sr] = pf3.x; LsT[st0 + 13][sr] = pf3.y;                   \
      LsT[st0 + 14][sr] = pf3.z; LsT[st0 + 15][sr] = pf3.w; }

    {
        const float* Vjj = Vg + (size_t)jb * NB * NB;
        int r = tid >> 2, c4 = (tid & 3) * 4;
        float4 v = *(const float4*)(Vjj + r * NB + sp * 16 + c4);
        Xc[r][c4+0] = v.x; Xc[r][c4+1] = v.y; Xc[r][c4+2] = v.z; Xc[r][c4+3] = v.w;
        *(float4*)(Xg + (size_t)(jb * NB + r) * NPTS + c0 + c4) = v;
    }
    if (jb + 1 < NT) TRINV_ISSUE_L(jb + 1, jb);
    __syncthreads();

    for (int ib = jb + 1; ib < NT; ++ib) {
        float acc[4] = {};
        for (int kb = jb; kb < ib; ++kb) {
            TRINV_COMMIT();                    // pf -> LsT (loads awaited here)
            __syncthreads();
            if (kb + 1 < ib) { TRINV_ISSUE_L(ib, kb + 1); }   // prefetch next
            else             { TRINV_ISSUE_V(ib); }
            int xbase = (kb - jb) * 64;
            #pragma unroll 8
            for (int t = 0; t < 64; ++t) {
                float a4[4]; *(float4*)a4 = *(const float4*)&LsT[t][ty*4];
                float xv = Xc[xbase + t][tx];
                #pragma unroll
                for (int i = 0; i < 4; ++i) acc[i] += a4[i] * xv;
            }
            __syncthreads();
        }
        TRINV_COMMIT();                        // V tile
        #pragma unroll
        for (int i = 0; i < 4; ++i) Ss[ty*4+i][tx] = acc[i];
        __syncthreads();
        if (ib + 1 < NT) TRINV_ISSUE_L(ib + 1, jb);   // prefetch next ib stage 0
        float acc2[4] = {};
        #pragma unroll 8
        for (int t = 0; t < 64; ++t) {
            float a4[4]; *(float4*)a4 = *(const float4*)&LsT[t][ty*4];
            float sv = Ss[t][tx];
            #pragma unroll
            for (int i = 0; i < 4; ++i) acc2[i] += a4[i] * sv;
        }
        int obase = (ib - jb) * 64;
        #pragma unroll
        for (int i = 0; i < 4; ++i) {
            float v = -acc2[i];
            Xc[obase + ty*4 + i][tx] = v;
            Xg[(size_t)(ib * NB + ty*4 + i) * NPTS + c0 + tx] = v;
        }
        __syncthreads();
    }
#undef TRINV_ISSUE_L
#undef TRINV_ISSUE_V
#undef TRINV_COMMIT
}

// ---------------------------------------------------------------------------
// bf16x3 split helpers for fp32-precision MFMA GEMM.
// ---------------------------------------------------------------------------
__device__ inline void split3(float v, unsigned short& h0, unsigned short& h1,
                              unsigned short& h2) {
    unsigned u0 = __float_as_uint(v) & 0xffff0000u;
    float f0 = __uint_as_float(u0);
    float r1 = v - f0;                       // exact
    unsigned u1 = __float_as_uint(r1) & 0xffff0000u;
    float f1 = __uint_as_float(u1);
    float r2 = r1 - f1;                      // exact
    h0 = (unsigned short)(u0 >> 16);
    h1 = (unsigned short)(u1 >> 16);
    h2 = (unsigned short)((__float_as_uint(r2) + 0x8000u) >> 16);  // RNE-ish
}

__device__ inline void pack_store(unsigned short* dst, const unsigned short* v) {
    uint4 w;
    w.x = (unsigned)v[0] | ((unsigned)v[1] << 16);
    w.y = (unsigned)v[2] | ((unsigned)v[3] << 16);
    w.z = (unsigned)v[4] | ((unsigned)v[5] << 16);
    w.w = (unsigned)v[6] | ((unsigned)v[7] << 16);
    *(uint4*)dst = w;
}

// ---------------------------------------------------------------------------
// mm_p2_mfma: plane-pair GEMM C[p] = A[p] @ B (bf16x3, 6 MFMAs/product).
// ---------------------------------------------------------------------------
template<int EPIB>
__global__ __launch_bounds__(256, 2)
void mm_p2_mfma(const float* __restrict__ Aall, const float* __restrict__ Ball,
                float* __restrict__ Call, long sA, long sB, long sC)
{
    int id = blockIdx.x;
    int x8 = id & 7, qq = id >> 3;
    int nx = qq % 9;
    int band = x8 + 8 * (qq / 9);
    if (band >= 18 * BSZ) return;
    int t  = band % 18;
    int b  = band / 18;
    int pp = t / 9, my = t % 9;
    const float* A0 = Aall + (size_t)b * sA + (size_t)(pp * 2) * N2;
    const float* A1 = A0 + N2;
    const float* B  = Ball + (size_t)b * sB;
    float* C0 = Call + (size_t)b * sC + (size_t)(pp * 2) * N2;
    float* C1 = C0 + N2;
    int n0 = nx * 64, m0 = my * 64;

    __shared__ __align__(16) unsigned short As[12][2][64][8];   // 24 KB
    __shared__ __align__(16) unsigned short Bs[6][2][64][8];    // 12 KB

    int tid  = threadIdx.x;
    int lane = tid & 63;
    int wid  = tid >> 6;
    int wr = wid >> 1, wc = wid & 1;

    f32x16 acc0, acc1;
    #pragma unroll
    for (int i = 0; i < 16; ++i) { acc0[i] = 0.0f; acc1[i] = 0.0f; }

    int ap   = tid >> 7;
    int aq   = tid & 127;
    int ar   = aq >> 1;
    int asub = aq & 1;
    const float* Apl = ap ? A1 : A0;
    int areg = ar >> 5;
    int aln  = ar & 31;

    int bc   = tid & 63;
    int bkg  = tid >> 6;
    int bsub = bkg >> 1;
    int bln  = (bc & 31) + 32 * (bkg & 1);
    int bwc  = bc >> 5;

    float av[16];
    float bv[8];

    auto loadA = [&](int k0) {
        const float* p = Apl + (size_t)(m0 + ar) * 576 + k0 + asub * 16;
        float4 t0 = *(const float4*)(p);
        float4 t1 = *(const float4*)(p + 4);
        float4 t2 = *(const float4*)(p + 8);
        float4 t3 = *(const float4*)(p + 12);
        av[0]=t0.x;  av[1]=t0.y;  av[2]=t0.z;  av[3]=t0.w;
        av[4]=t1.x;  av[5]=t1.y;  av[6]=t1.z;  av[7]=t1.w;
        av[8]=t2.x;  av[9]=t2.y;  av[10]=t2.z; av[11]=t2.w;
        av[12]=t3.x; av[13]=t3.y; av[14]=t3.z; av[15]=t3.w;
    };
    auto loadB = [&](int k0) {
        const float* p = B + (size_t)(k0 + bkg * 8) * 576 + n0 + bc;
        #pragma unroll
        for (int j = 0; j < 8; ++j) {
            float v = p[(size_t)j * 576];
            if (EPIB) { if (k0 + bkg * 8 + j == n0 + bc) v -= 1.0f; }
            bv[j] = v;
        }
    };
    auto storeA = [&]() {
        unsigned short s0[16], s1[16], s2[16];
        #pragma unroll
        for (int j = 0; j < 16; ++j) split3(av[j], s0[j], s1[j], s2[j]);
        #pragma unroll
        for (int h = 0; h < 2; ++h) {
            int ln = aln + 32 * h;
            pack_store(&As[(ap*3 + 0)*2 + areg][asub][ln][0], &s0[8*h]);
            pack_store(&As[(ap*3 + 1)*2 + areg][asub][ln][0], &s1[8*h]);
            pack_store(&As[(ap*3 + 2)*2 + areg][asub][ln][0], &s2[8*h]);
        }
    };
    auto storeB = [&]() {
        unsigned short s0[8], s1[8], s2[8];
        #pragma unroll
        for (int j = 0; j < 8; ++j) split3(bv[j], s0[j], s1[j], s2[j]);
        pack_store(&Bs[0*2 + bwc][bsub][bln][0], s0);
        pack_store(&Bs[1*2 + bwc][bsub][bln][0], s1);
        pack_store(&Bs[2*2 + bwc][bsub][bln][0], s2);
    };

    const short8v* Af = (const short8v*)As;
    const short8v* Bf = (const short8v*)Bs;

    loadA(0); loadB(0);
    for (int k0 = 0; k0 < 576; k0 += 32) {
        storeA(); storeB();
        __syncthreads();
        if (k0 + 32 < 576) { loadA(k0 + 32); loadB(k0 + 32); }
        #pragma unroll
        for (int sub = 0; sub < 2; ++sub) {
            short8v b0 = Bf[((0*2 + wc)*2 + sub)*64 + lane];
            short8v b1 = Bf[((1*2 + wc)*2 + sub)*64 + lane];
            short8v b2 = Bf[((2*2 + wc)*2 + sub)*64 + lane];
            short8v a0 = Af[((0*3 + 0)*2 + wr)*128 + sub*64 + lane];
            short8v a1 = Af[((0*3 + 1)*2 + wr)*128 + sub*64 + lane];
            short8v a2 = Af[((0*3 + 2)*2 + wr)*128 + sub*64 + lane];
            acc0 = __builtin_amdgcn_mfma_f32_32x32x16_bf16(a0, b0, acc0, 0, 0, 0);
            acc0 = __builtin_amdgcn_mfma_f32_32x32x16_bf16(a0, b1, acc0, 0, 0, 0);
            acc0 = __builtin_amdgcn_mfma_f32_32x32x16_bf16(a1, b0, acc0, 0, 0, 0);
            acc0 = __builtin_amdgcn_mfma_f32_32x32x16_bf16(a1, b1, acc0, 0, 0, 0);
            acc0 = __builtin_amdgcn_mfma_f32_32x32x16_bf16(a0, b2, acc0, 0, 0, 0);
            acc0 = __builtin_amdgcn_mfma_f32_32x32x16_bf16(a2, b0, acc0, 0, 0, 0);
            a0 = Af[((1*3 + 0)*2 + wr)*128 + sub*64 + lane];
            a1 = Af[((1*3 + 1)*2 + wr)*128 + sub*64 + lane];
            a2 = Af[((1*3 + 2)*2 + wr)*128 + sub*64 + lane];
            acc1 = __builtin_amdgcn_mfma_f32_32x32x16_bf16(a0, b0, acc1, 0, 0, 0);
            acc1 = __builtin_amdgcn_mfma_f32_32x32x16_bf16(a0, b1, acc1, 0, 0, 0);
            acc1 = __builtin_amdgcn_mfma_f32_32x32x16_bf16(a1, b0, acc1, 0, 0, 0);
            acc1 = __builtin_amdgcn_mfma_f32_32x32x16_bf16(a1, b1, acc1, 0, 0, 0);
            acc1 = __builtin_amdgcn_mfma_f32_32x32x16_bf16(a0, b2, acc1, 0, 0, 0);
            acc1 = __builtin_amdgcn_mfma_f32_32x32x16_bf16(a2, b0, acc1, 0, 0, 0);
        }
        __syncthreads();
    }

    int colg = n0 + 32*wc + (lane & 31);
    int rowb = m0 + 32*wr + 4*(lane >> 5);
    #pragma unroll
    for (int reg = 0; reg < 16; ++reg) {
        int row = rowb + (reg & 3) + 8*(reg >> 2);
        C0[(size_t)row * 576 + colg] = acc0[reg];
        C1[(size_t)row * 576 + colg] = acc1[reg];
    }
}

// ---------------------------------------------------------------------------
// mm_abt_mfma: final AKA partial GEMM (C = A @ B^T per plane), r5-verified.
// ---------------------------------------------------------------------------
__global__ __launch_bounds__(256, 2)
void mm_abt_mfma(const float* __restrict__ Aall, const float* __restrict__ Ball,
                 float* __restrict__ Call, long sA, long sB, long sC, long sSplit)
{
    int p = blockIdx.x;
    int ir = 0;
    while (p >= ir + 1) { p -= ir + 1; ir++; }
    int my = ir, nx = p;
    int zz = blockIdx.z;
    int sp = zz & 3, b = zz >> 2;
    const float* A = Aall + (size_t)b * sA + (size_t)sp * N2;   // [m][k]
    const float* B = Ball + (size_t)b * sB + (size_t)sp * N2;   // [n][k]
    float* Cp = Call + (size_t)b * sC + (size_t)sp * sSplit;
    int m0 = my * 64, n0 = nx * 64;

    __shared__ __align__(16) unsigned short Fr[12][2][64][8];   // 24 KB

    int tid  = threadIdx.x;
    int lane = tid & 63;
    int wid  = tid >> 6;
    int wr = wid >> 1, wc = wid & 1;

    f32x16 acc;
    #pragma unroll
    for (int i = 0; i < 16; ++i) acc[i] = 0.0f;

    int sel  = tid >> 7;          // 0: stage A, 1: stage B
    int q2   = tid & 127;
    int r    = q2 >> 1;           // row 0..63 (m for A, n for B)
    int ssub = q2 & 1;            // 16-k half
    const float* Src = sel ? B : A;
    int base0 = sel ? n0 : m0;
    int rreg = r >> 5;
    int rln  = r & 31;

    float av[16];

    auto loadF = [&](int k0) {
        const float* pp = Src + (size_t)(base0 + r) * 576 + k0 + ssub * 16;
        float4 t0 = *(const float4*)(pp);
        float4 t1 = *(const float4*)(pp + 4);
        float4 t2 = *(const float4*)(pp + 8);
        float4 t3 = *(const float4*)(pp + 12);
        av[0]=t0.x;  av[1]=t0.y;  av[2]=t0.z;  av[3]=t0.w;
        av[4]=t1.x;  av[5]=t1.y;  av[6]=t1.z;  av[7]=t1.w;
        av[8]=t2.x;  av[9]=t2.y;  av[10]=t2.z; av[11]=t2.w;
        av[12]=t3.x; av[13]=t3.y; av[14]=t3.z; av[15]=t3.w;
    };
    auto storeF = [&]() {
        unsigned short s0[16], s1[16], s2[16];
        #pragma unroll
        for (int j = 0; j < 16; ++j) split3(av[j], s0[j], s1[j], s2[j]);
        #pragma unroll
        for (int h = 0; h < 2; ++h) {
            int ln = rln + 32 * h;
            pack_store(&Fr[sel*6 + 0*2 + rreg][ssub][ln][0], &s0[8*h]);
            pack_store(&Fr[sel*6 + 1*2 + rreg][ssub][ln][0], &s1[8*h]);
            pack_store(&Fr[sel*6 + 2*2 + rreg][ssub][ln][0], &s2[8*h]);
        }
    };

    const short8v* Ff = (const short8v*)Fr;   // region*128 + sub*64 + lane

    loadF(0);
    for (int k0 = 0; k0 < 576; k0 += 32) {
        storeF();
        __syncthreads();
        if (k0 + 32 < 576) loadF(k0 + 32);
        #pragma unroll
        for (int sub = 0; sub < 2; ++sub) {
            short8v a0 = Ff[((0*2 + wr)*2 + sub)*64 + lane];
            short8v a1 = Ff[((1*2 + wr)*2 + sub)*64 + lane];
            short8v a2 = Ff[((2*2 + wr)*2 + sub)*64 + lane];
            short8v b0 = Ff[((6 + 0*2 + wc)*2 + sub)*64 + lane];
            short8v b1 = Ff[((6 + 1*2 + wc)*2 + sub)*64 + lane];
            short8v b2 = Ff[((6 + 2*2 + wc)*2 + sub)*64 + lane];
            acc = __builtin_amdgcn_mfma_f32_32x32x16_bf16(a0, b0, acc, 0, 0, 0);
            acc = __builtin_amdgcn_mfma_f32_32x32x16_bf16(a0, b1, acc, 0, 0, 0);
            acc = __builtin_amdgcn_mfma_f32_32x32x16_bf16(a1, b0, acc, 0, 0, 0);
            acc = __builtin_amdgcn_mfma_f32_32x32x16_bf16(a1, b1, acc, 0, 0, 0);
            acc = __builtin_amdgcn_mfma_f32_32x32x16_bf16(a0, b2, acc, 0, 0, 0);
            acc = __builtin_amdgcn_mfma_f32_32x32x16_bf16(a2, b0, acc, 0, 0, 0);
        }
        __syncthreads();
    }

    int colg = n0 + 32*wc + (lane & 31);
    int rowb = m0 + 32*wr + 4*(lane >> 5);
    #pragma unroll
    for (int reg = 0; reg < 16; ++reg) {
        int row = rowb + (reg & 3) + 8*(reg >> 2);
        Cp[(size_t)row * 576 + colg] = acc[reg];
    }
}

// ---------------------------------------------------------------------------
// mm_ata_mfma (r6-verified): Kinv = Linv^T @ Linv, symmetric lower + mirror.
// ---------------------------------------------------------------------------
__global__ __launch_bounds__(256, 2)
void mm_ata_mfma(const float* __restrict__ Lg, float* __restrict__ C,
                 long sA, long sC)
{
    int p = blockIdx.x;
    int ir = 0;
    while (p >= ir + 1) { p -= ir + 1; ir++; }
    int my = ir, nx = p;
    int b = blockIdx.z;
    const float* A = Lg + (size_t)b * sA;    // Linv, [k][col] row-major in k
    float* Cb = C + (size_t)b * sC;
    int m0 = my * 64, n0 = nx * 64;
    int kBeg = m0;                           // my >= nx

    __shared__ __align__(16) unsigned short Fr[12][2][64][8];   // 24 KB

    int tid  = threadIdx.x;
    int lane = tid & 63;
    int wid  = tid >> 6;
    int wr = wid >> 1, wc = wid & 1;

    f32x16 acc;
    #pragma unroll
    for (int i = 0; i < 16; ++i) acc[i] = 0.0f;

    int sel  = tid >> 7;          // 0: A-frag (m cols), 1: B-frag (n cols)
    int q2   = tid & 127;
    int col  = q2 & 63;           // coalesced: lanes 0..63 -> consecutive cols
    int ssub = q2 >> 6;           // 16-k half
    int c0base = sel ? n0 : m0;
    int rreg = col >> 5;
    int rln  = col & 31;

    float av[16];

    auto loadF = [&](int k0) {
        const float* pp = A + (size_t)(k0 + ssub * 16) * 576 + c0base + col;
        #pragma unroll
        for (int j = 0; j < 16; ++j) av[j] = pp[(size_t)j * 576];
    };
    auto storeF = [&]() {
        unsigned short s0[16], s1[16], s2[16];
        #pragma unroll
        for (int j = 0; j < 16; ++j) split3(av[j], s0[j], s1[j], s2[j]);
        #pragma unroll
        for (int h = 0; h < 2; ++h) {
            int ln = rln + 32 * h;
            pack_store(&Fr[sel*6 + 0*2 + rreg][ssub][ln][0], &s0[8*h]);
            pack_store(&Fr[sel*6 + 1*2 + rreg][ssub][ln][0], &s1[8*h]);
            pack_store(&Fr[sel*6 + 2*2 + rreg][ssub][ln][0], &s2[8*h]);
        }
    };

    const short8v* Ff = (const short8v*)Fr;

    loadF(kBeg);
    for (int k0 = kBeg; k0 < 576; k0 += 32) {
        storeF();
        __syncthreads();
        if (k0 + 32 < 576) loadF(k0 + 32);
        #pragma unroll
        for (int sub = 0; sub < 2; ++sub) {
            short8v a0 = Ff[((0*2 + wr)*2 + sub)*64 + lane];
            short8v a1 = Ff[((1*2 + wr)*2 + sub)*64 + lane];
            short8v a2 = Ff[((2*2 + wr)*2 + sub)*64 + lane];
            short8v b0 = Ff[((6 + 0*2 + wc)*2 + sub)*64 + lane];
            short8v b1 = Ff[((6 + 1*2 + wc)*2 + sub)*64 + lane];
            short8v b2 = Ff[((6 + 2*2 + wc)*2 + sub)*64 + lane];
            acc = __builtin_amdgcn_mfma_f32_32x32x16_bf16(a0, b0, acc, 0, 0, 0);
            acc = __builtin_amdgcn_mfma_f32_32x32x16_bf16(a0, b1, acc, 0, 0, 0);
            acc = __builtin_amdgcn_mfma_f32_32x32x16_bf16(a1, b0, acc, 0, 0, 0);
            acc = __builtin_amdgcn_mfma_f32_32x32x16_bf16(a1, b1, acc, 0, 0, 0);
            acc = __builtin_amdgcn_mfma_f32_32x32x16_bf16(a0, b2, acc, 0, 0, 0);
            acc = __builtin_amdgcn_mfma_f32_32x32x16_bf16(a2, b0, acc, 0, 0, 0);
        }
        __syncthreads();
    }

    int colg = n0 + 32*wc + (lane & 31);
    int rowb = m0 + 32*wr + 4*(lane >> 5);
    #pragma unroll
    for (int reg = 0; reg < 16; ++reg) {
        int row = rowb + (reg & 3) + 8*(reg >> 2);
        float v = acc[reg];
        Cb[(size_t)row * 576 + colg] = v;
        Cb[(size_t)colg * 576 + row] = v;    // mirror (bit-identical value)
    }
}

// ---------------------------------------------------------------------------
// mm_ab_mfma (r6-verified): iW = Kin @ Kinv, direct write.
// ---------------------------------------------------------------------------
__global__ __launch_bounds__(256, 2)
void mm_ab_mfma(const float* __restrict__ Aall, const float* __restrict__ Ball,
                float* __restrict__ Call, long sA, long sB, long sC)
{
    int nx = blockIdx.x % 9, my = blockIdx.x / 9;
    int b = blockIdx.z;
    const float* A = Aall + (size_t)b * sA;   // [m][k]
    const float* B = Ball + (size_t)b * sB;   // [k][n]
    float* Cb = Call + (size_t)b * sC;
    int m0 = my * 64, n0 = nx * 64;

    __shared__ __align__(16) unsigned short Fr[12][2][64][8];   // 24 KB

    int tid  = threadIdx.x;
    int lane = tid & 63;
    int wid  = tid >> 6;
    int wr = wid >> 1, wc = wid & 1;

    f32x16 acc;
    #pragma unroll
    for (int i = 0; i < 16; ++i) acc[i] = 0.0f;

    int sel  = tid >> 7;          // 0: A rows (float4), 1: B cols (scalar)
    int q2   = tid & 127;
    int ar   = q2 >> 1;
    int asub = q2 & 1;
    int areg = ar >> 5, aln = ar & 31;
    int bcol = q2 & 63;
    int bssub = q2 >> 6;
    int breg = bcol >> 5, brln = bcol & 31;

    float av[16];

    auto loadF = [&](int k0) {
        if (sel == 0) {
            const float* pp = A + (size_t)(m0 + ar) * 576 + k0 + asub * 16;
            float4 t0 = *(const float4*)(pp);
            float4 t1 = *(const float4*)(pp + 4);
            float4 t2 = *(const float4*)(pp + 8);
            float4 t3 = *(const float4*)(pp + 12);
            av[0]=t0.x;  av[1]=t0.y;  av[2]=t0.z;  av[3]=t0.w;
            av[4]=t1.x;  av[5]=t1.y;  av[6]=t1.z;  av[7]=t1.w;
            av[8]=t2.x;  av[9]=t2.y;  av[10]=t2.z; av[11]=t2.w;
            av[12]=t3.x; av[13]=t3.y; av[14]=t3.z; av[15]=t3.w;
        } else {
            const float* pp = B + (size_t)(k0 + bssub * 16) * 576 + n0 + bcol;
            #pragma unroll
            for (int j = 0; j < 16; ++j) av[j] = pp[(size_t)j * 576];
        }
    };
    auto storeF = [&]() {
        unsigned short s0[16], s1[16], s2[16];
        #pragma unroll
        for (int j = 0; j < 16; ++j) split3(av[j], s0[j], s1[j], s2[j]);
        int reg0 = sel ? (6 + 0*2 + breg) : (0*2 + areg);
        int reg1 = sel ? (6 + 1*2 + breg) : (1*2 + areg);
        int reg2 = sel ? (6 + 2*2 + breg) : (2*2 + areg);
        int sb   = sel ? bssub : asub;
        int ln0  = sel ? brln : aln;
        #pragma unroll
        for (int h = 0; h < 2; ++h) {
            int ln = ln0 + 32 * h;
            pack_store(&Fr[reg0][sb][ln][0], &s0[8*h]);
            pack_store(&Fr[reg1][sb][ln][0], &s1[8*h]);
            pack_store(&Fr[reg2][sb][ln][0], &s2[8*h]);
        }
    };

    const short8v* Ff = (const short8v*)Fr;

    loadF(0);
    for (int k0 = 0; k0 < 576; k0 += 32) {
        storeF();
        __syncthreads();
        if (k0 + 32 < 576) loadF(k0 + 32);
        #pragma unroll
        for (int sub = 0; sub < 2; ++sub) {
            short8v a0 = Ff[((0*2 + wr)*2 + sub)*64 + lane];
            short8v a1 = Ff[((1*2 + wr)*2 + sub)*64 + lane];
            short8v a2 = Ff[((2*2 + wr)*2 + sub)*64 + lane];
            short8v b0 = Ff[((6 + 0*2 + wc)*2 + sub)*64 + lane];
            short8v b1 = Ff[((6 + 1*2 + wc)*2 + sub)*64 + lane];
            short8v b2 = Ff[((6 + 2*2 + wc)*2 + sub)*64 + lane];
            acc = __builtin_amdgcn_mfma_f32_32x32x16_bf16(a0, b0, acc, 0, 0, 0);
            acc = __builtin_amdgcn_mfma_f32_32x32x16_bf16(a0, b1, acc, 0, 0, 0);
            acc = __builtin_amdgcn_mfma_f32_32x32x16_bf16(a1, b0, acc, 0, 0, 0);
            acc = __builtin_amdgcn_mfma_f32_32x32x16_bf16(a1, b1, acc, 0, 0, 0);
            acc = __builtin_amdgcn_mfma_f32_32x32x16_bf16(a0, b2, acc, 0, 0, 0);
            acc = __builtin_amdgcn_mfma_f32_32x32x16_bf16(a2, b0, acc, 0, 0, 0);
        }
        __syncthreads();
    }

    int colg = n0 + 32*wc + (lane & 31);
    int rowb = m0 + 32*wr + 4*(lane >> 5);
    #pragma unroll
    for (int reg = 0; reg < 16; ++reg) {
        int row = rowb + (reg & 3) + 8*(reg >> 2);
        Cb[(size_t)row * 576 + colg] = acc[reg];
    }
}

// ---------------------------------------------------------------------------
// batched tiled matmul, 64x64 C-tile, 256 threads (4x4 micro), reg prefetch.
// (still used for the small skinny GEMMs: sol_mean, opimean)
// ---------------------------------------------------------------------------
template<int TA, int TB, int SK, int TRI, int SWZ, int EPIB, int TRIC>
__global__ __launch_bounds__(256)
void mm_kernel(const float* __restrict__ Aall, const float* __restrict__ Ball,
               float* __restrict__ Call,
               int M, int N, int K, int planeK,
               int lda, int ldb, int ldc,
               long sA, long sB, long sC, long pA, long pB, long sSplit, int MT)
{
    int nx, my, zz;
    if (TRIC) {
        int p = blockIdx.x;
        int ir = 0;
        while (p >= ir + 1) { p -= ir + 1; ir++; }
        my = ir; nx = p; zz = blockIdx.z;
    } else if (SWZ) {
        int id = blockIdx.x;
        int x8 = id & 7;
        int q  = id >> 3;
        nx = q % 9;
        int band = x8 + 8 * (q / 9);
        if (band >= MT * 4 * SK) return;
        my = band % MT;
        zz = band / MT;
    } else { nx = blockIdx.x; my = blockIdx.y; zz = blockIdx.z; }
    int sp = (SK > 1) ? (zz % SK) : 0;
    int b  = (SK > 1) ? (zz / SK) : zz;
    const float* A = Aall + (size_t)b * sA;
    const float* B = Ball + (size_t)b * sB;
    float* C = Call + (size_t)b * sC + (size_t)sp * sSplit;
    int n0 = nx * 64;
    int m0 = my * 64;

    __shared__ float As[16][68];
    __shared__ float Bs[16][68];

    int tid = threadIdx.x;
    int tx = tid & 15, ty = tid >> 4;

    float acc[4][4] = {};
    bool mFull = (m0 + 64 <= M);
    bool nFull = (n0 + 64 <= N);

    int triBeg = 0;
    if (TRI) { int mx = (m0 > n0 ? m0 : n0); triBeg = mx & ~15; }
    int kBeg = triBeg, kEnd = K;
    if (SK > 1) {
        int len = K - triBeg;
        int chunk = ((len / SK) + 15) & ~15;
        kBeg = triBeg + sp * chunk;
        if (kBeg > K) kBeg = K;
        kEnd = (sp == SK - 1) ? K : (kBeg + chunk < K ? kBeg + chunk : K);
    }

    float avr[4];
    float bvr[4];

    auto loadA = [&](int k0) {
        int plane = k0 / planeK;
        int koff  = k0 - plane * planeK;
        if (TA == 0) {
            const float* Ab = A + (size_t)pA * plane;
            int r = tid >> 2, c4 = (tid & 3) * 4;
            int gm = m0 + r;
            if (mFull || gm < M) {
                float4 t = *(const float4*)(Ab + (size_t)gm * lda + koff + c4);
                avr[0]=t.x; avr[1]=t.y; avr[2]=t.z; avr[3]=t.w;
            } else { avr[0]=avr[1]=avr[2]=avr[3]=0.0f; }
        } else {
            int r = tid >> 4, c4 = (tid & 15) * 4;
            const float* p = A + (size_t)(koff + r) * lda + m0 + c4;
            if (mFull) {
                float4 t = *(const float4*)p;
                avr[0]=t.x; avr[1]=t.y; avr[2]=t.z; avr[3]=t.w;
            } else {
                #pragma unroll
                for (int jj = 0; jj < 4; ++jj)
                    avr[jj] = (m0 + c4 + jj < M) ? p[jj] : 0.0f;
            }
        }
    };
    auto storeA = [&]() {
        if (TA == 0) {
            int r = tid >> 2, c4 = (tid & 3) * 4;
            #pragma unroll
            for (int q = 0; q < 4; ++q) As[c4+q][r] = avr[q];
        } else {
            int r = tid >> 4, c4 = (tid & 15) * 4;
            #pragma unroll
            for (int q = 0; q < 4; ++q) As[r][c4+q] = avr[q];
        }
    };
    auto loadB = [&](int k0) {
        int plane = k0 / planeK;
        int koff  = k0 - plane * planeK;
        if (TB == 0) {
            int r = tid >> 4, c4 = (tid & 15) * 4;
            const float* p = B + (size_t)(koff + r) * ldb + n0 + c4;
            if (nFull) {
                float4 t = *(const float4*)p;
                bvr[0]=t.x; bvr[1]=t.y; bvr[2]=t.z; bvr[3]=t.w;
            } else {
                #pragma unroll
                for (int jj = 0; jj < 4; ++jj)
                    bvr[jj] = (n0 + c4 + jj < N) ? p[jj] : 0.0f;
            }
            if (EPIB) {
                int gk = koff + r;
                #pragma unroll
                for (int jj = 0; jj < 4; ++jj)
                    if (gk == n0 + c4 + jj) bvr[jj] -= 1.0f;
            }
        } else {
            const float* Bb = B + (size_t)pB * plane;
            int r = tid >> 2, c4 = (tid & 3) * 4;
            int gp = n0 + r;
            if (nFull || gp < N) {
                float4 t = *(const float4*)(Bb + (size_t)gp * ldb + koff + c4);
                bvr[0]=t.x; bvr[1]=t.y; bvr[2]=t.z; bvr[3]=t.w;
            } else { bvr[0]=bvr[1]=bvr[2]=bvr[3]=0.0f; }
        }
    };
    auto storeB = [&]() {
        if (TB == 0) {
            int r = tid >> 4, c4 = (tid & 15) * 4;
            #pragma unroll
            for (int q = 0; q < 4; ++q) Bs[r][c4+q] = bvr[q];
        } else {
            int r = tid >> 2, c4 = (tid & 3) * 4;
            #pragma unroll
            for (int q = 0; q < 4; ++q) Bs[c4+q][r] = bvr[q];
        }
    };

    if (kBeg < kEnd) {
        loadA(kBeg); loadB(kBeg);
        for (int k0 = kBeg; k0 < kEnd; k0 += 16) {
            storeA(); storeB();
            __syncthreads();
            if (k0 + 16 < kEnd) { loadA(k0 + 16); loadB(k0 + 16); }
            #pragma unroll
            for (int kk = 0; kk < 16; ++kk) {
                float a[4], bb[4];
                *(float4*)a  = *(const float4*)&As[kk][ty*4];
                *(float4*)bb = *(const float4*)&Bs[kk][tx*4];
                #pragma unroll
                for (int i = 0; i < 4; ++i)
                    #pragma unroll
                    for (int j = 0; j < 4; ++j)
                        acc[i][j] += a[i] * bb[j];
            }
            __syncthreads();
        }
    }

    #pragma unroll
    for (int i = 0; i < 4; ++i) {
        int gm = m0 + ty*4 + i;
        if (gm >= M) continue;
        #pragma unroll
        for (int j = 0; j < 4; ++j) {
            int gn = n0 + tx*4 + j;
            if (gn >= N) continue;
            C[(size_t)gm * ldc + gn] = acc[i][j];
        }
    }
}

// ---------------------------------------------------------------------------
// combine kernels
// ---------------------------------------------------------------------------
__global__ void combine_solm4(const float* __restrict__ p, float* __restrict__ o) {
    int i = blockIdx.x * 256 + threadIdx.x;   // 73728 elems -> 288 WGs
    o[i] = p[i] + p[i + 73728] + p[i + 2*73728] + p[i + 3*73728];
}

// symmetric combine: partials valid only for m>=n; prior symmetric; write both
__global__ void combine_prior4_sym(const float* __restrict__ p0,
                                   const float* __restrict__ xin,
                                   const float* __restrict__ W2g,
                                   float* __restrict__ o, long stride) {
    __shared__ float w[16];
    int tid = threadIdx.x;
    if (tid < 16) w[tid] = W2g[tid];
    __syncthreads();
    int idx = blockIdx.x * 256 + tid;           // over 4*N2
    int b = idx / N2;
    int rem = idx - b * N2;
    int m = rem / NPTS, n = rem - m * NPTS;
    if (m < n) return;
    const float* xb = xin + (size_t)b * NPTS * 2;
    float r0 = xb[m*2+0] - xb[n*2+0];
    float r1 = xb[m*2+1] - xb[n*2+1];
    float u = (r0*r0 + r1*r1) * INVL2;
    float Kv = expf(-0.5f * u);
    float i2 = INVL2 * INVL2;
    float gK0 = r0 * INVL2 * Kv;
    float gK1 = r1 * INVL2 * Kv;
    float lapK = (u - 2.0f) * INVL2 * Kv;
    float gg00 = (INVL2 - r0*r0*i2) * Kv;
    float gg01 = (-r0*r1*i2) * Kv;
    float gg11 = (INVL2 - r1*r1*i2) * Kv;
    float gl0 = r0 * i2 * (4.0f - u) * Kv;
    float gl1 = r1 * i2 * (4.0f - u) * Kv;
    float ll = ((u-2.0f)*(u-2.0f) - 4.0f*u + 4.0f) * i2 * Kv;
    float prior =
          w[0]*Kv + w[1]*gK0 + w[2]*gK1 + w[3]*lapK
        + w[4]*(-gK0) + w[5]*gg00 + w[6]*gg01 + w[7]*gl0
        + w[8]*(-gK1) + w[9]*gg01 + w[10]*gg11 + w[11]*gl1
        + w[12]*lapK + w[13]*(-gl0) + w[14]*(-gl1) + w[15]*ll;
    float v = p0[idx] + p0[idx + stride] + p0[idx + 2*stride] + p0[idx + 3*stride]
            + prior;
    if (m == n) v += 1.1e-4f;
    o[(size_t)b * N2 + (size_t)m * NPTS + n] = v;
    if (m != n)
        o[(size_t)b * N2 + (size_t)n * NPTS + m] = v;
}

// ---------------------------------------------------------------------------
// opiKW2[b][i] = sum_j W2[i][j] * opiK[b][j]  — safe in-place (per-element)
// ---------------------------------------------------------------------------
__global__ void opiw2_k(const float* __restrict__ opiK, const float* __restrict__ W2,
                        float* __restrict__ outB) {
    int idx = blockIdx.x * 256 + threadIdx.x;
    int b = idx / N2;
    int rem = idx - b * N2;
    size_t base = (size_t)b * 4 * N2 + rem;
    float k0 = opiK[base], k1 = opiK[base + N2], k2 = opiK[base + 2*N2], k3 = opiK[base + 3*N2];
    #pragma unroll
    for (int i = 0; i < 4; ++i)
        outB[base + (size_t)i * N2] = W2[i*4+0]*k0 + W2[i*4+1]*k1 + W2[i*4+2]*k2 + W2[i*4+3]*k3;
}

// ---------------------------------------------------------------------------
__global__ __launch_bounds__(256)
void amean_k(const float* __restrict__ opimean, const float* __restrict__ weight,
             const float* __restrict__ bias, float* __restrict__ out) {
    int b = blockIdx.y;
    int m0 = blockIdx.x * 32;
    __shared__ float Wl[64][128];
    __shared__ float om[32][128];
    int tid = threadIdx.x;
    for (int idx = tid; idx < 64*128; idx += 256) Wl[idx / 128][idx & 127] = weight[idx];
    for (int idx = tid; idx < 32*128; idx += 256) {
        int m = idx >> 7, ck = idx & 127, c = ck >> 2, kop = ck & 3;
        om[m][ck] = opimean[((size_t)b * 4 + kop) * NPTS * 32 + (size_t)(m0 + m) * 32 + c];
    }
    __syncthreads();
    int ml = tid >> 3, o0 = (tid & 7) * 8;
    float acc[8] = {};
    for (int ck = 0; ck < 128; ++ck) {
        float v = om[ml][ck];
        #pragma unroll
        for (int q = 0; q < 8; ++q) acc[q] += v * Wl[o0+q][ck];
    }
    #pragma unroll
    for (int q = 0; q < 8; ++q)
        out[4608 + ((size_t)b * NPTS + m0 + ml) * 64 + o0 + q] = acc[q] + bias[o0+q];
}

// ---------------------------------------------------------------------------
static inline int gridSwz(int MT, int Z) { return 8 * 9 * ((MT * Z + 7) / 8); }

extern "C" void kernel_launch(void* const* d_in, const int* in_sizes, int n_in,
                              void* d_out, int out_size, void* d_ws, size_t ws_size,
                              hipStream_t stream) {
    const float* xin    = (const float*)d_in[0];
    const float* meanin = (const float*)d_in[1];
    const float* Kin    = (const float*)d_in[2];
    const float* weight = (const float*)d_in[3];
    const float* bias   = (const float*)d_in[4];
    float* out = (float*)d_out;
    float* ws  = (float*)d_ws;

    const long N2L = N2;
    float* W2      = ws;                       // 16 (pad 64)
    float* LinvKK  = ws + 64;                  // 4*9*4096
    float* R1 = LinvKK + 147456;               // 4*N2: Kxx/A; later iW (direct)
    float* R2 = R1 + 4*N2L;                    // 4*N2: Linv; later solm/opim
    float* R3 = R2 + 4*N2L;                    // 4*N2: L panels; later Kinv (direct)
    float* R4 = R3 + 4*N2L;                    // 16*N2: opiK; later opiKW2 (in-place)
    float* R5 = R4 + 16*N2L;                   // 16*N2: KiO (direct); final partials
    float* R6 = R5 + 16*N2L;                   // 16*N2: solm partials; H'

    // zero Linv (upper triangle must be 0)
    hipMemsetAsync(R2, 0, (size_t)4 * N2 * sizeof(float), stream);
    // build_k: Kxx + opiK + fused copy_xout + fused w2
    build_k<<<dim3((BSZ*N2)/256), dim3(256), 0, stream>>>(
        xin, R1, R4, out, weight, W2);
    // Cholesky: 9 launches. L panels -> R3; diag inverses -> LinvKK
    chol_diag0<<<dim3(BSZ), dim3(256), 0, stream>>>(R1, LinvKK);
    for (int kb = 0; kb < NT - 1; ++kb) {
        int t = NT - 1 - kb;
        chol_step<<<dim3(t*(t+1)/2, BSZ), dim3(256), 0, stream>>>(R1, R3, LinvKK, kb);
    }
    // triangular inverse (named-reg prefetch staging) -> R2
    trinv_blk<<<dim3(4, NT, BSZ), dim3(256), 0, stream>>>(R3, LinvKK, R2);
    // Kinv = Linv^T @ Linv  (bf16x3 MFMA, sym lower tiles + mirror, direct -> R3)
    mm_ata_mfma<<<dim3(45, 1, BSZ), dim3(256), 0, stream>>>(R2, R3, N2L, N2L);
    // sol_mean = Kinv @ meanin  (SK4 partials -> R6; combine -> R2)
    mm_kernel<0,0,4,0,0,0,0><<<dim3(1,9,16), dim3(256), 0, stream>>>(
        R3, meanin, R6, 576,32,576,576, 576,32,32,
        N2L,18432,18432, 0,0, 73728, 9);
    combine_solm4<<<dim3(288), dim3(256), 0, stream>>>(R6, R2);
    // opimean = opiK @ sol_mean -> R2+73728
    mm_kernel<0,0,1,0,0,0,0><<<dim3(1,36,BSZ), dim3(256), 0, stream>>>(
        R4, R2, R2 + 73728, 2304,32,576,576, 576,32,32,
        4*N2L,18432,73728, 0,0, 0, 9);
    amean_k<<<dim3(18,BSZ), dim3(256), 0, stream>>>(R2 + 73728, weight, bias, out);
    // iW = Kin @ Kinv  (bf16x3 MFMA, direct -> R1, no combine)
    mm_ab_mfma<<<dim3(81, 1, BSZ), dim3(256), 0, stream>>>(
        Kin, R3, R1, N2L, N2L, N2L);
    // KiO = opiK @ Kinv  (bf16x3 MFMA, full-K, direct write -> R5, no combine)
    mm_p2_mfma<0><<<dim3(gridSwz(18,4)), dim3(256), 0, stream>>>(
        R4, R3, R5, 4*N2L, N2L, 4*N2L);
    // opiKW2 in-place on R4 (opiK no longer needed)
    opiw2_k<<<dim3((BSZ*N2)/256), dim3(256), 0, stream>>>(R4, W2, R4);
    // H' = KiO @ (iW - I)  (bf16x3 MFMA, -I fold) -> R6
    mm_p2_mfma<1><<<dim3(gridSwz(18,4)), dim3(256), 0, stream>>>(
        R5, R1, R6, 4*N2L, N2L, 4*N2L);
    // final AKA partial GEMM — SYMMETRIC lower tiles, MFMA, SK4 = plane-split.
    // partials -> R5 (sC=N2 batch plane, sSplit=4*N2 split plane)
    mm_abt_mfma<<<dim3(45,1,BSZ*4), dim3(256), 0, stream>>>(
        R6, R4, R5, 4*N2L, 4*N2L, N2L, 4*N2L);
    // output 2: combine 4 partials (m>=n) + analytic prior + jitter, mirrored
    combine_prior4_sym<<<dim3(5184), dim3(256), 0, stream>>>(
        R5, xin, W2, out + 152064, 4*N2L);
}

// Round 11
// 855.318 us; speedup vs baseline: 1.0688x; 1.0224x over previous
//
#include <hip/hip_runtime.h>
#include <math.h>

#define NPTS 576
#define N2 331776           // 576*576
#define BSZ 4
#define NB 64               // cholesky block
#define NT 9                // 576/64

#define INVL2 (1.0f/0.29311396f)

typedef __attribute__((ext_vector_type(8))) short short8v;   // 8 bf16 (4 VGPRs)
typedef __attribute__((ext_vector_type(16))) float f32x16;   // MFMA 32x32 acc

// ---------------------------------------------------------------------------
// build Kxx (+jitter) and opiK (4 planes) from xin; fused copy_xout + w2.
// ---------------------------------------------------------------------------
__global__ void build_k(const float* __restrict__ xin,
                        float* __restrict__ Kxx, float* __restrict__ opiK,
                        float* __restrict__ out,
                        const float* __restrict__ w, float* __restrict__ W2) {
    int idx = blockIdx.x * 256 + threadIdx.x;
    if (idx < 4608) out[idx] = xin[idx];     // fused copy_xout
    int b = idx / N2;
    int rem = idx - b * N2;
    int m = rem / NPTS;
    int nn = rem - m * NPTS;
    const float* xb = xin + (size_t)b * NPTS * 2;
    float xm0 = xb[m*2],  xm1 = xb[m*2+1];
    float xn0 = xb[nn*2], xn1 = xb[nn*2+1];
    float r0 = xm0 - xn0, r1 = xm1 - xn1;
    float u = (r0*r0 + r1*r1) * INVL2;
    float Kv = expf(-0.5f * u);
    Kxx[idx] = Kv + ((m == nn) ? 1e-5f : 0.0f);
    size_t base = (size_t)b * 4 * N2 + rem;
    opiK[base]          = Kv;
    opiK[base + N2]     = -r0 * INVL2 * Kv;
    opiK[base + 2*N2]   = -r1 * INVL2 * Kv;
    opiK[base + 3*N2]   = (u - 2.0f) * INVL2 * Kv;
    // fused w2 (one WG): W2[i][j] = mean_o sum_c w[o][c][i] w[o][c][j]
    if (blockIdx.x == 5183) {
        __shared__ float red[256];
        int tid = threadIdx.x;
        int pair = tid & 15;
        int slice = tid >> 4;
        int i = pair >> 2, j = pair & 3;
        float s = 0.0f;
        for (int o = slice * 4; o < slice * 4 + 4; ++o)
            for (int c = 0; c < 32; ++c)
                s += w[o*128 + c*4 + i] * w[o*128 + c*4 + j];
        red[tid] = s;
        __syncthreads();
        if (tid < 16) {
            float t = 0.0f;
            #pragma unroll
            for (int k = 0; k < 16; ++k) t += red[pair + 16*k];
            W2[pair] = t * (1.0f/64.0f);
        }
    }
}

// ---------------------------------------------------------------------------
// factor 64x64 SPD block in T (lower), produce V = T^{-1} (lower).
// r4: panel factor row-per-lane in registers + __shfl (no LDS on the chain).
// r5: diag 16x16 inverse also register+shuffle. Block-solve r0 verbatim.
// ---------------------------------------------------------------------------
__device__ void factor_invert_64(float (*T)[NB+1], float (*V)[NB+1],
                                 float (*tmp)[17], int tid) {
    for (int p = 0; p < 4; ++p) {
        int cp = p * 16;
        if (tid < 64) {
            int r = tid;
            float reg[16];
            #pragma unroll
            for (int q = 0; q < 16; ++q) reg[q] = T[r][cp + q];
            #pragma unroll
            for (int j = 0; j < 16; ++j) {
                int col = cp + j;
                float d2 = __shfl(reg[j], col);          // pivot (pre-sqrt)
                float d = sqrtf(fmaxf(d2, 1e-12f));
                float lr = (r == col) ? d : reg[j] / d;  // junk for r<col, unused
                reg[j] = lr;
                #pragma unroll
                for (int q = j + 1; q < 16; ++q) {
                    float lc = __shfl(lr, cp + q);       // L[cp+q][col]
                    if (r >= cp + q) reg[q] -= lr * lc;
                }
            }
            #pragma unroll
            for (int q = 0; q < 16; ++q) T[r][cp + q] = reg[q];
        }
        __syncthreads();
        int tr = 48 - cp;
        if (tr > 0) {
            for (int idx = tid; idx < tr * tr; idx += 256) {
                int r = cp + 16 + idx / tr;
                int c = cp + 16 + idx % tr;
                if (c <= r) {
                    float s = 0.0f;
                    #pragma unroll
                    for (int k = 0; k < 16; ++k) s += T[r][cp+k] * T[c][cp+k];
                    T[r][c] -= s;
                }
            }
        }
        __syncthreads();
    }
    // diag 16x16 inverses: column-per-lane forward substitution in registers.
    if (tid < 64) {
        int I = tid >> 4, c = tid & 15, base = I * 16;
        float tcol[16];
        #pragma unroll
        for (int i = 0; i < 16; ++i) tcol[i] = T[base + i][base + c];
        float v[16];
        #pragma unroll
        for (int i = 0; i < 16; ++i) {
            float s = (i == c) ? 1.0f : 0.0f;
            #pragma unroll
            for (int k = 0; k < 16; ++k) {
                if (k < i) {                              // compile-time mask
                    float tik = __shfl(tcol[i], base + k);
                    s -= tik * v[k];
                }
            }
            float tii = __shfl(tcol[i], base + i);
            v[i] = s / tii;                               // exact 0 for i<c
        }
        #pragma unroll
        for (int i = 0; i < 16; ++i) V[base + i][base + c] = v[i];
    }
    __syncthreads();
    const int PI[6] = {1,2,3,2,3,3};
    const int PJ[6] = {0,1,2,0,1,0};
    int rr16 = tid >> 4, cc16 = tid & 15;
    for (int p = 0; p < 6; ++p) {
        int I = PI[p], J = PJ[p];
        float s = 0.0f;
        for (int K = J; K < I; ++K)
            #pragma unroll
            for (int t = 0; t < 16; ++t)
                s += T[I*16+rr16][K*16+t] * V[K*16+t][J*16+cc16];
        tmp[rr16][cc16] = s;
        __syncthreads();
        float s2 = 0.0f;
        for (int t = 0; t <= rr16; ++t) s2 += V[I*16+rr16][I*16+t] * tmp[t][cc16];
        __syncthreads();
        V[I*16+rr16][J*16+cc16] = -s2;
        __syncthreads();
    }
}

// ---------------------------------------------------------------------------
__global__ void chol_diag0(const float* __restrict__ A, float* __restrict__ LinvKK) {
    int b = blockIdx.x;
    const float* Ab = A + (size_t)b * N2;
    __shared__ float T[NB][NB+1];
    __shared__ float V[NB][NB+1];
    __shared__ float tmp[16][17];
    int tid = threadIdx.x;
    for (int idx = tid; idx < NB*NB; idx += 256) {
        int r = idx >> 6, c = idx & 63;
        T[r][c] = Ab[(size_t)r * NPTS + c];
        V[r][c] = 0.0f;
    }
    __syncthreads();
    factor_invert_64(T, V, tmp, tid);
    float* Vg = LinvKK + (size_t)b * NT * NB * NB;
    for (int idx = tid; idx < NB*NB; idx += 256) Vg[idx] = V[idx >> 6][idx & 63];
}

// ---------------------------------------------------------------------------
// fused Cholesky step for panel kb. 9 total launches.
// ---------------------------------------------------------------------------
__global__ __launch_bounds__(256)
void chol_step(float* __restrict__ A, float* __restrict__ LL,
               float* __restrict__ LinvKK, int kb) {
    int b = blockIdx.y;
    int p = blockIdx.x;
    int ir = 0;
    while (p >= ir + 1) { p -= ir + 1; ir++; }
    int ib = kb + 1 + ir, jb = kb + 1 + p;
    float* Ab = A + (size_t)b * N2;
    float* LLb = LL + (size_t)b * N2;
    __shared__ float Ai[NB][NB+1];
    __shared__ float Aj[NB][NB+1];
    __shared__ float Vs[NB][NB+1];
    __shared__ float tmp[16][17];
    int tid = threadIdx.x;
    int tx = tid & 15, ty = tid >> 4;
    const float* Vg = LinvKK + ((size_t)b * NT + kb) * NB * NB;
    bool diag = (ib == jb);
    for (int idx = tid; idx < NB*NB; idx += 256) {
        int r = idx >> 6, c = idx & 63;
        Ai[r][c] = Ab[(size_t)(ib*NB + r) * NPTS + kb*NB + c];
        Aj[r][c] = diag ? 0.0f : Ab[(size_t)(jb*NB + r) * NPTS + kb*NB + c];
        Vs[r][c] = Vg[idx];
    }
    float U[4][4];
    #pragma unroll
    for (int i = 0; i < 4; ++i)
        #pragma unroll
        for (int j = 0; j < 4; ++j)
            U[i][j] = Ab[(size_t)(ib*NB + ty*4+i) * NPTS + jb*NB + tx*4+j];
    __syncthreads();
    float Li[4][4] = {}, Lj[4][4] = {};
    for (int k = 0; k < NB; ++k) {
        float a[4], v[4];
        #pragma unroll
        for (int i = 0; i < 4; ++i) a[i] = Ai[ty*4+i][k];
        #pragma unroll
        for (int j = 0; j < 4; ++j) v[j] = Vs[tx*4+j][k];
        #pragma unroll
        for (int i = 0; i < 4; ++i)
            #pragma unroll
            for (int j = 0; j < 4; ++j) Li[i][j] += a[i] * v[j];
        if (!diag) {
            float aj[4];
            #pragma unroll
            for (int i = 0; i < 4; ++i) aj[i] = Aj[ty*4+i][k];
            #pragma unroll
            for (int i = 0; i < 4; ++i)
                #pragma unroll
                for (int j = 0; j < 4; ++j) Lj[i][j] += aj[i] * v[j];
        }
    }
    __syncthreads();
    #pragma unroll
    for (int i = 0; i < 4; ++i)
        #pragma unroll
        for (int j = 0; j < 4; ++j) {
            Ai[ty*4+i][tx*4+j] = Li[i][j];
            Aj[ty*4+i][tx*4+j] = diag ? Li[i][j] : Lj[i][j];
        }
    if (diag) {
        #pragma unroll
        for (int i = 0; i < 4; ++i)
            #pragma unroll
            for (int j = 0; j < 4; ++j)
                LLb[(size_t)(ib*NB + ty*4+i) * NPTS + kb*NB + tx*4+j] = Li[i][j];
    }
    __syncthreads();
    float s[4][4] = {};
    for (int k = 0; k < NB; ++k) {
        float a[4], v[4];
        #pragma unroll
        for (int i = 0; i < 4; ++i) a[i] = Ai[ty*4+i][k];
        #pragma unroll
        for (int j = 0; j < 4; ++j) v[j] = Aj[tx*4+j][k];
        #pragma unroll
        for (int i = 0; i < 4; ++i)
            #pragma unroll
            for (int j = 0; j < 4; ++j) s[i][j] += a[i] * v[j];
    }
    #pragma unroll
    for (int i = 0; i < 4; ++i)
        #pragma unroll
        for (int j = 0; j < 4; ++j) U[i][j] -= s[i][j];
    if (blockIdx.x != 0) {
        #pragma unroll
        for (int i = 0; i < 4; ++i)
            #pragma unroll
            for (int j = 0; j < 4; ++j)
                Ab[(size_t)(ib*NB + ty*4+i) * NPTS + jb*NB + tx*4+j] = U[i][j];
        return;
    }
    __syncthreads();
    #pragma unroll
    for (int i = 0; i < 4; ++i)
        #pragma unroll
        for (int j = 0; j < 4; ++j) Ai[ty*4+i][tx*4+j] = U[i][j];
    for (int idx = tid; idx < NB*NB; idx += 256) Aj[idx >> 6][idx & 63] = 0.0f;
    __syncthreads();
    factor_invert_64(Ai, Aj, tmp, tid);
    float* Vo = LinvKK + ((size_t)b * NT + (kb + 1)) * NB * NB;
    for (int idx = tid; idx < NB*NB; idx += 256) Vo[idx] = Aj[idx >> 6][idx & 63];
}

// ---------------------------------------------------------------------------
// blocked triangular inverse. grid (4 col-splits, 9 block-cols, 4 batch)
// r11: trinv is ds_read ISSUE-bound (broadcast makes data traffic tiny).
// 4x4 register tiling + 4-way k-split: thread (kq,rg,cg) does 16 FMA per
// 2 b128 reads (was 4 per b128+b32) -> 4x fewer ds_read issues. k-partials
// stay in registers across kb stages; one LDS reduce per ib (Red buffer).
// Xc/Ss stride 20 for aligned b128. r10 named-reg prefetch retained.
// ---------------------------------------------------------------------------
__global__ __launch_bounds__(256)
void trinv_blk(const float* __restrict__ L, const float* __restrict__ LinvKK,
               float* __restrict__ Linv) {
    int sp = blockIdx.x, jb = blockIdx.y, b = blockIdx.z;
    const float* Lb = L + (size_t)b * N2;
    float* Xg = Linv + (size_t)b * N2;
    const float* Vg = LinvKK + (size_t)b * NT * NB * NB;
    int c0 = jb * NB + sp * 16;

    __shared__ float LsT[64][72];     // 18 KB
    __shared__ float Xc[576][20];     // 46 KB
    __shared__ float Ss[64][20];      //  5 KB
    __shared__ float Red[4][64][20];  // 20 KB  (kq-partial reduce buffer)

    int tid = threadIdx.x;
    int kq = tid >> 6;                // wave id = k-slice 0..3
    int rg = (tid >> 2) & 15;         // row group (4 rows)
    int cg = tid & 3;                 // col group (4 cols)
    int sr = tid >> 2, st0 = (tid & 3) * 16;   // staging coords

    float4 pf0, pf1, pf2, pf3;        // named regs (NOT an array; r8 lesson)

#define TRINV_ISSUE_L(ibv, kbv)                                               \
    { const float* src_ = Lb + (size_t)((ibv) * NB + sr) * NPTS + (kbv) * NB + st0; \
      pf0 = *(const float4*)(src_ + 0);  pf1 = *(const float4*)(src_ + 4);    \
      pf2 = *(const float4*)(src_ + 8);  pf3 = *(const float4*)(src_ + 12); }

#define TRINV_ISSUE_V(ibv)                                                    \
    { const float* src_ = Vg + (size_t)(ibv) * NB * NB + sr * NB + st0;       \
      pf0 = *(const float4*)(src_ + 0);  pf1 = *(const float4*)(src_ + 4);    \
      pf2 = *(const float4*)(src_ + 8);  pf3 = *(const float4*)(src_ + 12); }

#define TRINV_COMMIT()                                                        \
    { LsT[st0 + 0][sr]  = pf0.x; LsT[st0 + 1][sr]  = pf0.y;                   \
      LsT[st0 + 2][sr]  = pf0.z; LsT[st0 + 3][sr]  = pf0.w;                   \
      LsT[st0 + 4][sr]  = pf1.x; LsT[st0 + 5][sr]  = pf1.y;                   \
      LsT[st0 + 6][sr]  = pf1.z; LsT[st0 + 7][sr]  = pf1.w;                   \
      LsT[st0 + 8][sr]  = pf2.x; LsT[st0 + 9][sr]  = pf2.y;                   \
      LsT[st0 + 10][sr] = pf2.z; LsT[st0 + 11][sr] = pf2.w;                   \
      LsT[st0 + 12][sr] = pf3.x; LsT[st0 + 13][sr] = pf3.y;                   \
      LsT[st0 + 14][sr] = pf3.z; LsT[st0 + 15][sr] = pf3.w; }

    {
        const float* Vjj = Vg + (size_t)jb * NB * NB;
        int r = tid >> 2, c4 = (tid & 3) * 4;
        float4 v = *(const float4*)(Vjj + r * NB + sp * 16 + c4);
        *(float4*)&Xc[r][c4] = v;
        *(float4*)(Xg + (size_t)(jb * NB + r) * NPTS + c0 + c4) = v;
    }
    if (jb + 1 < NT) TRINV_ISSUE_L(jb + 1, jb);
    __syncthreads();

    for (int ib = jb + 1; ib < NT; ++ib) {
        float acc[4][4] = {};
        for (int kb = jb; kb < ib; ++kb) {
            TRINV_COMMIT();                    // pf -> LsT
            __syncthreads();
            if (kb + 1 < ib) { TRINV_ISSUE_L(ib, kb + 1); }
            else             { TRINV_ISSUE_V(ib); }
            int xbase = (kb - jb) * 64;
            #pragma unroll
            for (int t = 0; t < 16; ++t) {
                int k = kq * 16 + t;
                float a4[4]; *(float4*)a4 = *(const float4*)&LsT[k][rg * 4];
                float x4[4]; *(float4*)x4 = *(const float4*)&Xc[xbase + k][cg * 4];
                #pragma unroll
                for (int i = 0; i < 4; ++i)
                    #pragma unroll
                    for (int j = 0; j < 4; ++j)
                        acc[i][j] += a4[i] * x4[j];
            }
            __syncthreads();
        }
        TRINV_COMMIT();                        // V tile -> LsT
        // reduce acc over kq -> Ss
        #pragma unroll
        for (int i = 0; i < 4; ++i)
            *(float4*)&Red[kq][rg * 4 + i][cg * 4] = *(float4*)&acc[i][0];
        __syncthreads();
        {
            int r = tid >> 2, c4 = (tid & 3) * 4;
            float4 s0 = *(float4*)&Red[0][r][c4];
            float4 s1 = *(float4*)&Red[1][r][c4];
            float4 s2 = *(float4*)&Red[2][r][c4];
            float4 s3 = *(float4*)&Red[3][r][c4];
            float4 s; s.x = s0.x + s1.x + s2.x + s3.x;
            s.y = s0.y + s1.y + s2.y + s3.y;
            s.z = s0.z + s1.z + s2.z + s3.z;
            s.w = s0.w + s1.w + s2.w + s3.w;
            *(float4*)&Ss[r][c4] = s;
        }
        __syncthreads();
        if (ib + 1 < NT) TRINV_ISSUE_L(ib + 1, jb);
        float acc2[4][4] = {};
        #pragma unroll
        for (int t = 0; t < 16; ++t) {
            int k = kq * 16 + t;
            float a4[4]; *(float4*)a4 = *(const float4*)&LsT[k][rg * 4];
            float s4[4]; *(float4*)s4 = *(const float4*)&Ss[k][cg * 4];
            #pragma unroll
            for (int i = 0; i < 4; ++i)
                #pragma unroll
                for (int j = 0; j < 4; ++j)
                    acc2[i][j] += a4[i] * s4[j];
        }
        __syncthreads();
        #pragma unroll
        for (int i = 0; i < 4; ++i)
            *(float4*)&Red[kq][rg * 4 + i][cg * 4] = *(float4*)&acc2[i][0];
        __syncthreads();
        int obase = (ib - jb) * 64;
        {
            int r = tid >> 2, c4 = (tid & 3) * 4;
            float4 s0 = *(float4*)&Red[0][r][c4];
            float4 s1 = *(float4*)&Red[1][r][c4];
            float4 s2 = *(float4*)&Red[2][r][c4];
            float4 s3 = *(float4*)&Red[3][r][c4];
            float4 s; s.x = -(s0.x + s1.x + s2.x + s3.x);
            s.y = -(s0.y + s1.y + s2.y + s3.y);
            s.z = -(s0.z + s1.z + s2.z + s3.z);
            s.w = -(s0.w + s1.w + s2.w + s3.w);
            *(float4*)&Xc[obase + r][c4] = s;
            *(float4*)(Xg + (size_t)(ib * NB + r) * NPTS + c0 + c4) = s;
        }
        __syncthreads();
    }
#undef TRINV_ISSUE_L
#undef TRINV_ISSUE_V
#undef TRINV_COMMIT
}

// ---------------------------------------------------------------------------
// bf16x3 split helpers for fp32-precision MFMA GEMM.
// ---------------------------------------------------------------------------
__device__ inline void split3(float v, unsigned short& h0, unsigned short& h1,
                              unsigned short& h2) {
    unsigned u0 = __float_as_uint(v) & 0xffff0000u;
    float f0 = __uint_as_float(u0);
    float r1 = v - f0;                       // exact
    unsigned u1 = __float_as_uint(r1) & 0xffff0000u;
    float f1 = __uint_as_float(u1);
    float r2 = r1 - f1;                      // exact
    h0 = (unsigned short)(u0 >> 16);
    h1 = (unsigned short)(u1 >> 16);
    h2 = (unsigned short)((__float_as_uint(r2) + 0x8000u) >> 16);  // RNE-ish
}

__device__ inline void pack_store(unsigned short* dst, const unsigned short* v) {
    uint4 w;
    w.x = (unsigned)v[0] | ((unsigned)v[1] << 16);
    w.y = (unsigned)v[2] | ((unsigned)v[3] << 16);
    w.z = (unsigned)v[4] | ((unsigned)v[5] << 16);
    w.w = (unsigned)v[6] | ((unsigned)v[7] << 16);
    *(uint4*)dst = w;
}

// ---------------------------------------------------------------------------
// mm_p2_mfma: plane-pair GEMM C[p] = A[p] @ B (bf16x3, 6 MFMAs/product).
// ---------------------------------------------------------------------------
template<int EPIB>
__global__ __launch_bounds__(256, 2)
void mm_p2_mfma(const float* __restrict__ Aall, const float* __restrict__ Ball,
                float* __restrict__ Call, long sA, long sB, long sC)
{
    int id = blockIdx.x;
    int x8 = id & 7, qq = id >> 3;
    int nx = qq % 9;
    int band = x8 + 8 * (qq / 9);
    if (band >= 18 * BSZ) return;
    int t  = band % 18;
    int b  = band / 18;
    int pp = t / 9, my = t % 9;
    const float* A0 = Aall + (size_t)b * sA + (size_t)(pp * 2) * N2;
    const float* A1 = A0 + N2;
    const float* B  = Ball + (size_t)b * sB;
    float* C0 = Call + (size_t)b * sC + (size_t)(pp * 2) * N2;
    float* C1 = C0 + N2;
    int n0 = nx * 64, m0 = my * 64;

    __shared__ __align__(16) unsigned short As[12][2][64][8];   // 24 KB
    __shared__ __align__(16) unsigned short Bs[6][2][64][8];    // 12 KB

    int tid  = threadIdx.x;
    int lane = tid & 63;
    int wid  = tid >> 6;
    int wr = wid >> 1, wc = wid & 1;

    f32x16 acc0, acc1;
    #pragma unroll
    for (int i = 0; i < 16; ++i) { acc0[i] = 0.0f; acc1[i] = 0.0f; }

    int ap   = tid >> 7;
    int aq   = tid & 127;
    int ar   = aq >> 1;
    int asub = aq & 1;
    const float* Apl = ap ? A1 : A0;
    int areg = ar >> 5;
    int aln  = ar & 31;

    int bc   = tid & 63;
    int bkg  = tid >> 6;
    int bsub = bkg >> 1;
    int bln  = (bc & 31) + 32 * (bkg & 1);
    int bwc  = bc >> 5;

    float av[16];
    float bv[8];

    auto loadA = [&](int k0) {
        const float* p = Apl + (size_t)(m0 + ar) * 576 + k0 + asub * 16;
        float4 t0 = *(const float4*)(p);
        float4 t1 = *(const float4*)(p + 4);
        float4 t2 = *(const float4*)(p + 8);
        float4 t3 = *(const float4*)(p + 12);
        av[0]=t0.x;  av[1]=t0.y;  av[2]=t0.z;  av[3]=t0.w;
        av[4]=t1.x;  av[5]=t1.y;  av[6]=t1.z;  av[7]=t1.w;
        av[8]=t2.x;  av[9]=t2.y;  av[10]=t2.z; av[11]=t2.w;
        av[12]=t3.x; av[13]=t3.y; av[14]=t3.z; av[15]=t3.w;
    };
    auto loadB = [&](int k0) {
        const float* p = B + (size_t)(k0 + bkg * 8) * 576 + n0 + bc;
        #pragma unroll
        for (int j = 0; j < 8; ++j) {
            float v = p[(size_t)j * 576];
            if (EPIB) { if (k0 + bkg * 8 + j == n0 + bc) v -= 1.0f; }
            bv[j] = v;
        }
    };
    auto storeA = [&]() {
        unsigned short s0[16], s1[16], s2[16];
        #pragma unroll
        for (int j = 0; j < 16; ++j) split3(av[j], s0[j], s1[j], s2[j]);
        #pragma unroll
        for (int h = 0; h < 2; ++h) {
            int ln = aln + 32 * h;
            pack_store(&As[(ap*3 + 0)*2 + areg][asub][ln][0], &s0[8*h]);
            pack_store(&As[(ap*3 + 1)*2 + areg][asub][ln][0], &s1[8*h]);
            pack_store(&As[(ap*3 + 2)*2 + areg][asub][ln][0], &s2[8*h]);
        }
    };
    auto storeB = [&]() {
        unsigned short s0[8], s1[8], s2[8];
        #pragma unroll
        for (int j = 0; j < 8; ++j) split3(bv[j], s0[j], s1[j], s2[j]);
        pack_store(&Bs[0*2 + bwc][bsub][bln][0], s0);
        pack_store(&Bs[1*2 + bwc][bsub][bln][0], s1);
        pack_store(&Bs[2*2 + bwc][bsub][bln][0], s2);
    };

    const short8v* Af = (const short8v*)As;
    const short8v* Bf = (const short8v*)Bs;

    loadA(0); loadB(0);
    for (int k0 = 0; k0 < 576; k0 += 32) {
        storeA(); storeB();
        __syncthreads();
        if (k0 + 32 < 576) { loadA(k0 + 32); loadB(k0 + 32); }
        #pragma unroll
        for (int sub = 0; sub < 2; ++sub) {
            short8v b0 = Bf[((0*2 + wc)*2 + sub)*64 + lane];
            short8v b1 = Bf[((1*2 + wc)*2 + sub)*64 + lane];
            short8v b2 = Bf[((2*2 + wc)*2 + sub)*64 + lane];
            short8v a0 = Af[((0*3 + 0)*2 + wr)*128 + sub*64 + lane];
            short8v a1 = Af[((0*3 + 1)*2 + wr)*128 + sub*64 + lane];
            short8v a2 = Af[((0*3 + 2)*2 + wr)*128 + sub*64 + lane];
            acc0 = __builtin_amdgcn_mfma_f32_32x32x16_bf16(a0, b0, acc0, 0, 0, 0);
            acc0 = __builtin_amdgcn_mfma_f32_32x32x16_bf16(a0, b1, acc0, 0, 0, 0);
            acc0 = __builtin_amdgcn_mfma_f32_32x32x16_bf16(a1, b0, acc0, 0, 0, 0);
            acc0 = __builtin_amdgcn_mfma_f32_32x32x16_bf16(a1, b1, acc0, 0, 0, 0);
            acc0 = __builtin_amdgcn_mfma_f32_32x32x16_bf16(a0, b2, acc0, 0, 0, 0);
            acc0 = __builtin_amdgcn_mfma_f32_32x32x16_bf16(a2, b0, acc0, 0, 0, 0);
            a0 = Af[((1*3 + 0)*2 + wr)*128 + sub*64 + lane];
            a1 = Af[((1*3 + 1)*2 + wr)*128 + sub*64 + lane];
            a2 = Af[((1*3 + 2)*2 + wr)*128 + sub*64 + lane];
            acc1 = __builtin_amdgcn_mfma_f32_32x32x16_bf16(a0, b0, acc1, 0, 0, 0);
            acc1 = __builtin_amdgcn_mfma_f32_32x32x16_bf16(a0, b1, acc1, 0, 0, 0);
            acc1 = __builtin_amdgcn_mfma_f32_32x32x16_bf16(a1, b0, acc1, 0, 0, 0);
            acc1 = __builtin_amdgcn_mfma_f32_32x32x16_bf16(a1, b1, acc1, 0, 0, 0);
            acc1 = __builtin_amdgcn_mfma_f32_32x32x16_bf16(a0, b2, acc1, 0, 0, 0);
            acc1 = __builtin_amdgcn_mfma_f32_32x32x16_bf16(a2, b0, acc1, 0, 0, 0);
        }
        __syncthreads();
    }

    int colg = n0 + 32*wc + (lane & 31);
    int rowb = m0 + 32*wr + 4*(lane >> 5);
    #pragma unroll
    for (int reg = 0; reg < 16; ++reg) {
        int row = rowb + (reg & 3) + 8*(reg >> 2);
        C0[(size_t)row * 576 + colg] = acc0[reg];
        C1[(size_t)row * 576 + colg] = acc1[reg];
    }
}

// ---------------------------------------------------------------------------
// mm_abt_mfma: final AKA partial GEMM (C = A @ B^T per plane), r5-verified.
// ---------------------------------------------------------------------------
__global__ __launch_bounds__(256, 2)
void mm_abt_mfma(const float* __restrict__ Aall, const float* __restrict__ Ball,
                 float* __restrict__ Call, long sA, long sB, long sC, long sSplit)
{
    int p = blockIdx.x;
    int ir = 0;
    while (p >= ir + 1) { p -= ir + 1; ir++; }
    int my = ir, nx = p;
    int zz = blockIdx.z;
    int sp = zz & 3, b = zz >> 2;
    const float* A = Aall + (size_t)b * sA + (size_t)sp * N2;   // [m][k]
    const float* B = Ball + (size_t)b * sB + (size_t)sp * N2;   // [n][k]
    float* Cp = Call + (size_t)b * sC + (size_t)sp * sSplit;
    int m0 = my * 64, n0 = nx * 64;

    __shared__ __align__(16) unsigned short Fr[12][2][64][8];   // 24 KB

    int tid  = threadIdx.x;
    int lane = tid & 63;
    int wid  = tid >> 6;
    int wr = wid >> 1, wc = wid & 1;

    f32x16 acc;
    #pragma unroll
    for (int i = 0; i < 16; ++i) acc[i] = 0.0f;

    int sel  = tid >> 7;          // 0: stage A, 1: stage B
    int q2   = tid & 127;
    int r    = q2 >> 1;           // row 0..63 (m for A, n for B)
    int ssub = q2 & 1;            // 16-k half
    const float* Src = sel ? B : A;
    int base0 = sel ? n0 : m0;
    int rreg = r >> 5;
    int rln  = r & 31;

    float av[16];

    auto loadF = [&](int k0) {
        const float* pp = Src + (size_t)(base0 + r) * 576 + k0 + ssub * 16;
        float4 t0 = *(const float4*)(pp);
        float4 t1 = *(const float4*)(pp + 4);
        float4 t2 = *(const float4*)(pp + 8);
        float4 t3 = *(const float4*)(pp + 12);
        av[0]=t0.x;  av[1]=t0.y;  av[2]=t0.z;  av[3]=t0.w;
        av[4]=t1.x;  av[5]=t1.y;  av[6]=t1.z;  av[7]=t1.w;
        av[8]=t2.x;  av[9]=t2.y;  av[10]=t2.z; av[11]=t2.w;
        av[12]=t3.x; av[13]=t3.y; av[14]=t3.z; av[15]=t3.w;
    };
    auto storeF = [&]() {
        unsigned short s0[16], s1[16], s2[16];
        #pragma unroll
        for (int j = 0; j < 16; ++j) split3(av[j], s0[j], s1[j], s2[j]);
        #pragma unroll
        for (int h = 0; h < 2; ++h) {
            int ln = rln + 32 * h;
            pack_store(&Fr[sel*6 + 0*2 + rreg][ssub][ln][0], &s0[8*h]);
            pack_store(&Fr[sel*6 + 1*2 + rreg][ssub][ln][0], &s1[8*h]);
            pack_store(&Fr[sel*6 + 2*2 + rreg][ssub][ln][0], &s2[8*h]);
        }
    };

    const short8v* Ff = (const short8v*)Fr;   // region*128 + sub*64 + lane

    loadF(0);
    for (int k0 = 0; k0 < 576; k0 += 32) {
        storeF();
        __syncthreads();
        if (k0 + 32 < 576) loadF(k0 + 32);
        #pragma unroll
        for (int sub = 0; sub < 2; ++sub) {
            short8v a0 = Ff[((0*2 + wr)*2 + sub)*64 + lane];
            short8v a1 = Ff[((1*2 + wr)*2 + sub)*64 + lane];
            short8v a2 = Ff[((2*2 + wr)*2 + sub)*64 + lane];
            short8v b0 = Ff[((6 + 0*2 + wc)*2 + sub)*64 + lane];
            short8v b1 = Ff[((6 + 1*2 + wc)*2 + sub)*64 + lane];
            short8v b2 = Ff[((6 + 2*2 + wc)*2 + sub)*64 + lane];
            acc = __builtin_amdgcn_mfma_f32_32x32x16_bf16(a0, b0, acc, 0, 0, 0);
            acc = __builtin_amdgcn_mfma_f32_32x32x16_bf16(a0, b1, acc, 0, 0, 0);
            acc = __builtin_amdgcn_mfma_f32_32x32x16_bf16(a1, b0, acc, 0, 0, 0);
            acc = __builtin_amdgcn_mfma_f32_32x32x16_bf16(a1, b1, acc, 0, 0, 0);
            acc = __builtin_amdgcn_mfma_f32_32x32x16_bf16(a0, b2, acc, 0, 0, 0);
            acc = __builtin_amdgcn_mfma_f32_32x32x16_bf16(a2, b0, acc, 0, 0, 0);
        }
        __syncthreads();
    }

    int colg = n0 + 32*wc + (lane & 31);
    int rowb = m0 + 32*wr + 4*(lane >> 5);
    #pragma unroll
    for (int reg = 0; reg < 16; ++reg) {
        int row = rowb + (reg & 3) + 8*(reg >> 2);
        Cp[(size_t)row * 576 + colg] = acc[reg];
    }
}

// ---------------------------------------------------------------------------
// mm_ata_mfma (r6-verified): Kinv = Linv^T @ Linv, symmetric lower + mirror.
// ---------------------------------------------------------------------------
__global__ __launch_bounds__(256, 2)
void mm_ata_mfma(const float* __restrict__ Lg, float* __restrict__ C,
                 long sA, long sC)
{
    int p = blockIdx.x;
    int ir = 0;
    while (p >= ir + 1) { p -= ir + 1; ir++; }
    int my = ir, nx = p;
    int b = blockIdx.z;
    const float* A = Lg + (size_t)b * sA;    // Linv, [k][col] row-major in k
    float* Cb = C + (size_t)b * sC;
    int m0 = my * 64, n0 = nx * 64;
    int kBeg = m0;                           // my >= nx

    __shared__ __align__(16) unsigned short Fr[12][2][64][8];   // 24 KB

    int tid  = threadIdx.x;
    int lane = tid & 63;
    int wid  = tid >> 6;
    int wr = wid >> 1, wc = wid & 1;

    f32x16 acc;
    #pragma unroll
    for (int i = 0; i < 16; ++i) acc[i] = 0.0f;

    int sel  = tid >> 7;          // 0: A-frag (m cols), 1: B-frag (n cols)
    int q2   = tid & 127;
    int col  = q2 & 63;           // coalesced: lanes 0..63 -> consecutive cols
    int ssub = q2 >> 6;           // 16-k half
    int c0base = sel ? n0 : m0;
    int rreg = col >> 5;
    int rln  = col & 31;

    float av[16];

    auto loadF = [&](int k0) {
        const float* pp = A + (size_t)(k0 + ssub * 16) * 576 + c0base + col;
        #pragma unroll
        for (int j = 0; j < 16; ++j) av[j] = pp[(size_t)j * 576];
    };
    auto storeF = [&]() {
        unsigned short s0[16], s1[16], s2[16];
        #pragma unroll
        for (int j = 0; j < 16; ++j) split3(av[j], s0[j], s1[j], s2[j]);
        #pragma unroll
        for (int h = 0; h < 2; ++h) {
            int ln = rln + 32 * h;
            pack_store(&Fr[sel*6 + 0*2 + rreg][ssub][ln][0], &s0[8*h]);
            pack_store(&Fr[sel*6 + 1*2 + rreg][ssub][ln][0], &s1[8*h]);
            pack_store(&Fr[sel*6 + 2*2 + rreg][ssub][ln][0], &s2[8*h]);
        }
    };

    const short8v* Ff = (const short8v*)Fr;

    loadF(kBeg);
    for (int k0 = kBeg; k0 < 576; k0 += 32) {
        storeF();
        __syncthreads();
        if (k0 + 32 < 576) loadF(k0 + 32);
        #pragma unroll
        for (int sub = 0; sub < 2; ++sub) {
            short8v a0 = Ff[((0*2 + wr)*2 + sub)*64 + lane];
            short8v a1 = Ff[((1*2 + wr)*2 + sub)*64 + lane];
            short8v a2 = Ff[((2*2 + wr)*2 + sub)*64 + lane];
            short8v b0 = Ff[((6 + 0*2 + wc)*2 + sub)*64 + lane];
            short8v b1 = Ff[((6 + 1*2 + wc)*2 + sub)*64 + lane];
            short8v b2 = Ff[((6 + 2*2 + wc)*2 + sub)*64 + lane];
            acc = __builtin_amdgcn_mfma_f32_32x32x16_bf16(a0, b0, acc, 0, 0, 0);
            acc = __builtin_amdgcn_mfma_f32_32x32x16_bf16(a0, b1, acc, 0, 0, 0);
            acc = __builtin_amdgcn_mfma_f32_32x32x16_bf16(a1, b0, acc, 0, 0, 0);
            acc = __builtin_amdgcn_mfma_f32_32x32x16_bf16(a1, b1, acc, 0, 0, 0);
            acc = __builtin_amdgcn_mfma_f32_32x32x16_bf16(a0, b2, acc, 0, 0, 0);
            acc = __builtin_amdgcn_mfma_f32_32x32x16_bf16(a2, b0, acc, 0, 0, 0);
        }
        __syncthreads();
    }

    int colg = n0 + 32*wc + (lane & 31);
    int rowb = m0 + 32*wr + 4*(lane >> 5);
    #pragma unroll
    for (int reg = 0; reg < 16; ++reg) {
        int row = rowb + (reg & 3) + 8*(reg >> 2);
        float v = acc[reg];
        Cb[(size_t)row * 576 + colg] = v;
        Cb[(size_t)colg * 576 + row] = v;    // mirror (bit-identical value)
    }
}

// ---------------------------------------------------------------------------
// mm_ab_mfma (r6-verified): iW = Kin @ Kinv, direct write.
// ---------------------------------------------------------------------------
__global__ __launch_bounds__(256, 2)
void mm_ab_mfma(const float* __restrict__ Aall, const float* __restrict__ Ball,
                float* __restrict__ Call, long sA, long sB, long sC)
{
    int nx = blockIdx.x % 9, my = blockIdx.x / 9;
    int b = blockIdx.z;
    const float* A = Aall + (size_t)b * sA;   // [m][k]
    const float* B = Ball + (size_t)b * sB;   // [k][n]
    float* Cb = Call + (size_t)b * sC;
    int m0 = my * 64, n0 = nx * 64;

    __shared__ __align__(16) unsigned short Fr[12][2][64][8];   // 24 KB

    int tid  = threadIdx.x;
    int lane = tid & 63;
    int wid  = tid >> 6;
    int wr = wid >> 1, wc = wid & 1;

    f32x16 acc;
    #pragma unroll
    for (int i = 0; i < 16; ++i) acc[i] = 0.0f;

    int sel  = tid >> 7;          // 0: A rows (float4), 1: B cols (scalar)
    int q2   = tid & 127;
    int ar   = q2 >> 1;
    int asub = q2 & 1;
    int areg = ar >> 5, aln = ar & 31;
    int bcol = q2 & 63;
    int bssub = q2 >> 6;
    int breg = bcol >> 5, brln = bcol & 31;

    float av[16];

    auto loadF = [&](int k0) {
        if (sel == 0) {
            const float* pp = A + (size_t)(m0 + ar) * 576 + k0 + asub * 16;
            float4 t0 = *(const float4*)(pp);
            float4 t1 = *(const float4*)(pp + 4);
            float4 t2 = *(const float4*)(pp + 8);
            float4 t3 = *(const float4*)(pp + 12);
            av[0]=t0.x;  av[1]=t0.y;  av[2]=t0.z;  av[3]=t0.w;
            av[4]=t1.x;  av[5]=t1.y;  av[6]=t1.z;  av[7]=t1.w;
            av[8]=t2.x;  av[9]=t2.y;  av[10]=t2.z; av[11]=t2.w;
            av[12]=t3.x; av[13]=t3.y; av[14]=t3.z; av[15]=t3.w;
        } else {
            const float* pp = B + (size_t)(k0 + bssub * 16) * 576 + n0 + bcol;
            #pragma unroll
            for (int j = 0; j < 16; ++j) av[j] = pp[(size_t)j * 576];
        }
    };
    auto storeF = [&]() {
        unsigned short s0[16], s1[16], s2[16];
        #pragma unroll
        for (int j = 0; j < 16; ++j) split3(av[j], s0[j], s1[j], s2[j]);
        int reg0 = sel ? (6 + 0*2 + breg) : (0*2 + areg);
        int reg1 = sel ? (6 + 1*2 + breg) : (1*2 + areg);
        int reg2 = sel ? (6 + 2*2 + breg) : (2*2 + areg);
        int sb   = sel ? bssub : asub;
        int ln0  = sel ? brln : aln;
        #pragma unroll
        for (int h = 0; h < 2; ++h) {
            int ln = ln0 + 32 * h;
            pack_store(&Fr[reg0][sb][ln][0], &s0[8*h]);
            pack_store(&Fr[reg1][sb][ln][0], &s1[8*h]);
            pack_store(&Fr[reg2][sb][ln][0], &s2[8*h]);
        }
    };

    const short8v* Ff = (const short8v*)Fr;

    loadF(0);
    for (int k0 = 0; k0 < 576; k0 += 32) {
        storeF();
        __syncthreads();
        if (k0 + 32 < 576) loadF(k0 + 32);
        #pragma unroll
        for (int sub = 0; sub < 2; ++sub) {
            short8v a0 = Ff[((0*2 + wr)*2 + sub)*64 + lane];
            short8v a1 = Ff[((1*2 + wr)*2 + sub)*64 + lane];
            short8v a2 = Ff[((2*2 + wr)*2 + sub)*64 + lane];
            short8v b0 = Ff[((6 + 0*2 + wc)*2 + sub)*64 + lane];
            short8v b1 = Ff[((6 + 1*2 + wc)*2 + sub)*64 + lane];
            short8v b2 = Ff[((6 + 2*2 + wc)*2 + sub)*64 + lane];
            acc = __builtin_amdgcn_mfma_f32_32x32x16_bf16(a0, b0, acc, 0, 0, 0);
            acc = __builtin_amdgcn_mfma_f32_32x32x16_bf16(a0, b1, acc, 0, 0, 0);
            acc = __builtin_amdgcn_mfma_f32_32x32x16_bf16(a1, b0, acc, 0, 0, 0);
            acc = __builtin_amdgcn_mfma_f32_32x32x16_bf16(a1, b1, acc, 0, 0, 0);
            acc = __builtin_amdgcn_mfma_f32_32x32x16_bf16(a0, b2, acc, 0, 0, 0);
            acc = __builtin_amdgcn_mfma_f32_32x32x16_bf16(a2, b0, acc, 0, 0, 0);
        }
        __syncthreads();
    }

    int colg = n0 + 32*wc + (lane & 31);
    int rowb = m0 + 32*wr + 4*(lane >> 5);
    #pragma unroll
    for (int reg = 0; reg < 16; ++reg) {
        int row = rowb + (reg & 3) + 8*(reg >> 2);
        Cb[(size_t)row * 576 + colg] = acc[reg];
    }
}

// ---------------------------------------------------------------------------
// batched tiled matmul, 64x64 C-tile, 256 threads (4x4 micro), reg prefetch.
// (still used for the small skinny GEMMs: sol_mean, opimean)
// ---------------------------------------------------------------------------
template<int TA, int TB, int SK, int TRI, int SWZ, int EPIB, int TRIC>
__global__ __launch_bounds__(256)
void mm_kernel(const float* __restrict__ Aall, const float* __restrict__ Ball,
               float* __restrict__ Call,
               int M, int N, int K, int planeK,
               int lda, int ldb, int ldc,
               long sA, long sB, long sC, long pA, long pB, long sSplit, int MT)
{
    int nx, my, zz;
    if (TRIC) {
        int p = blockIdx.x;
        int ir = 0;
        while (p >= ir + 1) { p -= ir + 1; ir++; }
        my = ir; nx = p; zz = blockIdx.z;
    } else if (SWZ) {
        int id = blockIdx.x;
        int x8 = id & 7;
        int q  = id >> 3;
        nx = q % 9;
        int band = x8 + 8 * (q / 9);
        if (band >= MT * 4 * SK) return;
        my = band % MT;
        zz = band / MT;
    } else { nx = blockIdx.x; my = blockIdx.y; zz = blockIdx.z; }
    int sp = (SK > 1) ? (zz % SK) : 0;
    int b  = (SK > 1) ? (zz / SK) : zz;
    const float* A = Aall + (size_t)b * sA;
    const float* B = Ball + (size_t)b * sB;
    float* C = Call + (size_t)b * sC + (size_t)sp * sSplit;
    int n0 = nx * 64;
    int m0 = my * 64;

    __shared__ float As[16][68];
    __shared__ float Bs[16][68];

    int tid = threadIdx.x;
    int tx = tid & 15, ty = tid >> 4;

    float acc[4][4] = {};
    bool mFull = (m0 + 64 <= M);
    bool nFull = (n0 + 64 <= N);

    int triBeg = 0;
    if (TRI) { int mx = (m0 > n0 ? m0 : n0); triBeg = mx & ~15; }
    int kBeg = triBeg, kEnd = K;
    if (SK > 1) {
        int len = K - triBeg;
        int chunk = ((len / SK) + 15) & ~15;
        kBeg = triBeg + sp * chunk;
        if (kBeg > K) kBeg = K;
        kEnd = (sp == SK - 1) ? K : (kBeg + chunk < K ? kBeg + chunk : K);
    }

    float avr[4];
    float bvr[4];

    auto loadA = [&](int k0) {
        int plane = k0 / planeK;
        int koff  = k0 - plane * planeK;
        if (TA == 0) {
            const float* Ab = A + (size_t)pA * plane;
            int r = tid >> 2, c4 = (tid & 3) * 4;
            int gm = m0 + r;
            if (mFull || gm < M) {
                float4 t = *(const float4*)(Ab + (size_t)gm * lda + koff + c4);
                avr[0]=t.x; avr[1]=t.y; avr[2]=t.z; avr[3]=t.w;
            } else { avr[0]=avr[1]=avr[2]=avr[3]=0.0f; }
        } else {
            int r = tid >> 4, c4 = (tid & 15) * 4;
            const float* p = A + (size_t)(koff + r) * lda + m0 + c4;
            if (mFull) {
                float4 t = *(const float4*)p;
                avr[0]=t.x; avr[1]=t.y; avr[2]=t.z; avr[3]=t.w;
            } else {
                #pragma unroll
                for (int jj = 0; jj < 4; ++jj)
                    avr[jj] = (m0 + c4 + jj < M) ? p[jj] : 0.0f;
            }
        }
    };
    auto storeA = [&]() {
        if (TA == 0) {
            int r = tid >> 2, c4 = (tid & 3) * 4;
            #pragma unroll
            for (int q = 0; q < 4; ++q) As[c4+q][r] = avr[q];
        } else {
            int r = tid >> 4, c4 = (tid & 15) * 4;
            #pragma unroll
            for (int q = 0; q < 4; ++q) As[r][c4+q] = avr[q];
        }
    };
    auto loadB = [&](int k0) {
        int plane = k0 / planeK;
        int koff  = k0 - plane * planeK;
        if (TB == 0) {
            int r = tid >> 4, c4 = (tid & 15) * 4;
            const float* p = B + (size_t)(koff + r) * ldb + n0 + c4;
            if (nFull) {
                float4 t = *(const float4*)p;
                bvr[0]=t.x; bvr[1]=t.y; bvr[2]=t.z; bvr[3]=t.w;
            } else {
                #pragma unroll
                for (int jj = 0; jj < 4; ++jj)
                    bvr[jj] = (n0 + c4 + jj < N) ? p[jj] : 0.0f;
            }
            if (EPIB) {
                int gk = koff + r;
                #pragma unroll
                for (int jj = 0; jj < 4; ++jj)
                    if (gk == n0 + c4 + jj) bvr[jj] -= 1.0f;
            }
        } else {
            const float* Bb = B + (size_t)pB * plane;
            int r = tid >> 2, c4 = (tid & 3) * 4;
            int gp = n0 + r;
            if (nFull || gp < N) {
                float4 t = *(const float4*)(Bb + (size_t)gp * ldb + koff + c4);
                bvr[0]=t.x; bvr[1]=t.y; bvr[2]=t.z; bvr[3]=t.w;
            } else { bvr[0]=bvr[1]=bvr[2]=bvr[3]=0.0f; }
        }
    };
    auto storeB = [&]() {
        if (TB == 0) {
            int r = tid >> 4, c4 = (tid & 15) * 4;
            #pragma unroll
            for (int q = 0; q < 4; ++q) Bs[r][c4+q] = bvr[q];
        } else {
            int r = tid >> 2, c4 = (tid & 3) * 4;
            #pragma unroll
            for (int q = 0; q < 4; ++q) Bs[c4+q][r] = bvr[q];
        }
    };

    if (kBeg < kEnd) {
        loadA(kBeg); loadB(kBeg);
        for (int k0 = kBeg; k0 < kEnd; k0 += 16) {
            storeA(); storeB();
            __syncthreads();
            if (k0 + 16 < kEnd) { loadA(k0 + 16); loadB(k0 + 16); }
            #pragma unroll
            for (int kk = 0; kk < 16; ++kk) {
                float a[4], bb[4];
                *(float4*)a  = *(const float4*)&As[kk][ty*4];
                *(float4*)bb = *(const float4*)&Bs[kk][tx*4];
                #pragma unroll
                for (int i = 0; i < 4; ++i)
                    #pragma unroll
                    for (int j = 0; j < 4; ++j)
                        acc[i][j] += a[i] * bb[j];
            }
            __syncthreads();
        }
    }

    #pragma unroll
    for (int i = 0; i < 4; ++i) {
        int gm = m0 + ty*4 + i;
        if (gm >= M) continue;
        #pragma unroll
        for (int j = 0; j < 4; ++j) {
            int gn = n0 + tx*4 + j;
            if (gn >= N) continue;
            C[(size_t)gm * ldc + gn] = acc[i][j];
        }
    }
}

// ---------------------------------------------------------------------------
// combine kernels
// ---------------------------------------------------------------------------
__global__ void combine_solm4(const float* __restrict__ p, float* __restrict__ o) {
    int i = blockIdx.x * 256 + threadIdx.x;   // 73728 elems -> 288 WGs
    o[i] = p[i] + p[i + 73728] + p[i + 2*73728] + p[i + 3*73728];
}

// symmetric combine: partials valid only for m>=n; prior symmetric; write both
__global__ void combine_prior4_sym(const float* __restrict__ p0,
                                   const float* __restrict__ xin,
                                   const float* __restrict__ W2g,
                                   float* __restrict__ o, long stride) {
    __shared__ float w[16];
    int tid = threadIdx.x;
    if (tid < 16) w[tid] = W2g[tid];
    __syncthreads();
    int idx = blockIdx.x * 256 + tid;           // over 4*N2
    int b = idx / N2;
    int rem = idx - b * N2;
    int m = rem / NPTS, n = rem - m * NPTS;
    if (m < n) return;
    const float* xb = xin + (size_t)b * NPTS * 2;
    float r0 = xb[m*2+0] - xb[n*2+0];
    float r1 = xb[m*2+1] - xb[n*2+1];
    float u = (r0*r0 + r1*r1) * INVL2;
    float Kv = expf(-0.5f * u);
    float i2 = INVL2 * INVL2;
    float gK0 = r0 * INVL2 * Kv;
    float gK1 = r1 * INVL2 * Kv;
    float lapK = (u - 2.0f) * INVL2 * Kv;
    float gg00 = (INVL2 - r0*r0*i2) * Kv;
    float gg01 = (-r0*r1*i2) * Kv;
    float gg11 = (INVL2 - r1*r1*i2) * Kv;
    float gl0 = r0 * i2 * (4.0f - u) * Kv;
    float gl1 = r1 * i2 * (4.0f - u) * Kv;
    float ll = ((u-2.0f)*(u-2.0f) - 4.0f*u + 4.0f) * i2 * Kv;
    float prior =
          w[0]*Kv + w[1]*gK0 + w[2]*gK1 + w[3]*lapK
        + w[4]*(-gK0) + w[5]*gg00 + w[6]*gg01 + w[7]*gl0
        + w[8]*(-gK1) + w[9]*gg01 + w[10]*gg11 + w[11]*gl1
        + w[12]*lapK + w[13]*(-gl0) + w[14]*(-gl1) + w[15]*ll;
    float v = p0[idx] + p0[idx + stride] + p0[idx + 2*stride] + p0[idx + 3*stride]
            + prior;
    if (m == n) v += 1.1e-4f;
    o[(size_t)b * N2 + (size_t)m * NPTS + n] = v;
    if (m != n)
        o[(size_t)b * N2 + (size_t)n * NPTS + m] = v;
}

// ---------------------------------------------------------------------------
// opiKW2[b][i] = sum_j W2[i][j] * opiK[b][j]  — safe in-place (per-element)
// ---------------------------------------------------------------------------
__global__ void opiw2_k(const float* __restrict__ opiK, const float* __restrict__ W2,
                        float* __restrict__ outB) {
    int idx = blockIdx.x * 256 + threadIdx.x;
    int b = idx / N2;
    int rem = idx - b * N2;
    size_t base = (size_t)b * 4 * N2 + rem;
    float k0 = opiK[base], k1 = opiK[base + N2], k2 = opiK[base + 2*N2], k3 = opiK[base + 3*N2];
    #pragma unroll
    for (int i = 0; i < 4; ++i)
        outB[base + (size_t)i * N2] = W2[i*4+0]*k0 + W2[i*4+1]*k1 + W2[i*4+2]*k2 + W2[i*4+3]*k3;
}

// ---------------------------------------------------------------------------
__global__ __launch_bounds__(256)
void amean_k(const float* __restrict__ opimean, const float* __restrict__ weight,
             const float* __restrict__ bias, float* __restrict__ out) {
    int b = blockIdx.y;
    int m0 = blockIdx.x * 32;
    __shared__ float Wl[64][128];
    __shared__ float om[32][128];
    int tid = threadIdx.x;
    for (int idx = tid; idx < 64*128; idx += 256) Wl[idx / 128][idx & 127] = weight[idx];
    for (int idx = tid; idx < 32*128; idx += 256) {
        int m = idx >> 7, ck = idx & 127, c = ck >> 2, kop = ck & 3;
        om[m][ck] = opimean[((size_t)b * 4 + kop) * NPTS * 32 + (size_t)(m0 + m) * 32 + c];
    }
    __syncthreads();
    int ml = tid >> 3, o0 = (tid & 7) * 8;
    float acc[8] = {};
    for (int ck = 0; ck < 128; ++ck) {
        float v = om[ml][ck];
        #pragma unroll
        for (int q = 0; q < 8; ++q) acc[q] += v * Wl[o0+q][ck];
    }
    #pragma unroll
    for (int q = 0; q < 8; ++q)
        out[4608 + ((size_t)b * NPTS + m0 + ml) * 64 + o0 + q] = acc[q] + bias[o0+q];
}

// ---------------------------------------------------------------------------
static inline int gridSwz(int MT, int Z) { return 8 * 9 * ((MT * Z + 7) / 8); }

extern "C" void kernel_launch(void* const* d_in, const int* in_sizes, int n_in,
                              void* d_out, int out_size, void* d_ws, size_t ws_size,
                              hipStream_t stream) {
    const float* xin    = (const float*)d_in[0];
    const float* meanin = (const float*)d_in[1];
    const float* Kin    = (const float*)d_in[2];
    const float* weight = (const float*)d_in[3];
    const float* bias   = (const float*)d_in[4];
    float* out = (float*)d_out;
    float* ws  = (float*)d_ws;

    const long N2L = N2;
    float* W2      = ws;                       // 16 (pad 64)
    float* LinvKK  = ws + 64;                  // 4*9*4096
    float* R1 = LinvKK + 147456;               // 4*N2: Kxx/A; later iW (direct)
    float* R2 = R1 + 4*N2L;                    // 4*N2: Linv; later solm/opim
    float* R3 = R2 + 4*N2L;                    // 4*N2: L panels; later Kinv (direct)
    float* R4 = R3 + 4*N2L;                    // 16*N2: opiK; later opiKW2 (in-place)
    float* R5 = R4 + 16*N2L;                   // 16*N2: KiO (direct); final partials
    float* R6 = R5 + 16*N2L;                   // 16*N2: solm partials; H'

    // zero Linv (upper triangle must be 0)
    hipMemsetAsync(R2, 0, (size_t)4 * N2 * sizeof(float), stream);
    // build_k: Kxx + opiK + fused copy_xout + fused w2
    build_k<<<dim3((BSZ*N2)/256), dim3(256), 0, stream>>>(
        xin, R1, R4, out, weight, W2);
    // Cholesky: 9 launches. L panels -> R3; diag inverses -> LinvKK
    chol_diag0<<<dim3(BSZ), dim3(256), 0, stream>>>(R1, LinvKK);
    for (int kb = 0; kb < NT - 1; ++kb) {
        int t = NT - 1 - kb;
        chol_step<<<dim3(t*(t+1)/2, BSZ), dim3(256), 0, stream>>>(R1, R3, LinvKK, kb);
    }
    // triangular inverse (4x4 reg-tiled k-split + prefetch) -> R2
    trinv_blk<<<dim3(4, NT, BSZ), dim3(256), 0, stream>>>(R3, LinvKK, R2);
    // Kinv = Linv^T @ Linv  (bf16x3 MFMA, sym lower tiles + mirror, direct -> R3)
    mm_ata_mfma<<<dim3(45, 1, BSZ), dim3(256), 0, stream>>>(R2, R3, N2L, N2L);
    // sol_mean = Kinv @ meanin  (SK4 partials -> R6; combine -> R2)
    mm_kernel<0,0,4,0,0,0,0><<<dim3(1,9,16), dim3(256), 0, stream>>>(
        R3, meanin, R6, 576,32,576,576, 576,32,32,
        N2L,18432,18432, 0,0, 73728, 9);
    combine_solm4<<<dim3(288), dim3(256), 0, stream>>>(R6, R2);
    // opimean = opiK @ sol_mean -> R2+73728
    mm_kernel<0,0,1,0,0,0,0><<<dim3(1,36,BSZ), dim3(256), 0, stream>>>(
        R4, R2, R2 + 73728, 2304,32,576,576, 576,32,32,
        4*N2L,18432,73728, 0,0, 0, 9);
    amean_k<<<dim3(18,BSZ), dim3(256), 0, stream>>>(R2 + 73728, weight, bias, out);
    // iW = Kin @ Kinv  (bf16x3 MFMA, direct -> R1, no combine)
    mm_ab_mfma<<<dim3(81, 1, BSZ), dim3(256), 0, stream>>>(
        Kin, R3, R1, N2L, N2L, N2L);
    // KiO = opiK @ Kinv  (bf16x3 MFMA, full-K, direct write -> R5, no combine)
    mm_p2_mfma<0><<<dim3(gridSwz(18,4)), dim3(256), 0, stream>>>(
        R4, R3, R5, 4*N2L, N2L, 4*N2L);
    // opiKW2 in-place on R4 (opiK no longer needed)
    opiw2_k<<<dim3((BSZ*N2)/256), dim3(256), 0, stream>>>(R4, W2, R4);
    // H' = KiO @ (iW - I)  (bf16x3 MFMA, -I fold) -> R6
    mm_p2_mfma<1><<<dim3(gridSwz(18,4)), dim3(256), 0, stream>>>(
        R5, R1, R6, 4*N2L, N2L, 4*N2L);
    // final AKA partial GEMM — SYMMETRIC lower tiles, MFMA, SK4 = plane-split.
    // partials -> R5 (sC=N2 batch plane, sSplit=4*N2 split plane)
    mm_abt_mfma<<<dim3(45,1,BSZ*4), dim3(256), 0, stream>>>(
        R6, R4, R5, 4*N2L, 4*N2L, N2L, 4*N2L);
    // output 2: combine 4 partials (m>=n) + analytic prior + jitter, mirrored
    combine_prior4_sym<<<dim3(5184), dim3(256), 0, stream>>>(
        R5, xin, W2, out + 152064, 4*N2L);
}